// Round 1
// baseline (862.702 us; speedup 1.0000x reference)
//
#include <hip/hip_runtime.h>
#include <cstdint>
#include <cstddef>

// Problem constants (fixed by the reference setup_inputs).
#define NN 100000
#define EE 500000
#define DD 128
#define GG 512
#define LL 4
#define BN_EPS 1e-5f

typedef __attribute__((ext_vector_type(8))) short short8;
typedef __attribute__((ext_vector_type(8))) unsigned short ushort8v;
typedef __attribute__((ext_vector_type(4))) float f32x4;

static __device__ __forceinline__ unsigned short f2bf(float f) {
  union { float f; unsigned u; } v;
  v.f = f;
  unsigned r = v.u + 0x7fffu + ((v.u >> 16) & 1u);  // RNE
  return (unsigned short)(r >> 16);
}
static __device__ __forceinline__ float bf2f(unsigned short u) {
  union { unsigned u; float f; } v;
  v.u = ((unsigned)u) << 16;
  return v.f;
}

// ---------------- CSR build (int32 inputs) ----------------

__global__ void k_hist(const int* __restrict__ ei, int* __restrict__ cnt) {
  int e = blockIdx.x * 256 + threadIdx.x;
  if (e < EE) {
    int d = ei[EE + e];
    if (d >= 0 && d < NN) atomicAdd(&cnt[d], 1);
  }
}

__global__ void k_part(const int* __restrict__ cnt, int* __restrict__ part) {
  __shared__ int sm[1024];
  int t = threadIdx.x;
  int i = blockIdx.x * 1024 + t;
  sm[t] = (i < NN) ? cnt[i] : 0;
  __syncthreads();
  for (int off = 512; off > 0; off >>= 1) {
    if (t < off) sm[t] += sm[t + off];
    __syncthreads();
  }
  if (t == 0) part[blockIdx.x] = sm[0];
}

__global__ void k_scanpart(const int* __restrict__ part, int* __restrict__ partx, int nb) {
  __shared__ int sm[128];
  int t = threadIdx.x;
  int v = (t < nb) ? part[t] : 0;
  sm[t] = v;
  __syncthreads();
  for (int off = 1; off < 128; off <<= 1) {
    int u = (t >= off) ? sm[t - off] : 0;
    __syncthreads();
    sm[t] += u;
    __syncthreads();
  }
  if (t < nb) partx[t] = sm[t] - v;
}

__global__ void k_rs(const int* __restrict__ cnt, const int* __restrict__ partx,
                     int* __restrict__ rs, int* __restrict__ cur) {
  __shared__ int sm[1024];
  int t = threadIdx.x;
  int i = blockIdx.x * 1024 + t;
  int v = (i < NN) ? cnt[i] : 0;
  sm[t] = v;
  __syncthreads();
  for (int off = 1; off < 1024; off <<= 1) {
    int u = (t >= off) ? sm[t - off] : 0;
    __syncthreads();
    sm[t] += u;
    __syncthreads();
  }
  if (i < NN) {
    int excl = partx[blockIdx.x] + sm[t] - v;
    rs[i] = excl;
    cur[i] = excl;
    if (i == NN - 1) rs[NN] = excl + v;
  }
}

__global__ void k_fill(const int* __restrict__ ei, int* __restrict__ cur,
                       int* __restrict__ ci) {
  int e = blockIdx.x * 256 + threadIdx.x;
  if (e < EE) {
    int s = ei[e];
    int d = ei[EE + e];
    if (d >= 0 && d < NN && s >= 0 && s < NN) {
      int pos = atomicAdd(&cur[d], 1);
      if (pos >= 0 && pos < EE) ci[pos] = s;  // order irrelevant (sum)
    }
  }
}

// ---------------- weight convert: W -> W^T in bf16, once per call ----------------

__global__ void k_conv(const float* __restrict__ W1, const float* __restrict__ W2,
                       unsigned short* __restrict__ W1t, unsigned short* __restrict__ W2t) {
  int idx = blockIdx.x * 256 + threadIdx.x;
  if (idx < 4 * 256 * 128) {
    {  // W1: [l][k][nc] (K=128,NC=256) -> [l][nc][k]
      int l = idx >> 15, rem = idx & 32767;
      int nc = rem >> 7, k = rem & 127;
      W1t[idx] = f2bf(W1[(l << 15) + k * 256 + nc]);
    }
    {  // W2: [l][k][nc] (K=256,NC=128) -> [l][nc][k]
      int l = idx >> 15, rem = idx & 32767;
      int nc = rem >> 8, k = rem & 255;
      W2t[idx] = f2bf(W2[(l << 15) + k * 128 + nc]);
    }
  }
}

// ---------------- x -> bf16 convert (streaming, once per call) ----------------

__global__ void k_x2bf(const float* __restrict__ x, unsigned short* __restrict__ xb) {
  int i = blockIdx.x * 256 + threadIdx.x;
  if (i < NN * DD / 4) {
    float4 v = *(const float4*)(x + (size_t)i * 4);
    ushort4 o;
    o.x = f2bf(v.x); o.y = f2bf(v.y); o.z = f2bf(v.z); o.w = f2bf(v.w);
    *(ushort4*)(xb + (size_t)i * 4) = o;
  }
}

// ---------------- aggregation: bf16 X in (opt. BN/ReLU), bf16 h0 out ----
// 16 lanes/node, ushort8 (16B) loads, 1-deep neighbor prefetch.

__global__ __launch_bounds__(256) void k_agg_bf16(
    const unsigned short* __restrict__ X, const int* __restrict__ rs,
    const int* __restrict__ ci, const float* __restrict__ epsv, int l, int mode,
    const float* __restrict__ tsc, const float* __restrict__ tsh,
    unsigned short* __restrict__ h0, int n) {
  int idx = blockIdx.x * 256 + threadIdx.x;
  int node = idx >> 4;
  int c8 = (idx & 15) << 3;
  if (node >= n) return;
  float sa[8], sb[8];
  if (mode) {
    float4 a0 = *(const float4*)(tsc + c8), a1 = *(const float4*)(tsc + c8 + 4);
    float4 b0 = *(const float4*)(tsh + c8), b1 = *(const float4*)(tsh + c8 + 4);
    sa[0] = a0.x; sa[1] = a0.y; sa[2] = a0.z; sa[3] = a0.w;
    sa[4] = a1.x; sa[5] = a1.y; sa[6] = a1.z; sa[7] = a1.w;
    sb[0] = b0.x; sb[1] = b0.y; sb[2] = b0.z; sb[3] = b0.w;
    sb[4] = b1.x; sb[5] = b1.y; sb[6] = b1.z; sb[7] = b1.w;
  }
  float se = 1.f + epsv[l];
  ushort8v v = *(const ushort8v*)(X + (size_t)node * DD + c8);
  float acc[8];
#pragma unroll
  for (int j = 0; j < 8; ++j) {
    float f = bf2f(v[j]);
    if (mode) f = fmaxf(0.f, f * sa[j] + sb[j]);
    acc[j] = se * f;
  }
  int e0 = rs[node], e1 = rs[node + 1];
  ushort8v un;
  if (e0 < e1) un = *(const ushort8v*)(X + (size_t)ci[e0] * DD + c8);
  for (int e = e0; e < e1; ++e) {
    ushort8v uc = un;
    if (e + 1 < e1) un = *(const ushort8v*)(X + (size_t)ci[e + 1] * DD + c8);
#pragma unroll
    for (int j = 0; j < 8; ++j) {
      float f = bf2f(uc[j]);
      if (mode) f = fmaxf(0.f, f * sa[j] + sb[j]);
      acc[j] += f;
    }
  }
  ushort8v o;
#pragma unroll
  for (int j = 0; j < 8; ++j) o[j] = f2bf(acc[j]);
  *(ushort8v*)(h0 + (size_t)node * DD + c8) = o;
}

// ---------------- MFMA bf16 GEMM, barrier-free streaming structure ----------------
// 512 threads = 8 waves x 16 rows (128 rows/block). A rows are wave-private, so A
// fragments are loaded straight from global (16 rows x 64B sectors per instr); only
// B (weights, 64KB) is staged into LDS once (padded stride K+8). K-loop has ZERO
// barriers: 64 ds_read_b128 + 64 MFMAs per wave, free-running across 16 waves/CU.
// Swapped-operand MFMA (bv as A-slot, av as B-slot) puts 4 consecutive C columns in
// each lane -> direct 8B packed-bf16 stores, no LDS C staging. BN partial stats via
// shfl_xor tree + Bsm-reuse scratch (2 epilogue barriers). 3 barriers/block total.

template <int K, int NC>
__global__ __launch_bounds__(512, 4) void k_gemm(
    const unsigned short* __restrict__ A, int mode, const float* __restrict__ tsc,
    const float* __restrict__ tsh, const unsigned short* __restrict__ Bt,
    const float* __restrict__ bias, unsigned short* __restrict__ C,
    float* __restrict__ psum, float* __restrict__ psq, int n) {
  constexpr int KT = K / 32;   // A/B k-fragments (4 or 8)
  constexpr int CF = NC / 16;  // column fragments (16 or 8)
  constexpr int BP = K + 8;    // padded LDS row stride (ushorts): stride%32dw==4
  constexpr int CH = K / 8;    // 16B chunks per B row
  __shared__ __align__(16) unsigned short Bsm[NC * BP];

  int tid = threadIdx.x;
  int lane = tid & 63, wave = tid >> 6;
  int quad = lane >> 4, l15 = lane & 15;
  int r = blockIdx.x * 128 + wave * 16 + l15;
  bool valid = r < n;

  // A fragments: lane holds A[r][ks*32+quad*8 .. +7]; 16 lanes x 64B = full sectors.
  short8 av[KT];
#pragma unroll
  for (int ks = 0; ks < KT; ++ks) {
    av[ks] = (short8){0, 0, 0, 0, 0, 0, 0, 0};
    if (valid) av[ks] = *(const short8*)(A + (size_t)r * K + ks * 32 + quad * 8);
  }

  // stage B ([NC][K] bf16) into padded LDS; coalesced 16B loads.
#pragma unroll
  for (int it = 0; it < NC * CH / 512; ++it) {
    int f = tid + it * 512;
    int br = f / CH;
    int c8 = (f % CH) * 8;
    *(ushort8v*)(&Bsm[br * BP + c8]) = *(const ushort8v*)(Bt + (size_t)br * K + c8);
  }

  // BN+ReLU transform of A (GEMM2 path); invalid lanes produce garbage but are
  // masked at store/stats time.
  if (mode) {
#pragma unroll
    for (int ks = 0; ks < KT; ++ks) {
      int kg = ks * 32 + quad * 8;
      float4 s0 = *(const float4*)(tsc + kg), s1 = *(const float4*)(tsc + kg + 4);
      float4 t0 = *(const float4*)(tsh + kg), t1 = *(const float4*)(tsh + kg + 4);
      float sa[8] = {s0.x, s0.y, s0.z, s0.w, s1.x, s1.y, s1.z, s1.w};
      float sb[8] = {t0.x, t0.y, t0.z, t0.w, t1.x, t1.y, t1.z, t1.w};
      short8 v = av[ks];
#pragma unroll
      for (int j = 0; j < 8; ++j)
        v[j] = (short)f2bf(fmaxf(0.f, bf2f((unsigned short)v[j]) * sa[j] + sb[j]));
      av[ks] = v;
    }
  }

  __syncthreads();  // B tile ready (the only pre-compute barrier)

  f32x4 acc[CF];
#pragma unroll
  for (int cf = 0; cf < CF; ++cf) acc[cf] = (f32x4){0.f, 0.f, 0.f, 0.f};

  // ks outer / cf inner: consecutive MFMAs hit independent acc chains.
#pragma unroll
  for (int ks = 0; ks < KT; ++ks) {
#pragma unroll
    for (int cf = 0; cf < CF; ++cf) {
      short8 bv = *(const short8*)(&Bsm[(cf * 16 + l15) * BP + ks * 32 + quad * 8]);
      // swapped operands: D[bcol][arow]; lane -> (row r, cols cf*16+quad*4+reg)
      acc[cf] = __builtin_amdgcn_mfma_f32_16x16x32_bf16(bv, av[ks], acc[cf], 0, 0, 0);
    }
  }

  __syncthreads();  // all waves done reading Bsm; reuse it as stats scratch

  float* Ssum = (float*)Bsm;       // [8][NC]
  float* Ssq = Ssum + 8 * NC;      // [8][NC]

#pragma unroll
  for (int cf = 0; cf < CF; ++cf) {
    float4 bb = *(const float4*)(bias + cf * 16 + quad * 4);
    float e0 = acc[cf][0] + bb.x;
    float e1 = acc[cf][1] + bb.y;
    float e2 = acc[cf][2] + bb.z;
    float e3 = acc[cf][3] + bb.w;
    if (valid) {
      ushort4 o;
      o.x = f2bf(e0); o.y = f2bf(e1); o.z = f2bf(e2); o.w = f2bf(e3);
      *(ushort4*)(C + (size_t)r * NC + cf * 16 + quad * 4) = o;  // 8B packed store
    }
    float s0 = valid ? e0 : 0.f, s1 = valid ? e1 : 0.f;
    float s2 = valid ? e2 : 0.f, s3 = valid ? e3 : 0.f;
    float q0 = s0 * e0, q1 = s1 * e1, q2 = s2 * e2, q3 = s3 * e3;
#pragma unroll
    for (int m = 1; m < 16; m <<= 1) {  // reduce over the 16 row-lanes
      s0 += __shfl_xor(s0, m, 64); s1 += __shfl_xor(s1, m, 64);
      s2 += __shfl_xor(s2, m, 64); s3 += __shfl_xor(s3, m, 64);
      q0 += __shfl_xor(q0, m, 64); q1 += __shfl_xor(q1, m, 64);
      q2 += __shfl_xor(q2, m, 64); q3 += __shfl_xor(q3, m, 64);
    }
    if (l15 == 0) {
      *(float4*)(&Ssum[wave * NC + cf * 16 + quad * 4]) = (float4){s0, s1, s2, s3};
      *(float4*)(&Ssq[wave * NC + cf * 16 + quad * 4]) = (float4){q0, q1, q2, q3};
    }
  }

  __syncthreads();

  if (tid < NC) {
    float s = 0.f, q = 0.f;
#pragma unroll
    for (int w = 0; w < 8; ++w) {
      s += Ssum[w * NC + tid];
      q += Ssq[w * NC + tid];
    }
    psum[(size_t)blockIdx.x * NC + tid] = s;
    psq[(size_t)blockIdx.x * NC + tid] = q;
  }
}

// ---------------- column-stat reduce + BN finalize (one block per column) --------

__global__ __launch_bounds__(256) void k_finred(
    const float* __restrict__ psum, const float* __restrict__ psq, int nb, int nc,
    const float* __restrict__ g, const float* __restrict__ be,
    float* __restrict__ osc, float* __restrict__ osh, float invn) {
  __shared__ float ws[4], wq[4];
  int col = blockIdx.x;
  int t = threadIdx.x;
  float s = 0.f, q = 0.f;
  for (int b = t; b < nb; b += 256) {
    s += psum[(size_t)b * nc + col];
    q += psq[(size_t)b * nc + col];
  }
#pragma unroll
  for (int off = 32; off > 0; off >>= 1) {
    s += __shfl_xor(s, off, 64);
    q += __shfl_xor(q, off, 64);
  }
  if ((t & 63) == 0) { ws[t >> 6] = s; wq[t >> 6] = q; }
  __syncthreads();
  if (t == 0) {
    s = ws[0] + ws[1] + ws[2] + ws[3];
    q = wq[0] + wq[1] + wq[2] + wq[3];
    float m = s * invn;
    float v = fmaxf(q * invn - m * m, 0.f);
    float sc = g[col] * rsqrtf(v + BN_EPS);
    osc[col] = sc;
    osh[col] = be[col] - m * sc;
  }
}

// ---------------- classifier z1 stats (sum & sumsq from one array) ----------------

__global__ __launch_bounds__(256) void k_statz(
    const float* __restrict__ z1, const float* __restrict__ g,
    const float* __restrict__ be, float* __restrict__ osc, float* __restrict__ osh) {
  __shared__ float ws[4], wq[4];
  int col = blockIdx.x;
  int t = threadIdx.x;
  float s = 0.f, q = 0.f;
  for (int b = t; b < GG; b += 256) {
    float v = z1[(size_t)b * 128 + col];
    s += v;
    q += v * v;
  }
#pragma unroll
  for (int off = 32; off > 0; off >>= 1) {
    s += __shfl_xor(s, off, 64);
    q += __shfl_xor(q, off, 64);
  }
  if ((t & 63) == 0) { ws[t >> 6] = s; wq[t >> 6] = q; }
  __syncthreads();
  if (t == 0) {
    s = ws[0] + ws[1] + ws[2] + ws[3];
    q = wq[0] + wq[1] + wq[2] + wq[3];
    float m = s / (float)GG;
    float v = fmaxf(q / (float)GG - m * m, 0.f);
    float sc = g[col] * rsqrtf(v + BN_EPS);
    osc[col] = sc;
    osh[col] = be[col] - m * sc;
  }
}

// ---------------- pooling (batch sorted -> contiguous ranges), bf16 X ------------

static __device__ __forceinline__ int lb_i32(const int* a, int n, int key) {
  int lo = 0, hi = n;
  while (lo < hi) {
    int mid = (lo + hi) >> 1;
    if (a[mid] < key) lo = mid + 1; else hi = mid;
  }
  return lo;
}

__global__ __launch_bounds__(512) void k_pool(
    const unsigned short* __restrict__ X, const int* __restrict__ batch,
    const float* __restrict__ tsc, const float* __restrict__ tsh,
    float* __restrict__ z, int n) {
  __shared__ int slo, shi;
  __shared__ float ssum[8][128], smax[8][128];
  int g = blockIdx.x;
  int t = threadIdx.x;
  int sg = t >> 6;           // 0..7 row-subgroup
  int c2 = (t & 63) << 1;    // column pair base
  if (t == 0) {
    slo = lb_i32(batch, n, g);
    shi = lb_i32(batch, n, g + 1);
  }
  __syncthreads();
  int lo = slo, hi = shi;
  float a0 = tsc[c2], a1 = tsc[c2 + 1];
  float b0 = tsh[c2], b1 = tsh[c2 + 1];
  float s0 = 0.f, s1 = 0.f;
  float m0 = -3.402823466e38f, m1 = -3.402823466e38f;
  for (int i = lo + sg; i < hi; i += 8) {
    unsigned u = *(const unsigned*)(X + (size_t)i * DD + c2);
    float v0 = fmaxf(0.f, bf2f((unsigned short)(u & 0xffff)) * a0 + b0);
    float v1 = fmaxf(0.f, bf2f((unsigned short)(u >> 16)) * a1 + b1);
    s0 += v0; m0 = fmaxf(m0, v0);
    s1 += v1; m1 = fmaxf(m1, v1);
  }
  ssum[sg][c2] = s0; ssum[sg][c2 + 1] = s1;
  smax[sg][c2] = m0; smax[sg][c2 + 1] = m1;
  __syncthreads();
  if (t < 128) {
    float S = 0.f, M = -3.402823466e38f;
#pragma unroll
    for (int k = 0; k < 8; ++k) {
      S += ssum[k][t];
      M = fmaxf(M, smax[k][t]);
    }
    float cntf = (float)(hi - lo);
    z[(size_t)g * 384 + t] = S;
    z[(size_t)g * 384 + 128 + t] = S / fmaxf(cntf, 1.f);
    z[(size_t)g * 384 + 256 + t] = M;
  }
}

// ---------------- classifier head (fp32, tiny; no atomics) ----------------

__global__ void k_cls1(const float* __restrict__ z, const float* __restrict__ cW1,
                       const float* __restrict__ cb1, float* __restrict__ z1) {
  __shared__ float zr[384];
  int g = blockIdx.x;
  int c = threadIdx.x;  // 128
  for (int i = c; i < 384; i += 128) zr[i] = z[(size_t)g * 384 + i];
  __syncthreads();
  float s = cb1[c];
#pragma unroll 4
  for (int k = 0; k < 384; ++k) s = fmaf(zr[k], cW1[(size_t)k * 128 + c], s);
  z1[(size_t)g * 128 + c] = s;
}

__global__ void k_cls2(const float* __restrict__ z1, const float* __restrict__ csc,
                       const float* __restrict__ csh, const float* __restrict__ cW2,
                       const float* __restrict__ cb2, const float* __restrict__ cW3,
                       const float* __restrict__ cb3, float* __restrict__ out) {
  __shared__ float z1n[128];
  __shared__ float z2s[64];
  int g = blockIdx.x;
  int t = threadIdx.x;  // 128
  z1n[t] = fmaxf(0.f, z1[(size_t)g * 128 + t] * csc[t] + csh[t]);
  __syncthreads();
  if (t < 64) {
    float s = cb2[t];
#pragma unroll 4
    for (int k = 0; k < 128; ++k) s = fmaf(z1n[k], cW2[(size_t)k * 64 + t], s);
    z2s[t] = fmaxf(0.f, s);
  }
  __syncthreads();
  if (t < 2) {
    float s = cb3[t];
#pragma unroll 4
    for (int c = 0; c < 64; ++c) s = fmaf(z2s[c], cW3[(size_t)c * 2 + t], s);
    out[(size_t)g * 2 + t] = s;
  }
}

// ---------------- launch ----------------

extern "C" void kernel_launch(void* const* d_in, const int* in_sizes, int n_in,
                              void* d_out, int out_size, void* d_ws, size_t ws_size,
                              hipStream_t stream) {
  const float* x = (const float*)d_in[0];
  const int* ei = (const int*)d_in[1];     // int32 (harness downcasts int64)
  const int* batch = (const int*)d_in[2];  // int32
  const float* W1 = (const float*)d_in[4];
  const float* b1 = (const float*)d_in[5];
  const float* g1 = (const float*)d_in[6];
  const float* be1 = (const float*)d_in[7];
  const float* W2 = (const float*)d_in[8];
  const float* b2 = (const float*)d_in[9];
  const float* gbn = (const float*)d_in[10];
  const float* bbn = (const float*)d_in[11];
  const float* epsv = (const float*)d_in[12];
  const float* cW1 = (const float*)d_in[13];
  const float* cb1 = (const float*)d_in[14];
  const float* cg = (const float*)d_in[15];
  const float* cbeta = (const float*)d_in[16];
  const float* cW2 = (const float*)d_in[17];
  const float* cb2 = (const float*)d_in[18];
  const float* cW3 = (const float*)d_in[19];
  const float* cb3 = (const float*)d_in[20];
  float* out = (float*)d_out;

  char* p = (char*)d_ws;
  auto alloc = [&](size_t bytes) {
    char* r = p;
    p += (bytes + 255) & ~(size_t)255;
    return r;
  };
  const int NB = (NN + 127) / 128;  // 782 GEMM row-blocks
  int* cnt = (int*)alloc((size_t)NN * 4);
  int* rs = (int*)alloc((size_t)(NN + 1) * 4);
  int* cur = (int*)alloc((size_t)NN * 4);
  int* ci = (int*)alloc((size_t)EE * 4);
  int* part = (int*)alloc(128 * 4);
  int* partx = (int*)alloc(128 * 4);
  unsigned short* xbf = (unsigned short*)alloc((size_t)NN * DD * 2);
  unsigned short* h0 = (unsigned short*)alloc((size_t)NN * DD * 2);
  unsigned short* h1 = (unsigned short*)alloc((size_t)NN * 2 * DD * 2);
  unsigned short* xp = (unsigned short*)alloc((size_t)NN * DD * 2);
  float* psum = (float*)alloc((size_t)NB * 256 * 4);
  float* psq = (float*)alloc((size_t)NB * 256 * 4);
  float* tsc1 = (float*)alloc(256 * 4);
  float* tsh1 = (float*)alloc(256 * 4);
  float* tscX = (float*)alloc(128 * 4);
  float* tshX = (float*)alloc(128 * 4);
  float* zbuf = (float*)alloc((size_t)GG * 384 * 4);
  float* z1 = (float*)alloc((size_t)GG * 128 * 4);
  unsigned short* W1t = (unsigned short*)alloc((size_t)4 * 256 * 128 * 2);
  unsigned short* W2t = (unsigned short*)alloc((size_t)4 * 128 * 256 * 2);
  (void)ws_size; (void)n_in; (void)in_sizes; (void)out_size;

  // weight convert+transpose to bf16 (static across layers/calls)
  k_conv<<<512, 256, 0, stream>>>(W1, W2, W1t, W2t);
  // x -> bf16
  k_x2bf<<<(NN * DD / 4 + 255) / 256, 256, 0, stream>>>(x, xbf);

  // CSR build (edges static across layers)
  hipMemsetAsync(cnt, 0, (size_t)NN * 4, stream);
  k_hist<<<(EE + 255) / 256, 256, 0, stream>>>(ei, cnt);
  const int nscan = (NN + 1023) / 1024;  // 98
  k_part<<<nscan, 1024, 0, stream>>>(cnt, part);
  k_scanpart<<<1, 128, 0, stream>>>(part, partx, nscan);
  k_rs<<<nscan, 1024, 0, stream>>>(cnt, partx, rs, cur);
  k_fill<<<(EE + 255) / 256, 256, 0, stream>>>(ei, cur, ci);

  for (int l = 0; l < LL; ++l) {
    const unsigned short* Xl = (l == 0) ? xbf : xp;
    k_agg_bf16<<<(NN * 16 + 255) / 256, 256, 0, stream>>>(
        Xl, rs, ci, epsv, l, (l > 0) ? 1 : 0, tscX, tshX, h0, NN);
    k_gemm<128, 256><<<NB, 512, 0, stream>>>(
        h0, 0, nullptr, nullptr, W1t + (size_t)l * 256 * 128,
        b1 + (size_t)l * 256, h1, psum, psq, NN);
    k_finred<<<256, 256, 0, stream>>>(psum, psq, NB, 256, g1 + (size_t)l * 256,
                                      be1 + (size_t)l * 256, tsc1, tsh1, 1.0f / NN);
    k_gemm<256, 128><<<NB, 512, 0, stream>>>(
        h1, 1, tsc1, tsh1, W2t + (size_t)l * 128 * 256,
        b2 + (size_t)l * 128, xp, psum, psq, NN);
    k_finred<<<128, 256, 0, stream>>>(psum, psq, NB, 128, gbn + (size_t)l * 128,
                                      bbn + (size_t)l * 128, tscX, tshX, 1.0f / NN);
  }

  k_pool<<<GG, 512, 0, stream>>>(xp, batch, tscX, tshX, zbuf, NN);
  k_cls1<<<GG, 128, 0, stream>>>(zbuf, cW1, cb1, z1);
  k_statz<<<128, 256, 0, stream>>>(z1, cg, cbeta, tscX, tshX);
  k_cls2<<<GG, 128, 0, stream>>>(z1, tscX, tshX, cW2, cb2, cW3, cb3, out);
}

// Round 3
// 825.829 us; speedup vs baseline: 1.0447x; 1.0447x over previous
//
#include <hip/hip_runtime.h>
#include <cstdint>
#include <cstddef>

// Problem constants (fixed by the reference setup_inputs).
#define NN 100000
#define EE 500000
#define DD 128
#define GG 512
#define LL 4
#define BN_EPS 1e-5f

typedef __attribute__((ext_vector_type(8))) short short8;
typedef __attribute__((ext_vector_type(8))) unsigned short ushort8v;
typedef __attribute__((ext_vector_type(4))) float f32x4;

static __device__ __forceinline__ unsigned short f2bf(float f) {
  union { float f; unsigned u; } v;
  v.f = f;
  unsigned r = v.u + 0x7fffu + ((v.u >> 16) & 1u);  // RNE
  return (unsigned short)(r >> 16);
}
static __device__ __forceinline__ float bf2f(unsigned short u) {
  union { unsigned u; float f; } v;
  v.u = ((unsigned)u) << 16;
  return v.f;
}

// ---------------- CSR build (int32 inputs) ----------------

__global__ void k_hist(const int* __restrict__ ei, int* __restrict__ cnt) {
  int e = blockIdx.x * 256 + threadIdx.x;
  if (e < EE) {
    int d = ei[EE + e];
    if (d >= 0 && d < NN) atomicAdd(&cnt[d], 1);
  }
}

__global__ void k_part(const int* __restrict__ cnt, int* __restrict__ part) {
  __shared__ int sm[1024];
  int t = threadIdx.x;
  int i = blockIdx.x * 1024 + t;
  sm[t] = (i < NN) ? cnt[i] : 0;
  __syncthreads();
  for (int off = 512; off > 0; off >>= 1) {
    if (t < off) sm[t] += sm[t + off];
    __syncthreads();
  }
  if (t == 0) part[blockIdx.x] = sm[0];
}

__global__ void k_scanpart(const int* __restrict__ part, int* __restrict__ partx, int nb) {
  __shared__ int sm[128];
  int t = threadIdx.x;
  int v = (t < nb) ? part[t] : 0;
  sm[t] = v;
  __syncthreads();
  for (int off = 1; off < 128; off <<= 1) {
    int u = (t >= off) ? sm[t - off] : 0;
    __syncthreads();
    sm[t] += u;
    __syncthreads();
  }
  if (t < nb) partx[t] = sm[t] - v;
}

__global__ void k_rs(const int* __restrict__ cnt, const int* __restrict__ partx,
                     int* __restrict__ rs, int* __restrict__ cur) {
  __shared__ int sm[1024];
  int t = threadIdx.x;
  int i = blockIdx.x * 1024 + t;
  int v = (i < NN) ? cnt[i] : 0;
  sm[t] = v;
  __syncthreads();
  for (int off = 1; off < 1024; off <<= 1) {
    int u = (t >= off) ? sm[t - off] : 0;
    __syncthreads();
    sm[t] += u;
    __syncthreads();
  }
  if (i < NN) {
    int excl = partx[blockIdx.x] + sm[t] - v;
    rs[i] = excl;
    cur[i] = excl;
    if (i == NN - 1) rs[NN] = excl + v;
  }
}

__global__ void k_fill(const int* __restrict__ ei, int* __restrict__ cur,
                       int* __restrict__ ci) {
  int e = blockIdx.x * 256 + threadIdx.x;
  if (e < EE) {
    int s = ei[e];
    int d = ei[EE + e];
    if (d >= 0 && d < NN && s >= 0 && s < NN) {
      int pos = atomicAdd(&cur[d], 1);
      if (pos >= 0 && pos < EE) ci[pos] = s;  // order irrelevant (sum)
    }
  }
}

// ---------------- weight convert: W -> W^T in bf16, once per call ----------------

__global__ void k_conv(const float* __restrict__ W1, const float* __restrict__ W2,
                       unsigned short* __restrict__ W1t, unsigned short* __restrict__ W2t) {
  int idx = blockIdx.x * 256 + threadIdx.x;
  if (idx < 4 * 256 * 128) {
    {  // W1: [l][k][nc] (K=128,NC=256) -> [l][nc][k]
      int l = idx >> 15, rem = idx & 32767;
      int nc = rem >> 7, k = rem & 127;
      W1t[idx] = f2bf(W1[(l << 15) + k * 256 + nc]);
    }
    {  // W2: [l][k][nc] (K=256,NC=128) -> [l][nc][k]
      int l = idx >> 15, rem = idx & 32767;
      int nc = rem >> 8, k = rem & 255;
      W2t[idx] = f2bf(W2[(l << 15) + k * 128 + nc]);
    }
  }
}

// ---------------- x -> bf16 convert (streaming, once per call) ----------------

__global__ void k_x2bf(const float* __restrict__ x, unsigned short* __restrict__ xb) {
  int i = blockIdx.x * 256 + threadIdx.x;
  if (i < NN * DD / 4) {
    float4 v = *(const float4*)(x + (size_t)i * 4);
    ushort4 o;
    o.x = f2bf(v.x); o.y = f2bf(v.y); o.z = f2bf(v.z); o.w = f2bf(v.w);
    *(ushort4*)(xb + (size_t)i * 4) = o;
  }
}

// ---------------- aggregation: bf16 X in (opt. BN/ReLU), bf16 h0 out ----
// 16 lanes/node, ushort8 (16B) loads, 1-deep neighbor prefetch.

__global__ __launch_bounds__(256) void k_agg_bf16(
    const unsigned short* __restrict__ X, const int* __restrict__ rs,
    const int* __restrict__ ci, const float* __restrict__ epsv, int l, int mode,
    const float* __restrict__ tsc, const float* __restrict__ tsh,
    unsigned short* __restrict__ h0, int n) {
  int idx = blockIdx.x * 256 + threadIdx.x;
  int node = idx >> 4;
  int c8 = (idx & 15) << 3;
  if (node >= n) return;
  float sa[8], sb[8];
  if (mode) {
    float4 a0 = *(const float4*)(tsc + c8), a1 = *(const float4*)(tsc + c8 + 4);
    float4 b0 = *(const float4*)(tsh + c8), b1 = *(const float4*)(tsh + c8 + 4);
    sa[0] = a0.x; sa[1] = a0.y; sa[2] = a0.z; sa[3] = a0.w;
    sa[4] = a1.x; sa[5] = a1.y; sa[6] = a1.z; sa[7] = a1.w;
    sb[0] = b0.x; sb[1] = b0.y; sb[2] = b0.z; sb[3] = b0.w;
    sb[4] = b1.x; sb[5] = b1.y; sb[6] = b1.z; sb[7] = b1.w;
  }
  float se = 1.f + epsv[l];
  ushort8v v = *(const ushort8v*)(X + (size_t)node * DD + c8);
  float acc[8];
#pragma unroll
  for (int j = 0; j < 8; ++j) {
    float f = bf2f(v[j]);
    if (mode) f = fmaxf(0.f, f * sa[j] + sb[j]);
    acc[j] = se * f;
  }
  int e0 = rs[node], e1 = rs[node + 1];
  ushort8v un;
  if (e0 < e1) un = *(const ushort8v*)(X + (size_t)ci[e0] * DD + c8);
  for (int e = e0; e < e1; ++e) {
    ushort8v uc = un;
    if (e + 1 < e1) un = *(const ushort8v*)(X + (size_t)ci[e + 1] * DD + c8);
#pragma unroll
    for (int j = 0; j < 8; ++j) {
      float f = bf2f(uc[j]);
      if (mode) f = fmaxf(0.f, f * sa[j] + sb[j]);
      acc[j] += f;
    }
  }
  ushort8v o;
#pragma unroll
  for (int j = 0; j < 8; ++j) o[j] = f2bf(acc[j]);
  *(ushort8v*)(h0 + (size_t)node * DD + c8) = o;
}

// ---------------- M2 = h0^T h0 (128x128) + colsum(h0), for analytic BN1 stats ----
// Per block: 256-row chunk of h0 staged TRANSPOSED into LDS (Ht[c][n]).
// HT=264 ushorts = 528 B: 16B-aligned rows (ds_read_b128 legal) and 132-dword
// stride (%32==4) -> MFMA fragment reads only 2-way bank-aliased (free).
// Wave w owns M2 rows w*16..+15, contraction over n via ds_read_b128. 8 output
// slabs (blockIdx&7) cut global-atomic contention 8x; k_red folds slabs.

__global__ __launch_bounds__(512) void k_mom(
    const unsigned short* __restrict__ h0, float* __restrict__ M2s,
    float* __restrict__ css, int n) {
  constexpr int HT = 264;
  __shared__ __align__(16) unsigned short Ht[128 * HT];  // 67584 B
  __shared__ float lcs[128];
  int tid = threadIdx.x;
  int lane = tid & 63, wave = tid >> 6;
  int quad = lane >> 4, l15 = lane & 15;
  int n0 = blockIdx.x * 256;
  if (tid < 128) lcs[tid] = 0.f;
  int c8 = (tid & 15) << 3;
  int rloc = tid >> 4;  // 0..31
  float csr[8];
#pragma unroll
  for (int j = 0; j < 8; ++j) csr[j] = 0.f;
  __syncthreads();  // lcs zeroed
#pragma unroll
  for (int pass = 0; pass < 8; ++pass) {
    int nl = rloc + pass * 32;  // 0..255
    int gr = n0 + nl;
    ushort8v v = (ushort8v){0, 0, 0, 0, 0, 0, 0, 0};
    if (gr < n) v = *(const ushort8v*)(h0 + (size_t)gr * DD + c8);
#pragma unroll
    for (int j = 0; j < 8; ++j) {
      Ht[(c8 + j) * HT + nl] = v[j];  // transpose: scalar b16 writes
      csr[j] += bf2f(v[j]);
    }
  }
#pragma unroll
  for (int j = 0; j < 8; ++j) atomicAdd(&lcs[c8 + j], csr[j]);
  __syncthreads();
  f32x4 acc[8];
#pragma unroll
  for (int j = 0; j < 8; ++j) acc[j] = (f32x4){0.f, 0.f, 0.f, 0.f};
#pragma unroll
  for (int kc = 0; kc < 8; ++kc) {
    int ko = kc * 32 + quad * 8;
    short8 av = *(const short8*)(&Ht[(wave * 16 + l15) * HT + ko]);
#pragma unroll
    for (int j = 0; j < 8; ++j) {
      short8 bv = *(const short8*)(&Ht[(j * 16 + l15) * HT + ko]);
      acc[j] = __builtin_amdgcn_mfma_f32_16x16x32_bf16(av, bv, acc[j], 0, 0, 0);
    }
  }
  int slab = blockIdx.x & 7;
  float* M2 = M2s + (size_t)slab * (128 * 128);
  int lr = wave * 16 + quad * 4;
#pragma unroll
  for (int j = 0; j < 8; ++j)
#pragma unroll
    for (int reg = 0; reg < 4; ++reg)
      atomicAdd(&M2[(lr + reg) * 128 + j * 16 + l15], acc[j][reg]);
  if (tid < 128) atomicAdd(&css[slab * 128 + tid], lcs[tid]);
}

// fold the 8 slabs
__global__ void k_red(const float* __restrict__ M2s, const float* __restrict__ css,
                      float* __restrict__ M2f, float* __restrict__ csf) {
  int i = blockIdx.x * 256 + threadIdx.x;  // 64 blocks -> 16384
  float s = 0.f;
#pragma unroll
  for (int k = 0; k < 8; ++k) s += M2s[(size_t)k * 16384 + i];
  M2f[i] = s;
  if (i < 128) {
    float c = 0.f;
#pragma unroll
    for (int k = 0; k < 8; ++k) c += css[k * 128 + i];
    csf[i] = c;
  }
}

// analytic BN1 scale/shift: var_c = w^T M2 w / N - (colsum.w/N)^2  (b1 cancels)
__global__ __launch_bounds__(128) void k_bn1(
    const float* __restrict__ M2, const float* __restrict__ cs,
    const unsigned short* __restrict__ W1t_l, const float* __restrict__ g1_l,
    const float* __restrict__ be1_l, float* __restrict__ osc,
    float* __restrict__ osh) {
  __shared__ float wsh[128];
  __shared__ float red1[2], red2[2];
  int c = blockIdx.x, t = threadIdx.x;
  float w = bf2f(W1t_l[c * 128 + t]);
  wsh[t] = w;
  __syncthreads();
  float inner = 0.f;
#pragma unroll 4
  for (int k = 0; k < 128; ++k) inner = fmaf(M2[t * 128 + k], wsh[k], inner);
  float s1 = w * inner;
  float s2 = w * cs[t];
#pragma unroll
  for (int off = 32; off > 0; off >>= 1) {
    s1 += __shfl_xor(s1, off, 64);
    s2 += __shfl_xor(s2, off, 64);
  }
  if ((t & 63) == 0) { red1[t >> 6] = s1; red2[t >> 6] = s2; }
  __syncthreads();
  if (t == 0) {
    float q = (red1[0] + red1[1]) * (1.0f / NN);
    float um = (red2[0] + red2[1]) * (1.0f / NN);
    float var = fmaxf(q - um * um, 0.f);
    float sc = g1_l[c] * rsqrtf(var + BN_EPS);
    osc[c] = sc;
    osh[c] = be1_l[c] - um * sc;
  }
}

// ---------------- fused GEMM1+BN1+ReLU+GEMM2 (round-0 phased skeleton) ----------
// 128 rows/block, 8 waves x 16 rows, 8 phases with register-prefetch pipeline
// (phase p+1's global loads issued before phase p's MFMAs). Stage 1 (P0-P1,P4-P5):
// h0 @ W1 colgroup -> BN1(analytic sc/sh)+ReLU -> H (LDS bf16, never HBM).
// Stage 2 (P2-P3,P6-P7): acc2 += H-half @ W2 k-slice (A-frags straight from LDS,
// W2 16KB tiles staged). One epilogue: +b2, BN2 partial stats, coalesced C store.

__global__ __launch_bounds__(512, 4) void k_gfused(
    const unsigned short* __restrict__ A, const float* __restrict__ sc1,
    const float* __restrict__ sh1, const unsigned short* __restrict__ W1t_l,
    const unsigned short* __restrict__ W2t_l, const float* __restrict__ b2_l,
    unsigned short* __restrict__ C, float* __restrict__ psum,
    float* __restrict__ psq, int n) {
  constexpr int AST = 72;   // stage row stride (ushorts), 144B -> bank-offset 4
  constexpr int HP = 136;   // H / Ct row stride (ushorts), 272B -> bank-offset 4
  __shared__ __align__(16) unsigned short smem[2 * 128 * AST];  // Asm,Bsm / Ct
  __shared__ __align__(16) unsigned short H[128 * HP];          // 34816 B
  __shared__ float bsum[128], bsq[128];
  unsigned short* Asm = smem;
  unsigned short* Bsm = smem + 128 * AST;

  int tid = threadIdx.x;
  int lane = tid & 63, wave = tid >> 6;
  int quad = lane >> 4, l15 = lane & 15;
  int row0 = blockIdx.x * 128;

  ushort8v pa[2], pb[2];
  f32x4 acc1[8], acc2[8];
#pragma unroll
  for (int j = 0; j < 8; ++j) acc2[j] = (f32x4){0.f, 0.f, 0.f, 0.f};

#define LOADS1(cg, kc)                                                         \
  {                                                                            \
    _Pragma("unroll") for (int it = 0; it < 2; ++it) {                         \
      int f = tid + it * 512, rr = f >> 3, c8 = (f & 7) << 3;                  \
      int gr = row0 + rr;                                                      \
      pa[it] = (ushort8v){0, 0, 0, 0, 0, 0, 0, 0};                             \
      if (gr < n)                                                              \
        pa[it] = *(const ushort8v*)(A + (size_t)gr * 128 + (kc)*64 + c8);      \
      pb[it] = *(const ushort8v*)(W1t_l +                                      \
                                  (size_t)((cg)*128 + rr) * 128 + (kc)*64 + c8); \
    }                                                                          \
  }
#define LOADS2(kc2)                                                            \
  {                                                                            \
    _Pragma("unroll") for (int it = 0; it < 2; ++it) {                         \
      int f = tid + it * 512, rr = f >> 3, c8 = (f & 7) << 3;                  \
      pb[it] = *(const ushort8v*)(W2t_l + (size_t)rr * 256 + (kc2)*64 + c8);   \
    }                                                                          \
  }
#define WRITES1                                                                \
  {                                                                            \
    _Pragma("unroll") for (int it = 0; it < 2; ++it) {                         \
      int f = tid + it * 512, rr = f >> 3, c8 = (f & 7) << 3;                  \
      *(ushort8v*)(&Asm[rr * AST + c8]) = pa[it];                              \
      *(ushort8v*)(&Bsm[rr * AST + c8]) = pb[it];                              \
    }                                                                          \
  }
#define WRITES2                                                                \
  {                                                                            \
    _Pragma("unroll") for (int it = 0; it < 2; ++it) {                         \
      int f = tid + it * 512, rr = f >> 3, c8 = (f & 7) << 3;                  \
      *(ushort8v*)(&Bsm[rr * AST + c8]) = pb[it];                              \
    }                                                                          \
  }
#define ZERO1                                                                  \
  {                                                                            \
    _Pragma("unroll") for (int j = 0; j < 8; ++j)                              \
        acc1[j] = (f32x4){0.f, 0.f, 0.f, 0.f};                                 \
  }
#define MFMAS1                                                                 \
  {                                                                            \
    _Pragma("unroll") for (int kk = 0; kk < 64; kk += 32) {                    \
      int ko = kk + quad * 8;                                                  \
      short8 av = *(const short8*)(&Asm[(wave * 16 + l15) * AST + ko]);        \
      _Pragma("unroll") for (int cf = 0; cf < 8; ++cf) {                       \
        short8 bv = *(const short8*)(&Bsm[(cf * 16 + l15) * AST + ko]);        \
        acc1[cf] =                                                             \
            __builtin_amdgcn_mfma_f32_16x16x32_bf16(av, bv, acc1[cf], 0, 0, 0); \
      }                                                                        \
    }                                                                          \
  }
#define MFMAS2(half)                                                           \
  {                                                                            \
    _Pragma("unroll") for (int kk = 0; kk < 64; kk += 32) {                    \
      int ko = kk + quad * 8;                                                  \
      short8 av =                                                              \
          *(const short8*)(&H[(wave * 16 + l15) * HP + (half)*64 + ko]);       \
      _Pragma("unroll") for (int cf = 0; cf < 8; ++cf) {                       \
        short8 bv = *(const short8*)(&Bsm[(cf * 16 + l15) * AST + ko]);        \
        acc2[cf] =                                                             \
            __builtin_amdgcn_mfma_f32_16x16x32_bf16(av, bv, acc2[cf], 0, 0, 0); \
      }                                                                        \
    }                                                                          \
  }
#define EPI1(cg)                                                               \
  {                                                                            \
    int lrb = wave * 16 + quad * 4;                                            \
    _Pragma("unroll") for (int cf = 0; cf < 8; ++cf) {                         \
      int col = (cg)*128 + cf * 16 + l15;                                      \
      float sc = sc1[col], sh = sh1[col];                                      \
      _Pragma("unroll") for (int reg = 0; reg < 4; ++reg)                      \
          H[(lrb + reg) * HP + cf * 16 + l15] =                                \
              f2bf(fmaxf(0.f, acc1[cf][reg] * sc + sh));                       \
    }                                                                          \
  }

  LOADS1(0, 0)
  // P0: GEMM1 cg0 kc0
  WRITES1 __syncthreads();
  LOADS1(0, 1) ZERO1 MFMAS1 __syncthreads();
  // P1: GEMM1 cg0 kc1 -> h1 cols 0..127 into H
  WRITES1 __syncthreads();
  LOADS2(0) MFMAS1 EPI1(0) __syncthreads();
  // P2: GEMM2 k-slice 0 (h1 cols 0..63)
  WRITES2 __syncthreads();
  LOADS2(1) MFMAS2(0) __syncthreads();
  // P3: GEMM2 k-slice 1 (h1 cols 64..127)
  WRITES2 __syncthreads();
  LOADS1(1, 0) MFMAS2(1) __syncthreads();
  // P4: GEMM1 cg1 kc0
  WRITES1 __syncthreads();
  LOADS1(1, 1) ZERO1 MFMAS1 __syncthreads();
  // P5: GEMM1 cg1 kc1 -> h1 cols 128..255 into H
  WRITES1 __syncthreads();
  LOADS2(2) MFMAS1 EPI1(1) __syncthreads();
  // P6: GEMM2 k-slice 2
  WRITES2 __syncthreads();
  LOADS2(3) MFMAS2(0) __syncthreads();
  // P7: GEMM2 k-slice 3
  WRITES2 __syncthreads();
  MFMAS2(1)

  // ---- final epilogue: +b2, BN2 partial stats, coalesced C store ----
  __syncthreads();  // all LDS reads done; smem reusable as Ct
  unsigned short* Ct = smem;
  if (tid < 128) { bsum[tid] = 0.f; bsq[tid] = 0.f; }
  float s8[8], q8[8];
#pragma unroll
  for (int j = 0; j < 8; ++j) { s8[j] = 0.f; q8[j] = 0.f; }
  int lrbase = wave * 16 + quad * 4;
#pragma unroll
  for (int cf = 0; cf < 8; ++cf) {
    float bv = b2_l[cf * 16 + l15];
#pragma unroll
    for (int reg = 0; reg < 4; ++reg) {
      int lr = lrbase + reg;
      float e = acc2[cf][reg] + bv;
      Ct[lr * HP + cf * 16 + l15] = f2bf(e);
      if (row0 + lr < n) { s8[cf] += e; q8[cf] += e * e; }
    }
  }
#pragma unroll
  for (int cf = 0; cf < 8; ++cf) {
    s8[cf] += __shfl_xor(s8[cf], 16, 64);
    s8[cf] += __shfl_xor(s8[cf], 32, 64);
    q8[cf] += __shfl_xor(q8[cf], 16, 64);
    q8[cf] += __shfl_xor(q8[cf], 32, 64);
  }
  __syncthreads();  // Ct complete; bsum zeroed
  if (quad == 0) {
#pragma unroll
    for (int cf = 0; cf < 8; ++cf) {
      atomicAdd(&bsum[cf * 16 + l15], s8[cf]);
      atomicAdd(&bsq[cf * 16 + l15], q8[cf]);
    }
  }
#pragma unroll
  for (int it = 0; it < 4; ++it) {
    int f = tid + it * 512;
    int r = f >> 4, c8 = (f & 15) << 3;
    int gr = row0 + r;
    if (gr < n)
      *(ushort8v*)(C + (size_t)gr * 128 + c8) = *(const ushort8v*)(&Ct[r * HP + c8]);
  }
  __syncthreads();
  if (tid < 128) {
    psum[(size_t)blockIdx.x * 128 + tid] = bsum[tid];
    psq[(size_t)blockIdx.x * 128 + tid] = bsq[tid];
  }
#undef LOADS1
#undef LOADS2
#undef WRITES1
#undef WRITES2
#undef ZERO1
#undef MFMAS1
#undef MFMAS2
#undef EPI1
}

// ---------------- column-stat reduce + BN finalize (one block per column) --------

__global__ __launch_bounds__(256) void k_finred(
    const float* __restrict__ psum, const float* __restrict__ psq, int nb, int nc,
    const float* __restrict__ g, const float* __restrict__ be,
    float* __restrict__ osc, float* __restrict__ osh, float invn) {
  __shared__ float ws[4], wq[4];
  int col = blockIdx.x;
  int t = threadIdx.x;
  float s = 0.f, q = 0.f;
  for (int b = t; b < nb; b += 256) {
    s += psum[(size_t)b * nc + col];
    q += psq[(size_t)b * nc + col];
  }
#pragma unroll
  for (int off = 32; off > 0; off >>= 1) {
    s += __shfl_xor(s, off, 64);
    q += __shfl_xor(q, off, 64);
  }
  if ((t & 63) == 0) { ws[t >> 6] = s; wq[t >> 6] = q; }
  __syncthreads();
  if (t == 0) {
    s = ws[0] + ws[1] + ws[2] + ws[3];
    q = wq[0] + wq[1] + wq[2] + wq[3];
    float m = s * invn;
    float v = fmaxf(q * invn - m * m, 0.f);
    float sc = g[col] * rsqrtf(v + BN_EPS);
    osc[col] = sc;
    osh[col] = be[col] - m * sc;
  }
}

// ---------------- classifier z1 stats (sum & sumsq from one array) ----------------

__global__ __launch_bounds__(256) void k_statz(
    const float* __restrict__ z1, const float* __restrict__ g,
    const float* __restrict__ be, float* __restrict__ osc, float* __restrict__ osh) {
  __shared__ float ws[4], wq[4];
  int col = blockIdx.x;
  int t = threadIdx.x;
  float s = 0.f, q = 0.f;
  for (int b = t; b < GG; b += 256) {
    float v = z1[(size_t)b * 128 + col];
    s += v;
    q += v * v;
  }
#pragma unroll
  for (int off = 32; off > 0; off >>= 1) {
    s += __shfl_xor(s, off, 64);
    q += __shfl_xor(q, off, 64);
  }
  if ((t & 63) == 0) { ws[t >> 6] = s; wq[t >> 6] = q; }
  __syncthreads();
  if (t == 0) {
    s = ws[0] + ws[1] + ws[2] + ws[3];
    q = wq[0] + wq[1] + wq[2] + wq[3];
    float m = s / (float)GG;
    float v = fmaxf(q / (float)GG - m * m, 0.f);
    float sc = g[col] * rsqrtf(v + BN_EPS);
    osc[col] = sc;
    osh[col] = be[col] - m * sc;
  }
}

// ---------------- pooling (batch sorted -> contiguous ranges), bf16 X ------------

static __device__ __forceinline__ int lb_i32(const int* a, int n, int key) {
  int lo = 0, hi = n;
  while (lo < hi) {
    int mid = (lo + hi) >> 1;
    if (a[mid] < key) lo = mid + 1; else hi = mid;
  }
  return lo;
}

__global__ __launch_bounds__(512) void k_pool(
    const unsigned short* __restrict__ X, const int* __restrict__ batch,
    const float* __restrict__ tsc, const float* __restrict__ tsh,
    float* __restrict__ z, int n) {
  __shared__ int slo, shi;
  __shared__ float ssum[8][128], smax[8][128];
  int g = blockIdx.x;
  int t = threadIdx.x;
  int sg = t >> 6;           // 0..7 row-subgroup
  int c2 = (t & 63) << 1;    // column pair base
  if (t == 0) {
    slo = lb_i32(batch, n, g);
    shi = lb_i32(batch, n, g + 1);
  }
  __syncthreads();
  int lo = slo, hi = shi;
  float a0 = tsc[c2], a1 = tsc[c2 + 1];
  float b0 = tsh[c2], b1 = tsh[c2 + 1];
  float s0 = 0.f, s1 = 0.f;
  float m0 = -3.402823466e38f, m1 = -3.402823466e38f;
  for (int i = lo + sg; i < hi; i += 8) {
    unsigned u = *(const unsigned*)(X + (size_t)i * DD + c2);
    float v0 = fmaxf(0.f, bf2f((unsigned short)(u & 0xffff)) * a0 + b0);
    float v1 = fmaxf(0.f, bf2f((unsigned short)(u >> 16)) * a1 + b1);
    s0 += v0; m0 = fmaxf(m0, v0);
    s1 += v1; m1 = fmaxf(m1, v1);
  }
  ssum[sg][c2] = s0; ssum[sg][c2 + 1] = s1;
  smax[sg][c2] = m0; smax[sg][c2 + 1] = m1;
  __syncthreads();
  if (t < 128) {
    float S = 0.f, M = -3.402823466e38f;
#pragma unroll
    for (int k = 0; k < 8; ++k) {
      S += ssum[k][t];
      M = fmaxf(M, smax[k][t]);
    }
    float cntf = (float)(hi - lo);
    z[(size_t)g * 384 + t] = S;
    z[(size_t)g * 384 + 128 + t] = S / fmaxf(cntf, 1.f);
    z[(size_t)g * 384 + 256 + t] = M;
  }
}

// ---------------- classifier head (fp32, tiny; no atomics) ----------------

__global__ void k_cls1(const float* __restrict__ z, const float* __restrict__ cW1,
                       const float* __restrict__ cb1, float* __restrict__ z1) {
  __shared__ float zr[384];
  int g = blockIdx.x;
  int c = threadIdx.x;  // 128
  for (int i = c; i < 384; i += 128) zr[i] = z[(size_t)g * 384 + i];
  __syncthreads();
  float s = cb1[c];
#pragma unroll 4
  for (int k = 0; k < 384; ++k) s = fmaf(zr[k], cW1[(size_t)k * 128 + c], s);
  z1[(size_t)g * 128 + c] = s;
}

__global__ void k_cls2(const float* __restrict__ z1, const float* __restrict__ csc,
                       const float* __restrict__ csh, const float* __restrict__ cW2,
                       const float* __restrict__ cb2, const float* __restrict__ cW3,
                       const float* __restrict__ cb3, float* __restrict__ out) {
  __shared__ float z1n[128];
  __shared__ float z2s[64];
  int g = blockIdx.x;
  int t = threadIdx.x;  // 128
  z1n[t] = fmaxf(0.f, z1[(size_t)g * 128 + t] * csc[t] + csh[t]);
  __syncthreads();
  if (t < 64) {
    float s = cb2[t];
#pragma unroll 4
    for (int k = 0; k < 128; ++k) s = fmaf(z1n[k], cW2[(size_t)k * 64 + t], s);
    z2s[t] = fmaxf(0.f, s);
  }
  __syncthreads();
  if (t < 2) {
    float s = cb3[t];
#pragma unroll 4
    for (int c = 0; c < 64; ++c) s = fmaf(z2s[c], cW3[(size_t)c * 2 + t], s);
    out[(size_t)g * 2 + t] = s;
  }
}

// ---------------- launch ----------------

extern "C" void kernel_launch(void* const* d_in, const int* in_sizes, int n_in,
                              void* d_out, int out_size, void* d_ws, size_t ws_size,
                              hipStream_t stream) {
  const float* x = (const float*)d_in[0];
  const int* ei = (const int*)d_in[1];     // int32 (harness downcasts int64)
  const int* batch = (const int*)d_in[2];  // int32
  const float* W1 = (const float*)d_in[4];
  const float* b1 = (const float*)d_in[5];
  const float* g1 = (const float*)d_in[6];
  const float* be1 = (const float*)d_in[7];
  const float* W2 = (const float*)d_in[8];
  const float* b2 = (const float*)d_in[9];
  const float* gbn = (const float*)d_in[10];
  const float* bbn = (const float*)d_in[11];
  const float* epsv = (const float*)d_in[12];
  const float* cW1 = (const float*)d_in[13];
  const float* cb1 = (const float*)d_in[14];
  const float* cg = (const float*)d_in[15];
  const float* cbeta = (const float*)d_in[16];
  const float* cW2 = (const float*)d_in[17];
  const float* cb2 = (const float*)d_in[18];
  const float* cW3 = (const float*)d_in[19];
  const float* cb3 = (const float*)d_in[20];
  float* out = (float*)d_out;
  (void)b1;  // BN1 shift is independent of b1 (cancels in (y - mean))

  char* p = (char*)d_ws;
  auto alloc = [&](size_t bytes) {
    char* r = p;
    p += (bytes + 255) & ~(size_t)255;
    return r;
  };
  const int NB = (NN + 127) / 128;  // 782 GEMM row-blocks
  const int NMOM = (NN + 255) / 256;  // 391 moment blocks
  int* cnt = (int*)alloc((size_t)NN * 4);
  int* rs = (int*)alloc((size_t)(NN + 1) * 4);
  int* cur = (int*)alloc((size_t)NN * 4);
  int* ci = (int*)alloc((size_t)EE * 4);
  int* part = (int*)alloc(128 * 4);
  int* partx = (int*)alloc(128 * 4);
  unsigned short* xbf = (unsigned short*)alloc((size_t)NN * DD * 2);
  unsigned short* h0 = (unsigned short*)alloc((size_t)NN * DD * 2);
  unsigned short* xp = (unsigned short*)alloc((size_t)NN * DD * 2);
  float* psum = (float*)alloc((size_t)NB * 128 * 4);
  float* psq = (float*)alloc((size_t)NB * 128 * 4);
  float* tsc1 = (float*)alloc(256 * 4);
  float* tsh1 = (float*)alloc(256 * 4);
  float* tscX = (float*)alloc(128 * 4);
  float* tshX = (float*)alloc(128 * 4);
  float* zbuf = (float*)alloc((size_t)GG * 384 * 4);
  float* z1 = (float*)alloc((size_t)GG * 128 * 4);
  unsigned short* W1t = (unsigned short*)alloc((size_t)4 * 256 * 128 * 2);
  unsigned short* W2t = (unsigned short*)alloc((size_t)4 * 128 * 256 * 2);
  float* mz = (float*)alloc((size_t)(8 * 128 * 128 + 8 * 128) * 4);  // slabs
  float* M2s = mz;
  float* css = mz + 8 * 128 * 128;
  float* M2f = (float*)alloc((size_t)128 * 128 * 4);
  float* csf = (float*)alloc(128 * 4);
  (void)ws_size; (void)n_in; (void)in_sizes; (void)out_size;

  // weight convert+transpose to bf16 (static across layers/calls)
  k_conv<<<512, 256, 0, stream>>>(W1, W2, W1t, W2t);
  // x -> bf16
  k_x2bf<<<(NN * DD / 4 + 255) / 256, 256, 0, stream>>>(x, xbf);

  // CSR build (edges static across layers)
  hipMemsetAsync(cnt, 0, (size_t)NN * 4, stream);
  k_hist<<<(EE + 255) / 256, 256, 0, stream>>>(ei, cnt);
  const int nscan = (NN + 1023) / 1024;  // 98
  k_part<<<nscan, 1024, 0, stream>>>(cnt, part);
  k_scanpart<<<1, 128, 0, stream>>>(part, partx, nscan);
  k_rs<<<nscan, 1024, 0, stream>>>(cnt, partx, rs, cur);
  k_fill<<<(EE + 255) / 256, 256, 0, stream>>>(ei, cur, ci);

  for (int l = 0; l < LL; ++l) {
    const unsigned short* Xl = (l == 0) ? xbf : xp;
    k_agg_bf16<<<(NN * 16 + 255) / 256, 256, 0, stream>>>(
        Xl, rs, ci, epsv, l, (l > 0) ? 1 : 0, tscX, tshX, h0, NN);
    // analytic BN1 stats: M2 = h0^T h0 (8 slabs), colsum; fold; scale/shift
    hipMemsetAsync(mz, 0, (size_t)(8 * 128 * 128 + 8 * 128) * 4, stream);
    k_mom<<<NMOM, 512, 0, stream>>>(h0, M2s, css, NN);
    k_red<<<64, 256, 0, stream>>>(M2s, css, M2f, csf);
    k_bn1<<<256, 128, 0, stream>>>(M2f, csf, W1t + (size_t)l * 256 * 128,
                                   g1 + (size_t)l * 256, be1 + (size_t)l * 256,
                                   tsc1, tsh1);
    // fused GEMM1+BN1+ReLU+GEMM2 (h1 never touches HBM)
    k_gfused<<<NB, 512, 0, stream>>>(
        h0, tsc1, tsh1, W1t + (size_t)l * 256 * 128, W2t + (size_t)l * 128 * 256,
        b2 + (size_t)l * 128, xp, psum, psq, NN);
    k_finred<<<128, 256, 0, stream>>>(psum, psq, NB, 128, gbn + (size_t)l * 128,
                                      bbn + (size_t)l * 128, tscX, tshX, 1.0f / NN);
  }

  k_pool<<<GG, 512, 0, stream>>>(xp, batch, tscX, tshX, zbuf, NN);
  k_cls1<<<GG, 128, 0, stream>>>(zbuf, cW1, cb1, z1);
  k_statz<<<128, 256, 0, stream>>>(z1, cg, cbeta, tscX, tshX);
  k_cls2<<<GG, 128, 0, stream>>>(z1, tscX, tshX, cW2, cb2, cW3, cb3, out);
}

// Round 4
// 754.838 us; speedup vs baseline: 1.1429x; 1.0940x over previous
//
#include <hip/hip_runtime.h>
#include <cstdint>
#include <cstddef>

// Problem constants (fixed by the reference setup_inputs).
#define NN 100000
#define EE 500000
#define DD 128
#define GG 512
#define LL 4
#define BN_EPS 1e-5f

typedef __attribute__((ext_vector_type(8))) short short8;
typedef __attribute__((ext_vector_type(8))) unsigned short ushort8v;
typedef __attribute__((ext_vector_type(4))) float f32x4;

static __device__ __forceinline__ unsigned short f2bf(float f) {
  union { float f; unsigned u; } v;
  v.f = f;
  unsigned r = v.u + 0x7fffu + ((v.u >> 16) & 1u);  // RNE
  return (unsigned short)(r >> 16);
}
static __device__ __forceinline__ float bf2f(unsigned short u) {
  union { unsigned u; float f; } v;
  v.u = ((unsigned)u) << 16;
  return v.f;
}

// ---------------- CSR build (int32 inputs) ----------------

__global__ void k_hist(const int* __restrict__ ei, int* __restrict__ cnt) {
  int e = blockIdx.x * 256 + threadIdx.x;
  if (e < EE) {
    int d = ei[EE + e];
    if (d >= 0 && d < NN) atomicAdd(&cnt[d], 1);
  }
}

__global__ void k_part(const int* __restrict__ cnt, int* __restrict__ part) {
  __shared__ int sm[1024];
  int t = threadIdx.x;
  int i = blockIdx.x * 1024 + t;
  sm[t] = (i < NN) ? cnt[i] : 0;
  __syncthreads();
  for (int off = 512; off > 0; off >>= 1) {
    if (t < off) sm[t] += sm[t + off];
    __syncthreads();
  }
  if (t == 0) part[blockIdx.x] = sm[0];
}

__global__ void k_scanpart(const int* __restrict__ part, int* __restrict__ partx, int nb) {
  __shared__ int sm[128];
  int t = threadIdx.x;
  int v = (t < nb) ? part[t] : 0;
  sm[t] = v;
  __syncthreads();
  for (int off = 1; off < 128; off <<= 1) {
    int u = (t >= off) ? sm[t - off] : 0;
    __syncthreads();
    sm[t] += u;
    __syncthreads();
  }
  if (t < nb) partx[t] = sm[t] - v;
}

__global__ void k_rs(const int* __restrict__ cnt, const int* __restrict__ partx,
                     int* __restrict__ rs, int* __restrict__ cur) {
  __shared__ int sm[1024];
  int t = threadIdx.x;
  int i = blockIdx.x * 1024 + t;
  int v = (i < NN) ? cnt[i] : 0;
  sm[t] = v;
  __syncthreads();
  for (int off = 1; off < 1024; off <<= 1) {
    int u = (t >= off) ? sm[t - off] : 0;
    __syncthreads();
    sm[t] += u;
    __syncthreads();
  }
  if (i < NN) {
    int excl = partx[blockIdx.x] + sm[t] - v;
    rs[i] = excl;
    cur[i] = excl;
    if (i == NN - 1) rs[NN] = excl + v;
  }
}

__global__ void k_fill(const int* __restrict__ ei, int* __restrict__ cur,
                       int* __restrict__ ci) {
  int e = blockIdx.x * 256 + threadIdx.x;
  if (e < EE) {
    int s = ei[e];
    int d = ei[EE + e];
    if (d >= 0 && d < NN && s >= 0 && s < NN) {
      int pos = atomicAdd(&cur[d], 1);
      if (pos >= 0 && pos < EE) ci[pos] = s;  // order irrelevant (sum)
    }
  }
}

// ---------------- weight convert: W -> W^T in bf16, once per call ----------------

__global__ void k_conv(const float* __restrict__ W1, const float* __restrict__ W2,
                       unsigned short* __restrict__ W1t, unsigned short* __restrict__ W2t) {
  int idx = blockIdx.x * 256 + threadIdx.x;
  if (idx < 4 * 256 * 128) {
    {  // W1: [l][k][nc] (K=128,NC=256) -> [l][nc][k]
      int l = idx >> 15, rem = idx & 32767;
      int nc = rem >> 7, k = rem & 127;
      W1t[idx] = f2bf(W1[(l << 15) + k * 256 + nc]);
    }
    {  // W2: [l][k][nc] (K=256,NC=128) -> [l][nc][k]
      int l = idx >> 15, rem = idx & 32767;
      int nc = rem >> 8, k = rem & 255;
      W2t[idx] = f2bf(W2[(l << 15) + k * 128 + nc]);
    }
  }
}

// ---------------- x -> bf16 convert (streaming, once per call) ----------------

__global__ void k_x2bf(const float* __restrict__ x, unsigned short* __restrict__ xb) {
  int i = blockIdx.x * 256 + threadIdx.x;
  if (i < NN * DD / 4) {
    float4 v = *(const float4*)(x + (size_t)i * 4);
    ushort4 o;
    o.x = f2bf(v.x); o.y = f2bf(v.y); o.z = f2bf(v.z); o.w = f2bf(v.w);
    *(ushort4*)(xb + (size_t)i * 4) = o;
  }
}

// ---------------- aggregation: bf16 X in (opt. BN/ReLU), bf16 h0 out ----
// 16 lanes/node, ushort8 (16B) loads, 1-deep neighbor prefetch.

__global__ __launch_bounds__(256) void k_agg_bf16(
    const unsigned short* __restrict__ X, const int* __restrict__ rs,
    const int* __restrict__ ci, const float* __restrict__ epsv, int l, int mode,
    const float* __restrict__ tsc, const float* __restrict__ tsh,
    unsigned short* __restrict__ h0, int n) {
  int idx = blockIdx.x * 256 + threadIdx.x;
  int node = idx >> 4;
  int c8 = (idx & 15) << 3;
  if (node >= n) return;
  float sa[8], sb[8];
  if (mode) {
    float4 a0 = *(const float4*)(tsc + c8), a1 = *(const float4*)(tsc + c8 + 4);
    float4 b0 = *(const float4*)(tsh + c8), b1 = *(const float4*)(tsh + c8 + 4);
    sa[0] = a0.x; sa[1] = a0.y; sa[2] = a0.z; sa[3] = a0.w;
    sa[4] = a1.x; sa[5] = a1.y; sa[6] = a1.z; sa[7] = a1.w;
    sb[0] = b0.x; sb[1] = b0.y; sb[2] = b0.z; sb[3] = b0.w;
    sb[4] = b1.x; sb[5] = b1.y; sb[6] = b1.z; sb[7] = b1.w;
  }
  float se = 1.f + epsv[l];
  ushort8v v = *(const ushort8v*)(X + (size_t)node * DD + c8);
  float acc[8];
#pragma unroll
  for (int j = 0; j < 8; ++j) {
    float f = bf2f(v[j]);
    if (mode) f = fmaxf(0.f, f * sa[j] + sb[j]);
    acc[j] = se * f;
  }
  int e0 = rs[node], e1 = rs[node + 1];
  ushort8v un;
  if (e0 < e1) un = *(const ushort8v*)(X + (size_t)ci[e0] * DD + c8);
  for (int e = e0; e < e1; ++e) {
    ushort8v uc = un;
    if (e + 1 < e1) un = *(const ushort8v*)(X + (size_t)ci[e + 1] * DD + c8);
#pragma unroll
    for (int j = 0; j < 8; ++j) {
      float f = bf2f(uc[j]);
      if (mode) f = fmaxf(0.f, f * sa[j] + sb[j]);
      acc[j] += f;
    }
  }
  ushort8v o;
#pragma unroll
  for (int j = 0; j < 8; ++j) o[j] = f2bf(acc[j]);
  *(ushort8v*)(h0 + (size_t)node * DD + c8) = o;
}

// ---------------- M2 = h0^T h0 (128x128) + colsum(h0), for analytic BN1 stats ----
// v2: 196 persistent blocks grid-stride over 391 chunks of 256 rows. M2 partial
// accumulates in REGISTERS across chunks; one non-atomic 64KB slab write per block
// (no global atomics, no memset). Transposed staging bank conflicts cut to ~4-way
// by an XOR block-swizzle at 8-element granularity: sb = (n>>3) ^ ((row>>3)&7);
// reads stay contiguous 16B (HT=264 -> 528B = 33x16, aligned).

__global__ __launch_bounds__(512) void k_mom(
    const unsigned short* __restrict__ h0, float* __restrict__ M2s,
    float* __restrict__ css, int n) {
  constexpr int HT = 264;
  constexpr int NCH = (NN + 255) / 256;  // 391
  constexpr int NBLK = 196;
  __shared__ __align__(16) unsigned short Ht[128 * HT];  // 67584 B
  __shared__ float lcs[128];
  int tid = threadIdx.x;
  int lane = tid & 63, wave = tid >> 6;
  int quad = lane >> 4, l15 = lane & 15;
  if (tid < 128) lcs[tid] = 0.f;
  int c8 = (tid & 15) << 3;
  int rloc = tid >> 4;  // 0..31
  float csr[8];
#pragma unroll
  for (int j = 0; j < 8; ++j) csr[j] = 0.f;
  f32x4 acc[8];
#pragma unroll
  for (int j = 0; j < 8; ++j) acc[j] = (f32x4){0.f, 0.f, 0.f, 0.f};

  for (int ch = blockIdx.x; ch < NCH; ch += NBLK) {
    int n0 = ch * 256;
    __syncthreads();  // prev chunk's MFMA reads done (also covers lcs zeroing)
#pragma unroll
    for (int pass = 0; pass < 8; ++pass) {
      int nl = rloc + pass * 32;  // 0..255
      int gr = n0 + nl;
      ushort8v v = (ushort8v){0, 0, 0, 0, 0, 0, 0, 0};
      if (gr < n) v = *(const ushort8v*)(h0 + (size_t)gr * DD + c8);
#pragma unroll
      for (int j = 0; j < 8; ++j) {
        int row = c8 + j;
        int sb = (nl >> 3) ^ ((row >> 3) & 7);
        Ht[row * HT + (sb << 3) + (nl & 7)] = v[j];
        csr[j] += bf2f(v[j]);
      }
    }
    __syncthreads();
#pragma unroll
    for (int kc = 0; kc < 8; ++kc) {
      int b = kc * 4 + quad;  // 8-elem block index of ko = kc*32 + quad*8
      int arow = wave * 16 + l15;
      short8 avv =
          *(const short8*)(&Ht[arow * HT + ((b ^ ((arow >> 3) & 7)) << 3)]);
#pragma unroll
      for (int j = 0; j < 8; ++j) {
        int brow = j * 16 + l15;
        short8 bvv =
            *(const short8*)(&Ht[brow * HT + ((b ^ ((brow >> 3) & 7)) << 3)]);
        acc[j] = __builtin_amdgcn_mfma_f32_16x16x32_bf16(avv, bvv, acc[j], 0, 0, 0);
      }
    }
  }
  // slab write (block-private, non-atomic)
  float* M2 = M2s + (size_t)blockIdx.x * 16384;
  int lr = wave * 16 + quad * 4;
#pragma unroll
  for (int j = 0; j < 8; ++j)
#pragma unroll
    for (int g = 0; g < 4; ++g)
      M2[(lr + g) * 128 + j * 16 + l15] = acc[j][g];
#pragma unroll
  for (int j = 0; j < 8; ++j) atomicAdd(&lcs[c8 + j], csr[j]);
  __syncthreads();
  if (tid < 128) css[(size_t)blockIdx.x * 128 + tid] = lcs[tid];
}

// fold the 196 slabs
__global__ void k_red(const float* __restrict__ M2s, const float* __restrict__ css,
                      float* __restrict__ M2f, float* __restrict__ csf) {
  int i = blockIdx.x * 256 + threadIdx.x;  // 64 blocks -> 16384
  float s = 0.f;
  for (int k = 0; k < 196; ++k) s += M2s[(size_t)k * 16384 + i];
  M2f[i] = s;
  if (i < 128) {
    float c = 0.f;
    for (int k = 0; k < 196; ++k) c += css[(size_t)k * 128 + i];
    csf[i] = c;
  }
}

// analytic BN1 scale/shift: var_c = w^T M2 w / N - (colsum.w/N)^2  (b1 cancels)
__global__ __launch_bounds__(128) void k_bn1(
    const float* __restrict__ M2, const float* __restrict__ cs,
    const unsigned short* __restrict__ W1t_l, const float* __restrict__ g1_l,
    const float* __restrict__ be1_l, float* __restrict__ osc,
    float* __restrict__ osh) {
  __shared__ float wsh[128];
  __shared__ float red1[2], red2[2];
  int c = blockIdx.x, t = threadIdx.x;
  float w = bf2f(W1t_l[c * 128 + t]);
  wsh[t] = w;
  __syncthreads();
  float inner = 0.f;
#pragma unroll 4
  for (int k = 0; k < 128; ++k) inner = fmaf(M2[t * 128 + k], wsh[k], inner);
  float s1 = w * inner;
  float s2 = w * cs[t];
#pragma unroll
  for (int off = 32; off > 0; off >>= 1) {
    s1 += __shfl_xor(s1, off, 64);
    s2 += __shfl_xor(s2, off, 64);
  }
  if ((t & 63) == 0) { red1[t >> 6] = s1; red2[t >> 6] = s2; }
  __syncthreads();
  if (t == 0) {
    float q = (red1[0] + red1[1]) * (1.0f / NN);
    float um = (red2[0] + red2[1]) * (1.0f / NN);
    float var = fmaxf(q - um * um, 0.f);
    float sc = g1_l[c] * rsqrtf(var + BN_EPS);
    osc[c] = sc;
    osh[c] = be1_l[c] - um * sc;
  }
}

// ---------------- fused GEMM1+BN1+ReLU+GEMM2, v2 ----------------
// 128 rows/block, 8 waves x 16 rows. A rows live in REGISTERS (wave-private,
// loaded once; no Asm staging). B-tiles (16KB) double-buffered in LDS -> ONE
// barrier per phase, loads issued 2 phases ahead of their MFMA use. 8 MFMA
// phases: T0,T1 = W1cg0 (->acc1, EPI->H), T2,T3 = W2 k0,k1 (acc2 += H @ W2),
// T4..T7 same for cg1. Epilogue: +b2, BN2 partial stats, C store via H-reuse.

__global__ __launch_bounds__(512, 4) void k_gfused(
    const unsigned short* __restrict__ A, const float* __restrict__ sc1,
    const float* __restrict__ sh1, const unsigned short* __restrict__ W1t_l,
    const unsigned short* __restrict__ W2t_l, const float* __restrict__ b2_l,
    unsigned short* __restrict__ C, float* __restrict__ psum,
    float* __restrict__ psq, int n) {
  constexpr int BST = 72;  // B row stride (ushorts), 144B -> 2-way bank alias
  constexpr int HP = 136;  // H row stride (ushorts), 272B
  __shared__ __align__(16) unsigned short Bsm[2][128 * BST];  // 36864 B
  __shared__ __align__(16) unsigned short H[128 * HP];        // 34816 B
  __shared__ float bsum[128], bsq[128];

  int tid = threadIdx.x;
  int lane = tid & 63, wave = tid >> 6;
  int quad = lane >> 4, l15 = lane & 15;
  int row0 = blockIdx.x * 128;
  int r = row0 + wave * 16 + l15;
  bool valid = r < n;

  // A row fragments in registers (K=128: 4 slices of 32)
  short8 av[4];
#pragma unroll
  for (int ks = 0; ks < 4; ++ks) {
    av[ks] = (short8){0, 0, 0, 0, 0, 0, 0, 0};
    if (valid) av[ks] = *(const short8*)(A + (size_t)r * 128 + ks * 32 + quad * 8);
  }

  ushort8v pA[2], pB[2];  // alternating prefetch register sets
  f32x4 acc1[8], acc2[8];
#pragma unroll
  for (int j = 0; j < 8; ++j) acc1[j] = (f32x4){0.f, 0.f, 0.f, 0.f};
#pragma unroll
  for (int j = 0; j < 8; ++j) acc2[j] = (f32x4){0.f, 0.f, 0.f, 0.f};

#define LD_W1(dst, cg, kc)                                                      \
  {                                                                             \
    _Pragma("unroll") for (int it = 0; it < 2; ++it) {                          \
      int f = tid + it * 512, rr = f >> 3, cc = (f & 7) << 3;                   \
      dst[it] = *(const ushort8v*)(W1t_l + (size_t)((cg)*128 + rr) * 128 +      \
                                   (kc)*64 + cc);                               \
    }                                                                           \
  }
#define LD_W2(dst, kc2)                                                         \
  {                                                                             \
    _Pragma("unroll") for (int it = 0; it < 2; ++it) {                          \
      int f = tid + it * 512, rr = f >> 3, cc = (f & 7) << 3;                   \
      dst[it] = *(const ushort8v*)(W2t_l + (size_t)rr * 256 + (kc2)*64 + cc);   \
    }                                                                           \
  }
#define ST_B(buf, src)                                                          \
  {                                                                             \
    _Pragma("unroll") for (int it = 0; it < 2; ++it) {                          \
      int f = tid + it * 512, rr = f >> 3, cc = (f & 7) << 3;                   \
      *(ushort8v*)(&Bsm[buf][rr * BST + cc]) = src[it];                         \
    }                                                                           \
  }
#define MM1(buf, k2)                                                            \
  {                                                                             \
    _Pragma("unroll") for (int kk = 0; kk < 2; ++kk) {                          \
      int ko = kk * 32 + quad * 8;                                              \
      short8 a = av[(k2)*2 + kk];                                               \
      _Pragma("unroll") for (int cf = 0; cf < 8; ++cf) {                        \
        short8 bv = *(const short8*)(&Bsm[buf][(cf * 16 + l15) * BST + ko]);    \
        acc1[cf] = __builtin_amdgcn_mfma_f32_16x16x32_bf16(a, bv, acc1[cf],     \
                                                           0, 0, 0);            \
      }                                                                         \
    }                                                                           \
  }
#define MM2(buf, half)                                                          \
  {                                                                             \
    _Pragma("unroll") for (int kk = 0; kk < 64; kk += 32) {                     \
      int ko = kk + quad * 8;                                                   \
      short8 a = *(const short8*)(&H[(wave * 16 + l15) * HP + (half)*64 + ko]); \
      _Pragma("unroll") for (int cf = 0; cf < 8; ++cf) {                        \
        short8 bv = *(const short8*)(&Bsm[buf][(cf * 16 + l15) * BST + ko]);    \
        acc2[cf] = __builtin_amdgcn_mfma_f32_16x16x32_bf16(a, bv, acc2[cf],     \
                                                           0, 0, 0);            \
      }                                                                         \
    }                                                                           \
  }
#define EPI(cg)                                                                 \
  {                                                                             \
    int lrb = wave * 16 + quad * 4;                                             \
    _Pragma("unroll") for (int cf = 0; cf < 8; ++cf) {                          \
      int col = (cg)*128 + cf * 16 + l15;                                       \
      float sc = sc1[col], sh = sh1[col];                                       \
      _Pragma("unroll") for (int g = 0; g < 4; ++g)                             \
          H[(lrb + g) * HP + cf * 16 + l15] =                                   \
              f2bf(fmaxf(0.f, acc1[cf][g] * sc + sh));                          \
    }                                                                           \
  }
#define ZACC1                                                                   \
  {                                                                             \
    _Pragma("unroll") for (int j = 0; j < 8; ++j)                               \
        acc1[j] = (f32x4){0.f, 0.f, 0.f, 0.f};                                  \
  }

  // prologue: T0 -> B0 (immediate), T1 loads in flight
  LD_W1(pA, 0, 0)
  LD_W1(pB, 0, 1)
  ST_B(0, pA)
  __syncthreads();
  // Ph1: MFMA T0; stage T1->B1; issue T2
  LD_W2(pA, 0) MM1(0, 0) ST_B(1, pB) __syncthreads();
  // Ph2: MFMA T1 (acc1 cg0 done); EPI->H; stage T2->B0; issue T3
  LD_W2(pB, 1) MM1(1, 1) EPI(0) ST_B(0, pA) __syncthreads();
  // Ph3: MFMA T2 = W2k0 x H[:,0:64]; stage T3->B1; issue T4
  LD_W1(pA, 1, 0) MM2(0, 0) ST_B(1, pB) __syncthreads();
  // Ph4: MFMA T3 = W2k1 x H[:,64:128]; stage T4->B0; issue T5
  LD_W1(pB, 1, 1) MM2(1, 1) ST_B(0, pA) __syncthreads();
  // Ph5: MFMA T4 = W1cg1k0 (acc1 reset); stage T5->B1; issue T6
  LD_W2(pA, 2) ZACC1 MM1(0, 0) ST_B(1, pB) __syncthreads();
  // Ph6: MFMA T5 (acc1 cg1 done); EPI->H; stage T6->B0; issue T7
  LD_W2(pB, 3) MM1(1, 1) EPI(1) ST_B(0, pA) __syncthreads();
  // Ph7: MFMA T6 = W2k2 x H[:,0:64]; stage T7->B1
  MM2(0, 0) ST_B(1, pB) __syncthreads();
  // Ph8: MFMA T7 = W2k3 x H[:,64:128]
  MM2(1, 1)

  // ---- final epilogue: +b2, BN2 partial stats, coalesced C store (Ct = H) ----
  __syncthreads();  // all H reads done; reuse H as C staging tile
  unsigned short* Ct = H;
  if (tid < 128) { bsum[tid] = 0.f; bsq[tid] = 0.f; }
  float s8[8], q8[8];
#pragma unroll
  for (int j = 0; j < 8; ++j) { s8[j] = 0.f; q8[j] = 0.f; }
  int lrbase = wave * 16 + quad * 4;
#pragma unroll
  for (int cf = 0; cf < 8; ++cf) {
    float bv = b2_l[cf * 16 + l15];
#pragma unroll
    for (int g = 0; g < 4; ++g) {
      int lr = lrbase + g;
      float e = acc2[cf][g] + bv;
      Ct[lr * HP + cf * 16 + l15] = f2bf(e);
      if (row0 + lr < n) { s8[cf] += e; q8[cf] += e * e; }
    }
  }
#pragma unroll
  for (int cf = 0; cf < 8; ++cf) {
    s8[cf] += __shfl_xor(s8[cf], 16, 64);
    s8[cf] += __shfl_xor(s8[cf], 32, 64);
    q8[cf] += __shfl_xor(q8[cf], 16, 64);
    q8[cf] += __shfl_xor(q8[cf], 32, 64);
  }
  __syncthreads();  // Ct complete; bsum zeroed
  if (quad == 0) {
#pragma unroll
    for (int cf = 0; cf < 8; ++cf) {
      atomicAdd(&bsum[cf * 16 + l15], s8[cf]);
      atomicAdd(&bsq[cf * 16 + l15], q8[cf]);
    }
  }
#pragma unroll
  for (int it = 0; it < 4; ++it) {
    int f = tid + it * 512;
    int rr = f >> 4, cc = (f & 15) << 3;
    int gr = row0 + rr;
    if (gr < n)
      *(ushort8v*)(C + (size_t)gr * 128 + cc) = *(const ushort8v*)(&Ct[rr * HP + cc]);
  }
  __syncthreads();
  if (tid < 128) {
    psum[(size_t)blockIdx.x * 128 + tid] = bsum[tid];
    psq[(size_t)blockIdx.x * 128 + tid] = bsq[tid];
  }
#undef LD_W1
#undef LD_W2
#undef ST_B
#undef MM1
#undef MM2
#undef EPI
#undef ZACC1
}

// ---------------- column-stat reduce + BN finalize (one block per column) --------

__global__ __launch_bounds__(256) void k_finred(
    const float* __restrict__ psum, const float* __restrict__ psq, int nb, int nc,
    const float* __restrict__ g, const float* __restrict__ be,
    float* __restrict__ osc, float* __restrict__ osh, float invn) {
  __shared__ float ws[4], wq[4];
  int col = blockIdx.x;
  int t = threadIdx.x;
  float s = 0.f, q = 0.f;
  for (int b = t; b < nb; b += 256) {
    s += psum[(size_t)b * nc + col];
    q += psq[(size_t)b * nc + col];
  }
#pragma unroll
  for (int off = 32; off > 0; off >>= 1) {
    s += __shfl_xor(s, off, 64);
    q += __shfl_xor(q, off, 64);
  }
  if ((t & 63) == 0) { ws[t >> 6] = s; wq[t >> 6] = q; }
  __syncthreads();
  if (t == 0) {
    s = ws[0] + ws[1] + ws[2] + ws[3];
    q = wq[0] + wq[1] + wq[2] + wq[3];
    float m = s * invn;
    float v = fmaxf(q * invn - m * m, 0.f);
    float sc = g[col] * rsqrtf(v + BN_EPS);
    osc[col] = sc;
    osh[col] = be[col] - m * sc;
  }
}

// ---------------- classifier z1 stats (sum & sumsq from one array) ----------------

__global__ __launch_bounds__(256) void k_statz(
    const float* __restrict__ z1, const float* __restrict__ g,
    const float* __restrict__ be, float* __restrict__ osc, float* __restrict__ osh) {
  __shared__ float ws[4], wq[4];
  int col = blockIdx.x;
  int t = threadIdx.x;
  float s = 0.f, q = 0.f;
  for (int b = t; b < GG; b += 256) {
    float v = z1[(size_t)b * 128 + col];
    s += v;
    q += v * v;
  }
#pragma unroll
  for (int off = 32; off > 0; off >>= 1) {
    s += __shfl_xor(s, off, 64);
    q += __shfl_xor(q, off, 64);
  }
  if ((t & 63) == 0) { ws[t >> 6] = s; wq[t >> 6] = q; }
  __syncthreads();
  if (t == 0) {
    s = ws[0] + ws[1] + ws[2] + ws[3];
    q = wq[0] + wq[1] + wq[2] + wq[3];
    float m = s / (float)GG;
    float v = fmaxf(q / (float)GG - m * m, 0.f);
    float sc = g[col] * rsqrtf(v + BN_EPS);
    osc[col] = sc;
    osh[col] = be[col] - m * sc;
  }
}

// ---------------- pooling (batch sorted -> contiguous ranges), bf16 X ------------

static __device__ __forceinline__ int lb_i32(const int* a, int n, int key) {
  int lo = 0, hi = n;
  while (lo < hi) {
    int mid = (lo + hi) >> 1;
    if (a[mid] < key) lo = mid + 1; else hi = mid;
  }
  return lo;
}

__global__ __launch_bounds__(512) void k_pool(
    const unsigned short* __restrict__ X, const int* __restrict__ batch,
    const float* __restrict__ tsc, const float* __restrict__ tsh,
    float* __restrict__ z, int n) {
  __shared__ int slo, shi;
  __shared__ float ssum[8][128], smax[8][128];
  int g = blockIdx.x;
  int t = threadIdx.x;
  int sg = t >> 6;           // 0..7 row-subgroup
  int c2 = (t & 63) << 1;    // column pair base
  if (t == 0) {
    slo = lb_i32(batch, n, g);
    shi = lb_i32(batch, n, g + 1);
  }
  __syncthreads();
  int lo = slo, hi = shi;
  float a0 = tsc[c2], a1 = tsc[c2 + 1];
  float b0 = tsh[c2], b1 = tsh[c2 + 1];
  float s0 = 0.f, s1 = 0.f;
  float m0 = -3.402823466e38f, m1 = -3.402823466e38f;
  for (int i = lo + sg; i < hi; i += 8) {
    unsigned u = *(const unsigned*)(X + (size_t)i * DD + c2);
    float v0 = fmaxf(0.f, bf2f((unsigned short)(u & 0xffff)) * a0 + b0);
    float v1 = fmaxf(0.f, bf2f((unsigned short)(u >> 16)) * a1 + b1);
    s0 += v0; m0 = fmaxf(m0, v0);
    s1 += v1; m1 = fmaxf(m1, v1);
  }
  ssum[sg][c2] = s0; ssum[sg][c2 + 1] = s1;
  smax[sg][c2] = m0; smax[sg][c2 + 1] = m1;
  __syncthreads();
  if (t < 128) {
    float S = 0.f, M = -3.402823466e38f;
#pragma unroll
    for (int k = 0; k < 8; ++k) {
      S += ssum[k][t];
      M = fmaxf(M, smax[k][t]);
    }
    float cntf = (float)(hi - lo);
    z[(size_t)g * 384 + t] = S;
    z[(size_t)g * 384 + 128 + t] = S / fmaxf(cntf, 1.f);
    z[(size_t)g * 384 + 256 + t] = M;
  }
}

// ---------------- classifier head (fp32, tiny; no atomics) ----------------

__global__ void k_cls1(const float* __restrict__ z, const float* __restrict__ cW1,
                       const float* __restrict__ cb1, float* __restrict__ z1) {
  __shared__ float zr[384];
  int g = blockIdx.x;
  int c = threadIdx.x;  // 128
  for (int i = c; i < 384; i += 128) zr[i] = z[(size_t)g * 384 + i];
  __syncthreads();
  float s = cb1[c];
#pragma unroll 4
  for (int k = 0; k < 384; ++k) s = fmaf(zr[k], cW1[(size_t)k * 128 + c], s);
  z1[(size_t)g * 128 + c] = s;
}

__global__ void k_cls2(const float* __restrict__ z1, const float* __restrict__ csc,
                       const float* __restrict__ csh, const float* __restrict__ cW2,
                       const float* __restrict__ cb2, const float* __restrict__ cW3,
                       const float* __restrict__ cb3, float* __restrict__ out) {
  __shared__ float z1n[128];
  __shared__ float z2s[64];
  int g = blockIdx.x;
  int t = threadIdx.x;  // 128
  z1n[t] = fmaxf(0.f, z1[(size_t)g * 128 + t] * csc[t] + csh[t]);
  __syncthreads();
  if (t < 64) {
    float s = cb2[t];
#pragma unroll 4
    for (int k = 0; k < 128; ++k) s = fmaf(z1n[k], cW2[(size_t)k * 64 + t], s);
    z2s[t] = fmaxf(0.f, s);
  }
  __syncthreads();
  if (t < 2) {
    float s = cb3[t];
#pragma unroll 4
    for (int c = 0; c < 64; ++c) s = fmaf(z2s[c], cW3[(size_t)c * 2 + t], s);
    out[(size_t)g * 2 + t] = s;
  }
}

// ---------------- launch ----------------

extern "C" void kernel_launch(void* const* d_in, const int* in_sizes, int n_in,
                              void* d_out, int out_size, void* d_ws, size_t ws_size,
                              hipStream_t stream) {
  const float* x = (const float*)d_in[0];
  const int* ei = (const int*)d_in[1];     // int32 (harness downcasts int64)
  const int* batch = (const int*)d_in[2];  // int32
  const float* W1 = (const float*)d_in[4];
  const float* b1 = (const float*)d_in[5];
  const float* g1 = (const float*)d_in[6];
  const float* be1 = (const float*)d_in[7];
  const float* W2 = (const float*)d_in[8];
  const float* b2 = (const float*)d_in[9];
  const float* gbn = (const float*)d_in[10];
  const float* bbn = (const float*)d_in[11];
  const float* epsv = (const float*)d_in[12];
  const float* cW1 = (const float*)d_in[13];
  const float* cb1 = (const float*)d_in[14];
  const float* cg = (const float*)d_in[15];
  const float* cbeta = (const float*)d_in[16];
  const float* cW2 = (const float*)d_in[17];
  const float* cb2 = (const float*)d_in[18];
  const float* cW3 = (const float*)d_in[19];
  const float* cb3 = (const float*)d_in[20];
  float* out = (float*)d_out;
  (void)b1;  // BN1 shift is independent of b1 (cancels in (y - mean))

  char* p = (char*)d_ws;
  auto alloc = [&](size_t bytes) {
    char* r = p;
    p += (bytes + 255) & ~(size_t)255;
    return r;
  };
  const int NB = (NN + 127) / 128;  // 782 GEMM row-blocks
  int* cnt = (int*)alloc((size_t)NN * 4);
  int* rs = (int*)alloc((size_t)(NN + 1) * 4);
  int* cur = (int*)alloc((size_t)NN * 4);
  int* ci = (int*)alloc((size_t)EE * 4);
  int* part = (int*)alloc(128 * 4);
  int* partx = (int*)alloc(128 * 4);
  unsigned short* xbf = (unsigned short*)alloc((size_t)NN * DD * 2);
  unsigned short* h0 = (unsigned short*)alloc((size_t)NN * DD * 2);
  unsigned short* xp = (unsigned short*)alloc((size_t)NN * DD * 2);
  float* psum = (float*)alloc((size_t)NB * 128 * 4);
  float* psq = (float*)alloc((size_t)NB * 128 * 4);
  float* tsc1 = (float*)alloc(256 * 4);
  float* tsh1 = (float*)alloc(256 * 4);
  float* tscX = (float*)alloc(128 * 4);
  float* tshX = (float*)alloc(128 * 4);
  float* zbuf = (float*)alloc((size_t)GG * 384 * 4);
  float* z1 = (float*)alloc((size_t)GG * 128 * 4);
  unsigned short* W1t = (unsigned short*)alloc((size_t)4 * 256 * 128 * 2);
  unsigned short* W2t = (unsigned short*)alloc((size_t)4 * 128 * 256 * 2);
  float* M2s = (float*)alloc((size_t)196 * 16384 * 4);  // per-block slabs
  float* css = (float*)alloc((size_t)196 * 128 * 4);
  float* M2f = (float*)alloc((size_t)128 * 128 * 4);
  float* csf = (float*)alloc(128 * 4);
  (void)ws_size; (void)n_in; (void)in_sizes; (void)out_size;

  // weight convert+transpose to bf16 (static across layers/calls)
  k_conv<<<512, 256, 0, stream>>>(W1, W2, W1t, W2t);
  // x -> bf16
  k_x2bf<<<(NN * DD / 4 + 255) / 256, 256, 0, stream>>>(x, xbf);

  // CSR build (edges static across layers)
  hipMemsetAsync(cnt, 0, (size_t)NN * 4, stream);
  k_hist<<<(EE + 255) / 256, 256, 0, stream>>>(ei, cnt);
  const int nscan = (NN + 1023) / 1024;  // 98
  k_part<<<nscan, 1024, 0, stream>>>(cnt, part);
  k_scanpart<<<1, 128, 0, stream>>>(part, partx, nscan);
  k_rs<<<nscan, 1024, 0, stream>>>(cnt, partx, rs, cur);
  k_fill<<<(EE + 255) / 256, 256, 0, stream>>>(ei, cur, ci);

  for (int l = 0; l < LL; ++l) {
    const unsigned short* Xl = (l == 0) ? xbf : xp;
    k_agg_bf16<<<(NN * 16 + 255) / 256, 256, 0, stream>>>(
        Xl, rs, ci, epsv, l, (l > 0) ? 1 : 0, tscX, tshX, h0, NN);
    // analytic BN1 stats: M2 = h0^T h0 (196 reg-accum slabs); fold; scale/shift
    k_mom<<<196, 512, 0, stream>>>(h0, M2s, css, NN);
    k_red<<<64, 256, 0, stream>>>(M2s, css, M2f, csf);
    k_bn1<<<256, 128, 0, stream>>>(M2f, csf, W1t + (size_t)l * 256 * 128,
                                   g1 + (size_t)l * 256, be1 + (size_t)l * 256,
                                   tsc1, tsh1);
    // fused GEMM1+BN1+ReLU+GEMM2 (h1 never touches HBM)
    k_gfused<<<NB, 512, 0, stream>>>(
        h0, tsc1, tsh1, W1t + (size_t)l * 256 * 128, W2t + (size_t)l * 128 * 256,
        b2 + (size_t)l * 128, xp, psum, psq, NN);
    k_finred<<<128, 256, 0, stream>>>(psum, psq, NB, 128, gbn + (size_t)l * 128,
                                      bbn + (size_t)l * 128, tscX, tshX, 1.0f / NN);
  }

  k_pool<<<GG, 512, 0, stream>>>(xp, batch, tscX, tshX, zbuf, NN);
  k_cls1<<<GG, 128, 0, stream>>>(zbuf, cW1, cb1, z1);
  k_statz<<<128, 256, 0, stream>>>(z1, cg, cbeta, tscX, tshX);
  k_cls2<<<GG, 128, 0, stream>>>(z1, tscX, tshX, cW2, cb2, cW3, cb3, out);
}

// Round 5
// 713.102 us; speedup vs baseline: 1.2098x; 1.0585x over previous
//
#include <hip/hip_runtime.h>
#include <cstdint>
#include <cstddef>

// Problem constants (fixed by the reference setup_inputs).
#define NN 100000
#define EE 500000
#define DD 128
#define GG 512
#define LL 4
#define BN_EPS 1e-5f

typedef __attribute__((ext_vector_type(8))) short short8;
typedef __attribute__((ext_vector_type(8))) unsigned short ushort8v;
typedef __attribute__((ext_vector_type(4))) float f32x4;

static __device__ __forceinline__ unsigned short f2bf(float f) {
  union { float f; unsigned u; } v;
  v.f = f;
  unsigned r = v.u + 0x7fffu + ((v.u >> 16) & 1u);  // RNE
  return (unsigned short)(r >> 16);
}
static __device__ __forceinline__ float bf2f(unsigned short u) {
  union { unsigned u; float f; } v;
  v.u = ((unsigned)u) << 16;
  return v.f;
}

// ---------------- CSR build (int32 inputs) ----------------

__global__ void k_hist(const int* __restrict__ ei, int* __restrict__ cnt) {
  int e = blockIdx.x * 256 + threadIdx.x;
  if (e < EE) {
    int d = ei[EE + e];
    if (d >= 0 && d < NN) atomicAdd(&cnt[d], 1);
  }
}

__global__ void k_part(const int* __restrict__ cnt, int* __restrict__ part) {
  __shared__ int sm[1024];
  int t = threadIdx.x;
  int i = blockIdx.x * 1024 + t;
  sm[t] = (i < NN) ? cnt[i] : 0;
  __syncthreads();
  for (int off = 512; off > 0; off >>= 1) {
    if (t < off) sm[t] += sm[t + off];
    __syncthreads();
  }
  if (t == 0) part[blockIdx.x] = sm[0];
}

__global__ void k_scanpart(const int* __restrict__ part, int* __restrict__ partx, int nb) {
  __shared__ int sm[128];
  int t = threadIdx.x;
  int v = (t < nb) ? part[t] : 0;
  sm[t] = v;
  __syncthreads();
  for (int off = 1; off < 128; off <<= 1) {
    int u = (t >= off) ? sm[t - off] : 0;
    __syncthreads();
    sm[t] += u;
    __syncthreads();
  }
  if (t < nb) partx[t] = sm[t] - v;
}

__global__ void k_rs(const int* __restrict__ cnt, const int* __restrict__ partx,
                     int* __restrict__ rs, int* __restrict__ cur) {
  __shared__ int sm[1024];
  int t = threadIdx.x;
  int i = blockIdx.x * 1024 + t;
  int v = (i < NN) ? cnt[i] : 0;
  sm[t] = v;
  __syncthreads();
  for (int off = 1; off < 1024; off <<= 1) {
    int u = (t >= off) ? sm[t - off] : 0;
    __syncthreads();
    sm[t] += u;
    __syncthreads();
  }
  if (i < NN) {
    int excl = partx[blockIdx.x] + sm[t] - v;
    rs[i] = excl;
    cur[i] = excl;
    if (i == NN - 1) rs[NN] = excl + v;
  }
}

__global__ void k_fill(const int* __restrict__ ei, int* __restrict__ cur,
                       int* __restrict__ ci) {
  int e = blockIdx.x * 256 + threadIdx.x;
  if (e < EE) {
    int s = ei[e];
    int d = ei[EE + e];
    if (d >= 0 && d < NN && s >= 0 && s < NN) {
      int pos = atomicAdd(&cur[d], 1);
      if (pos >= 0 && pos < EE) ci[pos] = s;  // order irrelevant (sum)
    }
  }
}

// ---------------- weight convert: W -> W^T in bf16, once per call ----------------

__global__ void k_conv(const float* __restrict__ W1, const float* __restrict__ W2,
                       unsigned short* __restrict__ W1t, unsigned short* __restrict__ W2t) {
  int idx = blockIdx.x * 256 + threadIdx.x;
  if (idx < 4 * 256 * 128) {
    {  // W1: [l][k][nc] (K=128,NC=256) -> [l][nc][k]
      int l = idx >> 15, rem = idx & 32767;
      int nc = rem >> 7, k = rem & 127;
      W1t[idx] = f2bf(W1[(l << 15) + k * 256 + nc]);
    }
    {  // W2: [l][k][nc] (K=256,NC=128) -> [l][nc][k]
      int l = idx >> 15, rem = idx & 32767;
      int nc = rem >> 8, k = rem & 255;
      W2t[idx] = f2bf(W2[(l << 15) + k * 128 + nc]);
    }
  }
}

// ---------------- x -> bf16 convert (streaming, once per call) ----------------

__global__ void k_x2bf(const float* __restrict__ x, unsigned short* __restrict__ xb) {
  int i = blockIdx.x * 256 + threadIdx.x;
  if (i < NN * DD / 4) {
    float4 v = *(const float4*)(x + (size_t)i * 4);
    ushort4 o;
    o.x = f2bf(v.x); o.y = f2bf(v.y); o.z = f2bf(v.z); o.w = f2bf(v.w);
    *(ushort4*)(xb + (size_t)i * 4) = o;
  }
}

// ---------------- aggregation v2: 4-deep neighbor prefetch ----------------
// 16 lanes/node, ushort8 (16B) loads. Random-gather latency chain (avg degree 5):
// 4 named prefetch regs (static indexing, no scratch) keep 4 loads in flight.

__global__ __launch_bounds__(256) void k_agg_bf16(
    const unsigned short* __restrict__ X, const int* __restrict__ rs,
    const int* __restrict__ ci, const float* __restrict__ epsv, int l, int mode,
    const float* __restrict__ tsc, const float* __restrict__ tsh,
    unsigned short* __restrict__ h0, int n) {
  int idx = blockIdx.x * 256 + threadIdx.x;
  int node = idx >> 4;
  int c8 = (idx & 15) << 3;
  if (node >= n) return;
  float sa[8], sb[8];
  if (mode) {
    float4 a0 = *(const float4*)(tsc + c8), a1 = *(const float4*)(tsc + c8 + 4);
    float4 b0 = *(const float4*)(tsh + c8), b1 = *(const float4*)(tsh + c8 + 4);
    sa[0] = a0.x; sa[1] = a0.y; sa[2] = a0.z; sa[3] = a0.w;
    sa[4] = a1.x; sa[5] = a1.y; sa[6] = a1.z; sa[7] = a1.w;
    sb[0] = b0.x; sb[1] = b0.y; sb[2] = b0.z; sb[3] = b0.w;
    sb[4] = b1.x; sb[5] = b1.y; sb[6] = b1.z; sb[7] = b1.w;
  }
  float se = 1.f + epsv[l];
  ushort8v v = *(const ushort8v*)(X + (size_t)node * DD + c8);
  float acc[8];
#pragma unroll
  for (int j = 0; j < 8; ++j) {
    float f = bf2f(v[j]);
    if (mode) f = fmaxf(0.f, f * sa[j] + sb[j]);
    acc[j] = se * f;
  }
  int e0 = rs[node], e1 = rs[node + 1];
#define NLD(ee) (*(const ushort8v*)(X + (size_t)ci[ee] * DD + c8))
#define NACC(uc)                                                  \
  {                                                               \
    _Pragma("unroll") for (int j = 0; j < 8; ++j) {               \
      float f = bf2f(uc[j]);                                      \
      if (mode) f = fmaxf(0.f, f * sa[j] + sb[j]);                \
      acc[j] += f;                                                \
    }                                                             \
  }
  ushort8v p0 = (ushort8v){0, 0, 0, 0, 0, 0, 0, 0};
  ushort8v p1 = p0, p2 = p0, p3 = p0;
  if (e0 + 0 < e1) p0 = NLD(e0 + 0);
  if (e0 + 1 < e1) p1 = NLD(e0 + 1);
  if (e0 + 2 < e1) p2 = NLD(e0 + 2);
  if (e0 + 3 < e1) p3 = NLD(e0 + 3);
  for (int e = e0; e < e1; e += 4) {
    ushort8v c0 = p0, c1 = p1, c2 = p2, c3 = p3;
    if (e + 4 < e1) p0 = NLD(e + 4);
    if (e + 5 < e1) p1 = NLD(e + 5);
    if (e + 6 < e1) p2 = NLD(e + 6);
    if (e + 7 < e1) p3 = NLD(e + 7);
    NACC(c0);
    if (e + 1 < e1) NACC(c1);
    if (e + 2 < e1) NACC(c2);
    if (e + 3 < e1) NACC(c3);
  }
#undef NLD
#undef NACC
  ushort8v o;
#pragma unroll
  for (int j = 0; j < 8; ++j) o[j] = f2bf(acc[j]);
  *(ushort8v*)(h0 + (size_t)node * DD + c8) = o;
}

// ---------------- M2 = h0^T h0 (128x128) + colsum(h0), for analytic BN1 stats ----
// 196 persistent blocks grid-stride over 391 chunks of 256 rows; register M2
// accumulation; one non-atomic 64KB slab write per block. XOR block-swizzle on
// the transposed staging cuts write bank conflicts to ~4-way.

__global__ __launch_bounds__(512) void k_mom(
    const unsigned short* __restrict__ h0, float* __restrict__ M2s,
    float* __restrict__ css, int n) {
  constexpr int HT = 264;
  constexpr int NCH = (NN + 255) / 256;  // 391
  constexpr int NBLK = 196;
  __shared__ __align__(16) unsigned short Ht[128 * HT];  // 67584 B
  __shared__ float lcs[128];
  int tid = threadIdx.x;
  int lane = tid & 63, wave = tid >> 6;
  int quad = lane >> 4, l15 = lane & 15;
  if (tid < 128) lcs[tid] = 0.f;
  int c8 = (tid & 15) << 3;
  int rloc = tid >> 4;  // 0..31
  float csr[8];
#pragma unroll
  for (int j = 0; j < 8; ++j) csr[j] = 0.f;
  f32x4 acc[8];
#pragma unroll
  for (int j = 0; j < 8; ++j) acc[j] = (f32x4){0.f, 0.f, 0.f, 0.f};

  for (int ch = blockIdx.x; ch < NCH; ch += NBLK) {
    int n0 = ch * 256;
    __syncthreads();  // prev chunk's MFMA reads done (also covers lcs zeroing)
#pragma unroll
    for (int pass = 0; pass < 8; ++pass) {
      int nl = rloc + pass * 32;  // 0..255
      int gr = n0 + nl;
      ushort8v v = (ushort8v){0, 0, 0, 0, 0, 0, 0, 0};
      if (gr < n) v = *(const ushort8v*)(h0 + (size_t)gr * DD + c8);
#pragma unroll
      for (int j = 0; j < 8; ++j) {
        int row = c8 + j;
        int sb = (nl >> 3) ^ ((row >> 3) & 7);
        Ht[row * HT + (sb << 3) + (nl & 7)] = v[j];
        csr[j] += bf2f(v[j]);
      }
    }
    __syncthreads();
#pragma unroll
    for (int kc = 0; kc < 8; ++kc) {
      int b = kc * 4 + quad;  // 8-elem block index of ko = kc*32 + quad*8
      int arow = wave * 16 + l15;
      short8 avv =
          *(const short8*)(&Ht[arow * HT + ((b ^ ((arow >> 3) & 7)) << 3)]);
#pragma unroll
      for (int j = 0; j < 8; ++j) {
        int brow = j * 16 + l15;
        short8 bvv =
            *(const short8*)(&Ht[brow * HT + ((b ^ ((brow >> 3) & 7)) << 3)]);
        acc[j] = __builtin_amdgcn_mfma_f32_16x16x32_bf16(avv, bvv, acc[j], 0, 0, 0);
      }
    }
  }
  // slab write (block-private, non-atomic)
  float* M2 = M2s + (size_t)blockIdx.x * 16384;
  int lr = wave * 16 + quad * 4;
#pragma unroll
  for (int j = 0; j < 8; ++j)
#pragma unroll
    for (int g = 0; g < 4; ++g)
      M2[(lr + g) * 128 + j * 16 + l15] = acc[j][g];
#pragma unroll
  for (int j = 0; j < 8; ++j) atomicAdd(&lcs[c8 + j], csr[j]);
  __syncthreads();
  if (tid < 128) css[(size_t)blockIdx.x * 128 + tid] = lcs[tid];
}

// fold the 196 slabs
__global__ void k_red(const float* __restrict__ M2s, const float* __restrict__ css,
                      float* __restrict__ M2f, float* __restrict__ csf) {
  int i = blockIdx.x * 256 + threadIdx.x;  // 64 blocks -> 16384
  float s = 0.f;
  for (int k = 0; k < 196; ++k) s += M2s[(size_t)k * 16384 + i];
  M2f[i] = s;
  if (i < 128) {
    float c = 0.f;
    for (int k = 0; k < 196; ++k) c += css[(size_t)k * 128 + i];
    csf[i] = c;
  }
}

// analytic BN1 scale/shift: var_c = w^T M2 w / N - (colsum.w/N)^2  (b1 cancels)
__global__ __launch_bounds__(128) void k_bn1(
    const float* __restrict__ M2, const float* __restrict__ cs,
    const unsigned short* __restrict__ W1t_l, const float* __restrict__ g1_l,
    const float* __restrict__ be1_l, float* __restrict__ osc,
    float* __restrict__ osh) {
  __shared__ float wsh[128];
  __shared__ float red1[2], red2[2];
  int c = blockIdx.x, t = threadIdx.x;
  float w = bf2f(W1t_l[c * 128 + t]);
  wsh[t] = w;
  __syncthreads();
  float inner = 0.f;
#pragma unroll 4
  for (int k = 0; k < 128; ++k) inner = fmaf(M2[t * 128 + k], wsh[k], inner);
  float s1 = w * inner;
  float s2 = w * cs[t];
#pragma unroll
  for (int off = 32; off > 0; off >>= 1) {
    s1 += __shfl_xor(s1, off, 64);
    s2 += __shfl_xor(s2, off, 64);
  }
  if ((t & 63) == 0) { red1[t >> 6] = s1; red2[t >> 6] = s2; }
  __syncthreads();
  if (t == 0) {
    float q = (red1[0] + red1[1]) * (1.0f / NN);
    float um = (red2[0] + red2[1]) * (1.0f / NN);
    float var = fmaxf(q - um * um, 0.f);
    float sc = g1_l[c] * rsqrtf(var + BN_EPS);
    osc[c] = sc;
    osh[c] = be1_l[c] - um * sc;
  }
}

// ---------------- fused GEMM1+BN1+ReLU+GEMM2, v3: 256 rows/block ----------------
// 8 waves x 32 rows (2 row-groups of 16). Each B-fragment ds_read feeds TWO MFMAs
// (one per row-group) -> LDS B-read traffic per output HALVES vs v2; barriers per
// output halve. A rows in registers (av0/av1). B double-buffered; 8 MFMA phases,
// loads issued one phase ahead. LDS 107.5KB -> 1 block/CU (matches measured
// residency of v2). Grid 391.

__global__ __launch_bounds__(512, 2) void k_gfused(
    const unsigned short* __restrict__ A, const float* __restrict__ sc1,
    const float* __restrict__ sh1, const unsigned short* __restrict__ W1t_l,
    const unsigned short* __restrict__ W2t_l, const float* __restrict__ b2_l,
    unsigned short* __restrict__ C, float* __restrict__ psum,
    float* __restrict__ psq, int n) {
  constexpr int BST = 72;  // B row stride (ushorts), 144B
  constexpr int HP = 136;  // H row stride (ushorts), 272B
  __shared__ __align__(16) unsigned short Bsm[2][128 * BST];  // 36864 B
  __shared__ __align__(16) unsigned short H[256 * HP];        // 69632 B
  __shared__ float bsum[128], bsq[128];

  int tid = threadIdx.x;
  int lane = tid & 63, wave = tid >> 6;
  int quad = lane >> 4, l15 = lane & 15;
  int row0 = blockIdx.x * 256;
  int r0 = row0 + wave * 32 + l15;
  int r1 = r0 + 16;

  // A row fragments in registers: 2 row-groups x 4 k-slices
  short8 av0[4], av1[4];
#pragma unroll
  for (int ks = 0; ks < 4; ++ks) {
    av0[ks] = (short8){0, 0, 0, 0, 0, 0, 0, 0};
    av1[ks] = (short8){0, 0, 0, 0, 0, 0, 0, 0};
    if (r0 < n) av0[ks] = *(const short8*)(A + (size_t)r0 * 128 + ks * 32 + quad * 8);
    if (r1 < n) av1[ks] = *(const short8*)(A + (size_t)r1 * 128 + ks * 32 + quad * 8);
  }

  ushort8v pA[2], pB[2];  // alternating prefetch register sets
  f32x4 acc1a[8], acc1b[8], acc2a[8], acc2b[8];
#pragma unroll
  for (int j = 0; j < 8; ++j) {
    acc1a[j] = (f32x4){0.f, 0.f, 0.f, 0.f};
    acc1b[j] = (f32x4){0.f, 0.f, 0.f, 0.f};
    acc2a[j] = (f32x4){0.f, 0.f, 0.f, 0.f};
    acc2b[j] = (f32x4){0.f, 0.f, 0.f, 0.f};
  }

#define LD_W1(dst, cg, kc)                                                      \
  {                                                                             \
    _Pragma("unroll") for (int it = 0; it < 2; ++it) {                          \
      int f = tid + it * 512, rr = f >> 3, cc = (f & 7) << 3;                   \
      dst[it] = *(const ushort8v*)(W1t_l + (size_t)((cg)*128 + rr) * 128 +      \
                                   (kc)*64 + cc);                               \
    }                                                                           \
  }
#define LD_W2(dst, kc2)                                                         \
  {                                                                             \
    _Pragma("unroll") for (int it = 0; it < 2; ++it) {                          \
      int f = tid + it * 512, rr = f >> 3, cc = (f & 7) << 3;                   \
      dst[it] = *(const ushort8v*)(W2t_l + (size_t)rr * 256 + (kc2)*64 + cc);   \
    }                                                                           \
  }
#define ST_B(buf, src)                                                          \
  {                                                                             \
    _Pragma("unroll") for (int it = 0; it < 2; ++it) {                          \
      int f = tid + it * 512, rr = f >> 3, cc = (f & 7) << 3;                   \
      *(ushort8v*)(&Bsm[buf][rr * BST + cc]) = src[it];                         \
    }                                                                           \
  }
#define MM1(buf, k2)                                                            \
  {                                                                             \
    _Pragma("unroll") for (int kk = 0; kk < 2; ++kk) {                          \
      int ko = kk * 32 + quad * 8;                                              \
      short8 a0 = av0[(k2)*2 + kk];                                             \
      short8 a1 = av1[(k2)*2 + kk];                                             \
      _Pragma("unroll") for (int cf = 0; cf < 8; ++cf) {                        \
        short8 bv = *(const short8*)(&Bsm[buf][(cf * 16 + l15) * BST + ko]);    \
        acc1a[cf] = __builtin_amdgcn_mfma_f32_16x16x32_bf16(a0, bv, acc1a[cf],  \
                                                            0, 0, 0);           \
        acc1b[cf] = __builtin_amdgcn_mfma_f32_16x16x32_bf16(a1, bv, acc1b[cf],  \
                                                            0, 0, 0);           \
      }                                                                         \
    }                                                                           \
  }
#define MM2(buf, half)                                                          \
  {                                                                             \
    _Pragma("unroll") for (int kk = 0; kk < 64; kk += 32) {                     \
      int ko = kk + quad * 8;                                                   \
      short8 a0 =                                                               \
          *(const short8*)(&H[(wave * 32 + l15) * HP + (half)*64 + ko]);        \
      short8 a1 =                                                               \
          *(const short8*)(&H[(wave * 32 + 16 + l15) * HP + (half)*64 + ko]);   \
      _Pragma("unroll") for (int cf = 0; cf < 8; ++cf) {                        \
        short8 bv = *(const short8*)(&Bsm[buf][(cf * 16 + l15) * BST + ko]);    \
        acc2a[cf] = __builtin_amdgcn_mfma_f32_16x16x32_bf16(a0, bv, acc2a[cf],  \
                                                            0, 0, 0);           \
        acc2b[cf] = __builtin_amdgcn_mfma_f32_16x16x32_bf16(a1, bv, acc2b[cf],  \
                                                            0, 0, 0);           \
      }                                                                         \
    }                                                                           \
  }
#define EPI(cg)                                                                 \
  {                                                                             \
    int lrb = wave * 32 + quad * 4;                                             \
    _Pragma("unroll") for (int cf = 0; cf < 8; ++cf) {                          \
      int col = (cg)*128 + cf * 16 + l15;                                       \
      float sc = sc1[col], sh = sh1[col];                                       \
      _Pragma("unroll") for (int g = 0; g < 4; ++g) {                           \
        H[(lrb + g) * HP + cf * 16 + l15] =                                     \
            f2bf(fmaxf(0.f, acc1a[cf][g] * sc + sh));                           \
        H[(lrb + 16 + g) * HP + cf * 16 + l15] =                                \
            f2bf(fmaxf(0.f, acc1b[cf][g] * sc + sh));                           \
      }                                                                         \
    }                                                                           \
  }
#define ZACC1                                                                   \
  {                                                                             \
    _Pragma("unroll") for (int j = 0; j < 8; ++j) {                             \
      acc1a[j] = (f32x4){0.f, 0.f, 0.f, 0.f};                                   \
      acc1b[j] = (f32x4){0.f, 0.f, 0.f, 0.f};                                   \
    }                                                                           \
  }

  // prologue: T0 -> B0 (immediate), T1 loads in flight
  LD_W1(pA, 0, 0)
  LD_W1(pB, 0, 1)
  ST_B(0, pA)
  __syncthreads();
  // Ph1: MFMA T0; stage T1->B1; issue T2
  LD_W2(pA, 0) MM1(0, 0) ST_B(1, pB) __syncthreads();
  // Ph2: MFMA T1 (acc1 cg0 done); EPI->H; stage T2->B0; issue T3
  LD_W2(pB, 1) MM1(1, 1) EPI(0) ST_B(0, pA) __syncthreads();
  // Ph3: MFMA T2 = W2k0 x H[:,0:64]; stage T3->B1; issue T4
  LD_W1(pA, 1, 0) MM2(0, 0) ST_B(1, pB) __syncthreads();
  // Ph4: MFMA T3 = W2k1 x H[:,64:128]; stage T4->B0; issue T5
  LD_W1(pB, 1, 1) MM2(1, 1) ST_B(0, pA) __syncthreads();
  // Ph5: MFMA T4 = W1cg1k0 (acc1 reset); stage T5->B1; issue T6
  LD_W2(pA, 2) ZACC1 MM1(0, 0) ST_B(1, pB) __syncthreads();
  // Ph6: MFMA T5 (acc1 cg1 done); EPI->H; stage T6->B0; issue T7
  LD_W2(pB, 3) MM1(1, 1) EPI(1) ST_B(0, pA) __syncthreads();
  // Ph7: MFMA T6 = W2k2 x H[:,0:64]; stage T7->B1
  MM2(0, 0) ST_B(1, pB) __syncthreads();
  // Ph8: MFMA T7 = W2k3 x H[:,64:128]
  MM2(1, 1)

  // ---- final epilogue: +b2, BN2 partial stats, coalesced C store (Ct = H) ----
  __syncthreads();  // all H reads done; reuse H as C staging tile
  unsigned short* Ct = H;
  if (tid < 128) { bsum[tid] = 0.f; bsq[tid] = 0.f; }
  float s8[8], q8[8];
#pragma unroll
  for (int j = 0; j < 8; ++j) { s8[j] = 0.f; q8[j] = 0.f; }
  int lrbase = wave * 32 + quad * 4;
#pragma unroll
  for (int cf = 0; cf < 8; ++cf) {
    float bv = b2_l[cf * 16 + l15];
#pragma unroll
    for (int g = 0; g < 4; ++g) {
      {
        int lr = lrbase + g;
        float e = acc2a[cf][g] + bv;
        Ct[lr * HP + cf * 16 + l15] = f2bf(e);
        if (row0 + lr < n) { s8[cf] += e; q8[cf] += e * e; }
      }
      {
        int lr = lrbase + 16 + g;
        float e = acc2b[cf][g] + bv;
        Ct[lr * HP + cf * 16 + l15] = f2bf(e);
        if (row0 + lr < n) { s8[cf] += e; q8[cf] += e * e; }
      }
    }
  }
#pragma unroll
  for (int cf = 0; cf < 8; ++cf) {
    s8[cf] += __shfl_xor(s8[cf], 16, 64);
    s8[cf] += __shfl_xor(s8[cf], 32, 64);
    q8[cf] += __shfl_xor(q8[cf], 16, 64);
    q8[cf] += __shfl_xor(q8[cf], 32, 64);
  }
  __syncthreads();  // Ct complete; bsum zeroed
  if (quad == 0) {
#pragma unroll
    for (int cf = 0; cf < 8; ++cf) {
      atomicAdd(&bsum[cf * 16 + l15], s8[cf]);
      atomicAdd(&bsq[cf * 16 + l15], q8[cf]);
    }
  }
#pragma unroll
  for (int it = 0; it < 8; ++it) {
    int f = tid + it * 512;
    int rr = f >> 4, cc = (f & 15) << 3;
    int gr = row0 + rr;
    if (gr < n)
      *(ushort8v*)(C + (size_t)gr * 128 + cc) = *(const ushort8v*)(&Ct[rr * HP + cc]);
  }
  __syncthreads();
  if (tid < 128) {
    psum[(size_t)blockIdx.x * 128 + tid] = bsum[tid];
    psq[(size_t)blockIdx.x * 128 + tid] = bsq[tid];
  }
#undef LD_W1
#undef LD_W2
#undef ST_B
#undef MM1
#undef MM2
#undef EPI
#undef ZACC1
}

// ---------------- column-stat reduce + BN finalize (one block per column) --------

__global__ __launch_bounds__(256) void k_finred(
    const float* __restrict__ psum, const float* __restrict__ psq, int nb, int nc,
    const float* __restrict__ g, const float* __restrict__ be,
    float* __restrict__ osc, float* __restrict__ osh, float invn) {
  __shared__ float ws[4], wq[4];
  int col = blockIdx.x;
  int t = threadIdx.x;
  float s = 0.f, q = 0.f;
  for (int b = t; b < nb; b += 256) {
    s += psum[(size_t)b * nc + col];
    q += psq[(size_t)b * nc + col];
  }
#pragma unroll
  for (int off = 32; off > 0; off >>= 1) {
    s += __shfl_xor(s, off, 64);
    q += __shfl_xor(q, off, 64);
  }
  if ((t & 63) == 0) { ws[t >> 6] = s; wq[t >> 6] = q; }
  __syncthreads();
  if (t == 0) {
    s = ws[0] + ws[1] + ws[2] + ws[3];
    q = wq[0] + wq[1] + wq[2] + wq[3];
    float m = s * invn;
    float v = fmaxf(q * invn - m * m, 0.f);
    float sc = g[col] * rsqrtf(v + BN_EPS);
    osc[col] = sc;
    osh[col] = be[col] - m * sc;
  }
}

// ---------------- classifier z1 stats (sum & sumsq from one array) ----------------

__global__ __launch_bounds__(256) void k_statz(
    const float* __restrict__ z1, const float* __restrict__ g,
    const float* __restrict__ be, float* __restrict__ osc, float* __restrict__ osh) {
  __shared__ float ws[4], wq[4];
  int col = blockIdx.x;
  int t = threadIdx.x;
  float s = 0.f, q = 0.f;
  for (int b = t; b < GG; b += 256) {
    float v = z1[(size_t)b * 128 + col];
    s += v;
    q += v * v;
  }
#pragma unroll
  for (int off = 32; off > 0; off >>= 1) {
    s += __shfl_xor(s, off, 64);
    q += __shfl_xor(q, off, 64);
  }
  if ((t & 63) == 0) { ws[t >> 6] = s; wq[t >> 6] = q; }
  __syncthreads();
  if (t == 0) {
    s = ws[0] + ws[1] + ws[2] + ws[3];
    q = wq[0] + wq[1] + wq[2] + wq[3];
    float m = s / (float)GG;
    float v = fmaxf(q / (float)GG - m * m, 0.f);
    float sc = g[col] * rsqrtf(v + BN_EPS);
    osc[col] = sc;
    osh[col] = be[col] - m * sc;
  }
}

// ---------------- pooling (batch sorted -> contiguous ranges), bf16 X ------------

static __device__ __forceinline__ int lb_i32(const int* a, int n, int key) {
  int lo = 0, hi = n;
  while (lo < hi) {
    int mid = (lo + hi) >> 1;
    if (a[mid] < key) lo = mid + 1; else hi = mid;
  }
  return lo;
}

__global__ __launch_bounds__(512) void k_pool(
    const unsigned short* __restrict__ X, const int* __restrict__ batch,
    const float* __restrict__ tsc, const float* __restrict__ tsh,
    float* __restrict__ z, int n) {
  __shared__ int slo, shi;
  __shared__ float ssum[8][128], smax[8][128];
  int g = blockIdx.x;
  int t = threadIdx.x;
  int sg = t >> 6;           // 0..7 row-subgroup
  int c2 = (t & 63) << 1;    // column pair base
  if (t == 0) {
    slo = lb_i32(batch, n, g);
    shi = lb_i32(batch, n, g + 1);
  }
  __syncthreads();
  int lo = slo, hi = shi;
  float a0 = tsc[c2], a1 = tsc[c2 + 1];
  float b0 = tsh[c2], b1 = tsh[c2 + 1];
  float s0 = 0.f, s1 = 0.f;
  float m0 = -3.402823466e38f, m1 = -3.402823466e38f;
  for (int i = lo + sg; i < hi; i += 8) {
    unsigned u = *(const unsigned*)(X + (size_t)i * DD + c2);
    float v0 = fmaxf(0.f, bf2f((unsigned short)(u & 0xffff)) * a0 + b0);
    float v1 = fmaxf(0.f, bf2f((unsigned short)(u >> 16)) * a1 + b1);
    s0 += v0; m0 = fmaxf(m0, v0);
    s1 += v1; m1 = fmaxf(m1, v1);
  }
  ssum[sg][c2] = s0; ssum[sg][c2 + 1] = s1;
  smax[sg][c2] = m0; smax[sg][c2 + 1] = m1;
  __syncthreads();
  if (t < 128) {
    float S = 0.f, M = -3.402823466e38f;
#pragma unroll
    for (int k = 0; k < 8; ++k) {
      S += ssum[k][t];
      M = fmaxf(M, smax[k][t]);
    }
    float cntf = (float)(hi - lo);
    z[(size_t)g * 384 + t] = S;
    z[(size_t)g * 384 + 128 + t] = S / fmaxf(cntf, 1.f);
    z[(size_t)g * 384 + 256 + t] = M;
  }
}

// ---------------- classifier head (fp32, tiny; no atomics) ----------------

__global__ void k_cls1(const float* __restrict__ z, const float* __restrict__ cW1,
                       const float* __restrict__ cb1, float* __restrict__ z1) {
  __shared__ float zr[384];
  int g = blockIdx.x;
  int c = threadIdx.x;  // 128
  for (int i = c; i < 384; i += 128) zr[i] = z[(size_t)g * 384 + i];
  __syncthreads();
  float s = cb1[c];
#pragma unroll 4
  for (int k = 0; k < 384; ++k) s = fmaf(zr[k], cW1[(size_t)k * 128 + c], s);
  z1[(size_t)g * 128 + c] = s;
}

__global__ void k_cls2(const float* __restrict__ z1, const float* __restrict__ csc,
                       const float* __restrict__ csh, const float* __restrict__ cW2,
                       const float* __restrict__ cb2, const float* __restrict__ cW3,
                       const float* __restrict__ cb3, float* __restrict__ out) {
  __shared__ float z1n[128];
  __shared__ float z2s[64];
  int g = blockIdx.x;
  int t = threadIdx.x;  // 128
  z1n[t] = fmaxf(0.f, z1[(size_t)g * 128 + t] * csc[t] + csh[t]);
  __syncthreads();
  if (t < 64) {
    float s = cb2[t];
#pragma unroll 4
    for (int k = 0; k < 128; ++k) s = fmaf(z1n[k], cW2[(size_t)k * 64 + t], s);
    z2s[t] = fmaxf(0.f, s);
  }
  __syncthreads();
  if (t < 2) {
    float s = cb3[t];
#pragma unroll 4
    for (int c = 0; c < 64; ++c) s = fmaf(z2s[c], cW3[(size_t)c * 2 + t], s);
    out[(size_t)g * 2 + t] = s;
  }
}

// ---------------- launch ----------------

extern "C" void kernel_launch(void* const* d_in, const int* in_sizes, int n_in,
                              void* d_out, int out_size, void* d_ws, size_t ws_size,
                              hipStream_t stream) {
  const float* x = (const float*)d_in[0];
  const int* ei = (const int*)d_in[1];     // int32 (harness downcasts int64)
  const int* batch = (const int*)d_in[2];  // int32
  const float* W1 = (const float*)d_in[4];
  const float* b1 = (const float*)d_in[5];
  const float* g1 = (const float*)d_in[6];
  const float* be1 = (const float*)d_in[7];
  const float* W2 = (const float*)d_in[8];
  const float* b2 = (const float*)d_in[9];
  const float* gbn = (const float*)d_in[10];
  const float* bbn = (const float*)d_in[11];
  const float* epsv = (const float*)d_in[12];
  const float* cW1 = (const float*)d_in[13];
  const float* cb1 = (const float*)d_in[14];
  const float* cg = (const float*)d_in[15];
  const float* cbeta = (const float*)d_in[16];
  const float* cW2 = (const float*)d_in[17];
  const float* cb2 = (const float*)d_in[18];
  const float* cW3 = (const float*)d_in[19];
  const float* cb3 = (const float*)d_in[20];
  float* out = (float*)d_out;
  (void)b1;  // BN1 shift is independent of b1 (cancels in (y - mean))

  char* p = (char*)d_ws;
  auto alloc = [&](size_t bytes) {
    char* r = p;
    p += (bytes + 255) & ~(size_t)255;
    return r;
  };
  const int NB2 = (NN + 255) / 256;  // 391 fused GEMM row-blocks
  int* cnt = (int*)alloc((size_t)NN * 4);
  int* rs = (int*)alloc((size_t)(NN + 1) * 4);
  int* cur = (int*)alloc((size_t)NN * 4);
  int* ci = (int*)alloc((size_t)EE * 4);
  int* part = (int*)alloc(128 * 4);
  int* partx = (int*)alloc(128 * 4);
  unsigned short* xbf = (unsigned short*)alloc((size_t)NN * DD * 2);
  unsigned short* h0 = (unsigned short*)alloc((size_t)NN * DD * 2);
  unsigned short* xp = (unsigned short*)alloc((size_t)NN * DD * 2);
  float* psum = (float*)alloc((size_t)NB2 * 128 * 4);
  float* psq = (float*)alloc((size_t)NB2 * 128 * 4);
  float* tsc1 = (float*)alloc(256 * 4);
  float* tsh1 = (float*)alloc(256 * 4);
  float* tscX = (float*)alloc(128 * 4);
  float* tshX = (float*)alloc(128 * 4);
  float* zbuf = (float*)alloc((size_t)GG * 384 * 4);
  float* z1 = (float*)alloc((size_t)GG * 128 * 4);
  unsigned short* W1t = (unsigned short*)alloc((size_t)4 * 256 * 128 * 2);
  unsigned short* W2t = (unsigned short*)alloc((size_t)4 * 128 * 256 * 2);
  float* M2s = (float*)alloc((size_t)196 * 16384 * 4);  // per-block slabs
  float* css = (float*)alloc((size_t)196 * 128 * 4);
  float* M2f = (float*)alloc((size_t)128 * 128 * 4);
  float* csf = (float*)alloc(128 * 4);
  (void)ws_size; (void)n_in; (void)in_sizes; (void)out_size;

  // weight convert+transpose to bf16 (static across layers/calls)
  k_conv<<<512, 256, 0, stream>>>(W1, W2, W1t, W2t);
  // x -> bf16
  k_x2bf<<<(NN * DD / 4 + 255) / 256, 256, 0, stream>>>(x, xbf);

  // CSR build (edges static across layers)
  hipMemsetAsync(cnt, 0, (size_t)NN * 4, stream);
  k_hist<<<(EE + 255) / 256, 256, 0, stream>>>(ei, cnt);
  const int nscan = (NN + 1023) / 1024;  // 98
  k_part<<<nscan, 1024, 0, stream>>>(cnt, part);
  k_scanpart<<<1, 128, 0, stream>>>(part, partx, nscan);
  k_rs<<<nscan, 1024, 0, stream>>>(cnt, partx, rs, cur);
  k_fill<<<(EE + 255) / 256, 256, 0, stream>>>(ei, cur, ci);

  for (int l = 0; l < LL; ++l) {
    const unsigned short* Xl = (l == 0) ? xbf : xp;
    k_agg_bf16<<<(NN * 16 + 255) / 256, 256, 0, stream>>>(
        Xl, rs, ci, epsv, l, (l > 0) ? 1 : 0, tscX, tshX, h0, NN);
    // analytic BN1 stats: M2 = h0^T h0 (196 reg-accum slabs); fold; scale/shift
    k_mom<<<196, 512, 0, stream>>>(h0, M2s, css, NN);
    k_red<<<64, 256, 0, stream>>>(M2s, css, M2f, csf);
    k_bn1<<<256, 128, 0, stream>>>(M2f, csf, W1t + (size_t)l * 256 * 128,
                                   g1 + (size_t)l * 256, be1 + (size_t)l * 256,
                                   tsc1, tsh1);
    // fused GEMM1+BN1+ReLU+GEMM2 (h1 never touches HBM), 256 rows/block
    k_gfused<<<NB2, 512, 0, stream>>>(
        h0, tsc1, tsh1, W1t + (size_t)l * 256 * 128, W2t + (size_t)l * 128 * 256,
        b2 + (size_t)l * 128, xp, psum, psq, NN);
    k_finred<<<128, 256, 0, stream>>>(psum, psq, NB2, 128, gbn + (size_t)l * 128,
                                      bbn + (size_t)l * 128, tscX, tshX, 1.0f / NN);
  }

  k_pool<<<GG, 512, 0, stream>>>(xp, batch, tscX, tshX, zbuf, NN);
  k_cls1<<<GG, 128, 0, stream>>>(zbuf, cW1, cb1, z1);
  k_statz<<<128, 256, 0, stream>>>(z1, cg, cbeta, tscX, tshX);
  k_cls2<<<GG, 128, 0, stream>>>(z1, tscX, tshX, cW2, cb2, cW3, cb3, out);
}

// Round 6
// 681.736 us; speedup vs baseline: 1.2654x; 1.0460x over previous
//
#include <hip/hip_runtime.h>
#include <cstdint>
#include <cstddef>

// Problem constants (fixed by the reference setup_inputs).
#define NN 100000
#define EE 500000
#define DD 128
#define GG 512
#define LL 4
#define BN_EPS 1e-5f

typedef __attribute__((ext_vector_type(8))) short short8;
typedef __attribute__((ext_vector_type(8))) unsigned short ushort8v;
typedef __attribute__((ext_vector_type(4))) float f32x4;

static __device__ __forceinline__ unsigned short f2bf(float f) {
  union { float f; unsigned u; } v;
  v.f = f;
  unsigned r = v.u + 0x7fffu + ((v.u >> 16) & 1u);  // RNE
  return (unsigned short)(r >> 16);
}
static __device__ __forceinline__ float bf2f(unsigned short u) {
  union { unsigned u; float f; } v;
  v.u = ((unsigned)u) << 16;
  return v.f;
}

// ---------------- CSR build (int32 inputs) ----------------

__global__ void k_hist(const int* __restrict__ ei, int* __restrict__ cnt) {
  int e = blockIdx.x * 256 + threadIdx.x;
  if (e < EE) {
    int d = ei[EE + e];
    if (d >= 0 && d < NN) atomicAdd(&cnt[d], 1);
  }
}

__global__ void k_part(const int* __restrict__ cnt, int* __restrict__ part) {
  __shared__ int sm[1024];
  int t = threadIdx.x;
  int i = blockIdx.x * 1024 + t;
  sm[t] = (i < NN) ? cnt[i] : 0;
  __syncthreads();
  for (int off = 512; off > 0; off >>= 1) {
    if (t < off) sm[t] += sm[t + off];
    __syncthreads();
  }
  if (t == 0) part[blockIdx.x] = sm[0];
}

__global__ void k_scanpart(const int* __restrict__ part, int* __restrict__ partx, int nb) {
  __shared__ int sm[128];
  int t = threadIdx.x;
  int v = (t < nb) ? part[t] : 0;
  sm[t] = v;
  __syncthreads();
  for (int off = 1; off < 128; off <<= 1) {
    int u = (t >= off) ? sm[t - off] : 0;
    __syncthreads();
    sm[t] += u;
    __syncthreads();
  }
  if (t < nb) partx[t] = sm[t] - v;
}

__global__ void k_rs(const int* __restrict__ cnt, const int* __restrict__ partx,
                     int* __restrict__ rs, int* __restrict__ cur) {
  __shared__ int sm[1024];
  int t = threadIdx.x;
  int i = blockIdx.x * 1024 + t;
  int v = (i < NN) ? cnt[i] : 0;
  sm[t] = v;
  __syncthreads();
  for (int off = 1; off < 1024; off <<= 1) {
    int u = (t >= off) ? sm[t - off] : 0;
    __syncthreads();
    sm[t] += u;
    __syncthreads();
  }
  if (i < NN) {
    int excl = partx[blockIdx.x] + sm[t] - v;
    rs[i] = excl;
    cur[i] = excl;
    if (i == NN - 1) rs[NN] = excl + v;
  }
}

__global__ void k_fill(const int* __restrict__ ei, int* __restrict__ cur,
                       int* __restrict__ ci) {
  int e = blockIdx.x * 256 + threadIdx.x;
  if (e < EE) {
    int s = ei[e];
    int d = ei[EE + e];
    if (d >= 0 && d < NN && s >= 0 && s < NN) {
      int pos = atomicAdd(&cur[d], 1);
      if (pos >= 0 && pos < EE) ci[pos] = s;  // order irrelevant (sum)
    }
  }
}

// ---------------- weight convert: W -> W^T bf16 + cW1 -> cW1t fp32 ----------------

__global__ void k_conv(const float* __restrict__ W1, const float* __restrict__ W2,
                       const float* __restrict__ cW1, unsigned short* __restrict__ W1t,
                       unsigned short* __restrict__ W2t, float* __restrict__ cW1t) {
  int idx = blockIdx.x * 256 + threadIdx.x;
  if (idx < 4 * 256 * 128) {
    {  // W1: [l][k][nc] (K=128,NC=256) -> [l][nc][k]
      int l = idx >> 15, rem = idx & 32767;
      int nc = rem >> 7, k = rem & 127;
      W1t[idx] = f2bf(W1[(l << 15) + k * 256 + nc]);
    }
    {  // W2: [l][k][nc] (K=256,NC=128) -> [l][nc][k]
      int l = idx >> 15, rem = idx & 32767;
      int nc = rem >> 8, k = rem & 255;
      W2t[idx] = f2bf(W2[(l << 15) + k * 128 + nc]);
    }
  }
  if (idx < 128 * 384) {  // cW1: [k][c] -> [c][k] fp32 (for k_cls1 row loads)
    int c = idx / 384, k = idx - c * 384;
    cW1t[idx] = cW1[(size_t)k * 128 + c];
  }
}

// ---------------- x -> bf16 convert (streaming, once per call) ----------------

__global__ void k_x2bf(const float* __restrict__ x, unsigned short* __restrict__ xb) {
  int i = blockIdx.x * 256 + threadIdx.x;
  if (i < NN * DD / 4) {
    float4 v = *(const float4*)(x + (size_t)i * 4);
    ushort4 o;
    o.x = f2bf(v.x); o.y = f2bf(v.y); o.z = f2bf(v.z); o.w = f2bf(v.w);
    *(ushort4*)(xb + (size_t)i * 4) = o;
  }
}

// ---------------- aggregation v2: 4-deep neighbor prefetch ----------------
// 16 lanes/node, ushort8 (16B) loads. Random-gather latency chain (avg degree 5):
// 4 named prefetch regs (static indexing, no scratch) keep 4 loads in flight.

__global__ __launch_bounds__(256) void k_agg_bf16(
    const unsigned short* __restrict__ X, const int* __restrict__ rs,
    const int* __restrict__ ci, const float* __restrict__ epsv, int l, int mode,
    const float* __restrict__ tsc, const float* __restrict__ tsh,
    unsigned short* __restrict__ h0, int n) {
  int idx = blockIdx.x * 256 + threadIdx.x;
  int node = idx >> 4;
  int c8 = (idx & 15) << 3;
  if (node >= n) return;
  float sa[8], sb[8];
  if (mode) {
    float4 a0 = *(const float4*)(tsc + c8), a1 = *(const float4*)(tsc + c8 + 4);
    float4 b0 = *(const float4*)(tsh + c8), b1 = *(const float4*)(tsh + c8 + 4);
    sa[0] = a0.x; sa[1] = a0.y; sa[2] = a0.z; sa[3] = a0.w;
    sa[4] = a1.x; sa[5] = a1.y; sa[6] = a1.z; sa[7] = a1.w;
    sb[0] = b0.x; sb[1] = b0.y; sb[2] = b0.z; sb[3] = b0.w;
    sb[4] = b1.x; sb[5] = b1.y; sb[6] = b1.z; sb[7] = b1.w;
  }
  float se = 1.f + epsv[l];
  ushort8v v = *(const ushort8v*)(X + (size_t)node * DD + c8);
  float acc[8];
#pragma unroll
  for (int j = 0; j < 8; ++j) {
    float f = bf2f(v[j]);
    if (mode) f = fmaxf(0.f, f * sa[j] + sb[j]);
    acc[j] = se * f;
  }
  int e0 = rs[node], e1 = rs[node + 1];
#define NLD(ee) (*(const ushort8v*)(X + (size_t)ci[ee] * DD + c8))
#define NACC(uc)                                                  \
  {                                                               \
    _Pragma("unroll") for (int j = 0; j < 8; ++j) {               \
      float f = bf2f(uc[j]);                                      \
      if (mode) f = fmaxf(0.f, f * sa[j] + sb[j]);                \
      acc[j] += f;                                                \
    }                                                             \
  }
  ushort8v p0 = (ushort8v){0, 0, 0, 0, 0, 0, 0, 0};
  ushort8v p1 = p0, p2 = p0, p3 = p0;
  if (e0 + 0 < e1) p0 = NLD(e0 + 0);
  if (e0 + 1 < e1) p1 = NLD(e0 + 1);
  if (e0 + 2 < e1) p2 = NLD(e0 + 2);
  if (e0 + 3 < e1) p3 = NLD(e0 + 3);
  for (int e = e0; e < e1; e += 4) {
    ushort8v c0 = p0, c1 = p1, c2 = p2, c3 = p3;
    if (e + 4 < e1) p0 = NLD(e + 4);
    if (e + 5 < e1) p1 = NLD(e + 5);
    if (e + 6 < e1) p2 = NLD(e + 6);
    if (e + 7 < e1) p3 = NLD(e + 7);
    NACC(c0);
    if (e + 1 < e1) NACC(c1);
    if (e + 2 < e1) NACC(c2);
    if (e + 3 < e1) NACC(c3);
  }
#undef NLD
#undef NACC
  ushort8v o;
#pragma unroll
  for (int j = 0; j < 8; ++j) o[j] = f2bf(acc[j]);
  *(ushort8v*)(h0 + (size_t)node * DD + c8) = o;
}

// ---------------- M2 = h0^T h0 (128x128) + colsum(h0), for analytic BN1 stats ----
// 196 persistent blocks grid-stride over 391 chunks of 256 rows; register M2
// accumulation; one non-atomic 64KB slab write per block. XOR block-swizzle on
// the transposed staging cuts write bank conflicts to ~4-way.

__global__ __launch_bounds__(512) void k_mom(
    const unsigned short* __restrict__ h0, float* __restrict__ M2s,
    float* __restrict__ css, int n) {
  constexpr int HT = 264;
  constexpr int NCH = (NN + 255) / 256;  // 391
  constexpr int NBLK = 196;
  __shared__ __align__(16) unsigned short Ht[128 * HT];  // 67584 B
  __shared__ float lcs[128];
  int tid = threadIdx.x;
  int lane = tid & 63, wave = tid >> 6;
  int quad = lane >> 4, l15 = lane & 15;
  if (tid < 128) lcs[tid] = 0.f;
  int c8 = (tid & 15) << 3;
  int rloc = tid >> 4;  // 0..31
  float csr[8];
#pragma unroll
  for (int j = 0; j < 8; ++j) csr[j] = 0.f;
  f32x4 acc[8];
#pragma unroll
  for (int j = 0; j < 8; ++j) acc[j] = (f32x4){0.f, 0.f, 0.f, 0.f};

  for (int ch = blockIdx.x; ch < NCH; ch += NBLK) {
    int n0 = ch * 256;
    __syncthreads();  // prev chunk's MFMA reads done (also covers lcs zeroing)
#pragma unroll
    for (int pass = 0; pass < 8; ++pass) {
      int nl = rloc + pass * 32;  // 0..255
      int gr = n0 + nl;
      ushort8v v = (ushort8v){0, 0, 0, 0, 0, 0, 0, 0};
      if (gr < n) v = *(const ushort8v*)(h0 + (size_t)gr * DD + c8);
#pragma unroll
      for (int j = 0; j < 8; ++j) {
        int row = c8 + j;
        int sb = (nl >> 3) ^ ((row >> 3) & 7);
        Ht[row * HT + (sb << 3) + (nl & 7)] = v[j];
        csr[j] += bf2f(v[j]);
      }
    }
    __syncthreads();
#pragma unroll
    for (int kc = 0; kc < 8; ++kc) {
      int b = kc * 4 + quad;  // 8-elem block index of ko = kc*32 + quad*8
      int arow = wave * 16 + l15;
      short8 avv =
          *(const short8*)(&Ht[arow * HT + ((b ^ ((arow >> 3) & 7)) << 3)]);
#pragma unroll
      for (int j = 0; j < 8; ++j) {
        int brow = j * 16 + l15;
        short8 bvv =
            *(const short8*)(&Ht[brow * HT + ((b ^ ((brow >> 3) & 7)) << 3)]);
        acc[j] = __builtin_amdgcn_mfma_f32_16x16x32_bf16(avv, bvv, acc[j], 0, 0, 0);
      }
    }
  }
  // slab write (block-private, non-atomic)
  float* M2 = M2s + (size_t)blockIdx.x * 16384;
  int lr = wave * 16 + quad * 4;
#pragma unroll
  for (int j = 0; j < 8; ++j)
#pragma unroll
    for (int g = 0; g < 4; ++g)
      M2[(lr + g) * 128 + j * 16 + l15] = acc[j][g];
#pragma unroll
  for (int j = 0; j < 8; ++j) atomicAdd(&lcs[c8 + j], csr[j]);
  __syncthreads();
  if (tid < 128) css[(size_t)blockIdx.x * 128 + tid] = lcs[tid];
}

// fold the 196 slabs
__global__ void k_red(const float* __restrict__ M2s, const float* __restrict__ css,
                      float* __restrict__ M2f, float* __restrict__ csf) {
  int i = blockIdx.x * 256 + threadIdx.x;  // 64 blocks -> 16384
  float s = 0.f;
  for (int k = 0; k < 196; ++k) s += M2s[(size_t)k * 16384 + i];
  M2f[i] = s;
  if (i < 128) {
    float c = 0.f;
    for (int k = 0; k < 196; ++k) c += css[(size_t)k * 128 + i];
    csf[i] = c;
  }
}

// analytic BN1 scale/shift: var_c = w^T M2 w / N - (colsum.w/N)^2  (b1 cancels)
__global__ __launch_bounds__(128) void k_bn1(
    const float* __restrict__ M2, const float* __restrict__ cs,
    const unsigned short* __restrict__ W1t_l, const float* __restrict__ g1_l,
    const float* __restrict__ be1_l, float* __restrict__ osc,
    float* __restrict__ osh) {
  __shared__ float wsh[128];
  __shared__ float red1[2], red2[2];
  int c = blockIdx.x, t = threadIdx.x;
  float w = bf2f(W1t_l[c * 128 + t]);
  wsh[t] = w;
  __syncthreads();
  float inner = 0.f;
#pragma unroll 4
  for (int k = 0; k < 128; ++k) inner = fmaf(M2[t * 128 + k], wsh[k], inner);
  float s1 = w * inner;
  float s2 = w * cs[t];
#pragma unroll
  for (int off = 32; off > 0; off >>= 1) {
    s1 += __shfl_xor(s1, off, 64);
    s2 += __shfl_xor(s2, off, 64);
  }
  if ((t & 63) == 0) { red1[t >> 6] = s1; red2[t >> 6] = s2; }
  __syncthreads();
  if (t == 0) {
    float q = (red1[0] + red1[1]) * (1.0f / NN);
    float um = (red2[0] + red2[1]) * (1.0f / NN);
    float var = fmaxf(q - um * um, 0.f);
    float sc = g1_l[c] * rsqrtf(var + BN_EPS);
    osc[c] = sc;
    osh[c] = be1_l[c] - um * sc;
  }
}

// ---------------- fused GEMM1+BN1+ReLU+GEMM2, v3: 256 rows/block ----------------
// 8 waves x 32 rows (2 row-groups of 16). Each B-fragment ds_read feeds TWO MFMAs
// (one per row-group) -> LDS B-read traffic per output HALVES vs v2; barriers per
// output halve. A rows in registers (av0/av1). B double-buffered; 8 MFMA phases,
// loads issued one phase ahead. LDS 107.5KB -> 1 block/CU. Grid 391.

__global__ __launch_bounds__(512, 2) void k_gfused(
    const unsigned short* __restrict__ A, const float* __restrict__ sc1,
    const float* __restrict__ sh1, const unsigned short* __restrict__ W1t_l,
    const unsigned short* __restrict__ W2t_l, const float* __restrict__ b2_l,
    unsigned short* __restrict__ C, float* __restrict__ psum,
    float* __restrict__ psq, int n) {
  constexpr int BST = 72;  // B row stride (ushorts), 144B
  constexpr int HP = 136;  // H row stride (ushorts), 272B
  __shared__ __align__(16) unsigned short Bsm[2][128 * BST];  // 36864 B
  __shared__ __align__(16) unsigned short H[256 * HP];        // 69632 B
  __shared__ float bsum[128], bsq[128];

  int tid = threadIdx.x;
  int lane = tid & 63, wave = tid >> 6;
  int quad = lane >> 4, l15 = lane & 15;
  int row0 = blockIdx.x * 256;
  int r0 = row0 + wave * 32 + l15;
  int r1 = r0 + 16;

  // A row fragments in registers: 2 row-groups x 4 k-slices
  short8 av0[4], av1[4];
#pragma unroll
  for (int ks = 0; ks < 4; ++ks) {
    av0[ks] = (short8){0, 0, 0, 0, 0, 0, 0, 0};
    av1[ks] = (short8){0, 0, 0, 0, 0, 0, 0, 0};
    if (r0 < n) av0[ks] = *(const short8*)(A + (size_t)r0 * 128 + ks * 32 + quad * 8);
    if (r1 < n) av1[ks] = *(const short8*)(A + (size_t)r1 * 128 + ks * 32 + quad * 8);
  }

  ushort8v pA[2], pB[2];  // alternating prefetch register sets
  f32x4 acc1a[8], acc1b[8], acc2a[8], acc2b[8];
#pragma unroll
  for (int j = 0; j < 8; ++j) {
    acc1a[j] = (f32x4){0.f, 0.f, 0.f, 0.f};
    acc1b[j] = (f32x4){0.f, 0.f, 0.f, 0.f};
    acc2a[j] = (f32x4){0.f, 0.f, 0.f, 0.f};
    acc2b[j] = (f32x4){0.f, 0.f, 0.f, 0.f};
  }

#define LD_W1(dst, cg, kc)                                                      \
  {                                                                             \
    _Pragma("unroll") for (int it = 0; it < 2; ++it) {                          \
      int f = tid + it * 512, rr = f >> 3, cc = (f & 7) << 3;                   \
      dst[it] = *(const ushort8v*)(W1t_l + (size_t)((cg)*128 + rr) * 128 +      \
                                   (kc)*64 + cc);                               \
    }                                                                           \
  }
#define LD_W2(dst, kc2)                                                         \
  {                                                                             \
    _Pragma("unroll") for (int it = 0; it < 2; ++it) {                          \
      int f = tid + it * 512, rr = f >> 3, cc = (f & 7) << 3;                   \
      dst[it] = *(const ushort8v*)(W2t_l + (size_t)rr * 256 + (kc2)*64 + cc);   \
    }                                                                           \
  }
#define ST_B(buf, src)                                                          \
  {                                                                             \
    _Pragma("unroll") for (int it = 0; it < 2; ++it) {                          \
      int f = tid + it * 512, rr = f >> 3, cc = (f & 7) << 3;                   \
      *(ushort8v*)(&Bsm[buf][rr * BST + cc]) = src[it];                         \
    }                                                                           \
  }
#define MM1(buf, k2)                                                            \
  {                                                                             \
    _Pragma("unroll") for (int kk = 0; kk < 2; ++kk) {                          \
      int ko = kk * 32 + quad * 8;                                              \
      short8 a0 = av0[(k2)*2 + kk];                                             \
      short8 a1 = av1[(k2)*2 + kk];                                             \
      _Pragma("unroll") for (int cf = 0; cf < 8; ++cf) {                        \
        short8 bv = *(const short8*)(&Bsm[buf][(cf * 16 + l15) * BST + ko]);    \
        acc1a[cf] = __builtin_amdgcn_mfma_f32_16x16x32_bf16(a0, bv, acc1a[cf],  \
                                                            0, 0, 0);           \
        acc1b[cf] = __builtin_amdgcn_mfma_f32_16x16x32_bf16(a1, bv, acc1b[cf],  \
                                                            0, 0, 0);           \
      }                                                                         \
    }                                                                           \
  }
#define MM2(buf, half)                                                          \
  {                                                                             \
    _Pragma("unroll") for (int kk = 0; kk < 64; kk += 32) {                     \
      int ko = kk + quad * 8;                                                   \
      short8 a0 =                                                               \
          *(const short8*)(&H[(wave * 32 + l15) * HP + (half)*64 + ko]);        \
      short8 a1 =                                                               \
          *(const short8*)(&H[(wave * 32 + 16 + l15) * HP + (half)*64 + ko]);   \
      _Pragma("unroll") for (int cf = 0; cf < 8; ++cf) {                        \
        short8 bv = *(const short8*)(&Bsm[buf][(cf * 16 + l15) * BST + ko]);    \
        acc2a[cf] = __builtin_amdgcn_mfma_f32_16x16x32_bf16(a0, bv, acc2a[cf],  \
                                                            0, 0, 0);           \
        acc2b[cf] = __builtin_amdgcn_mfma_f32_16x16x32_bf16(a1, bv, acc2b[cf],  \
                                                            0, 0, 0);           \
      }                                                                         \
    }                                                                           \
  }
#define EPI(cg)                                                                 \
  {                                                                             \
    int lrb = wave * 32 + quad * 4;                                             \
    _Pragma("unroll") for (int cf = 0; cf < 8; ++cf) {                          \
      int col = (cg)*128 + cf * 16 + l15;                                       \
      float sc = sc1[col], sh = sh1[col];                                       \
      _Pragma("unroll") for (int g = 0; g < 4; ++g) {                           \
        H[(lrb + g) * HP + cf * 16 + l15] =                                     \
            f2bf(fmaxf(0.f, acc1a[cf][g] * sc + sh));                           \
        H[(lrb + 16 + g) * HP + cf * 16 + l15] =                                \
            f2bf(fmaxf(0.f, acc1b[cf][g] * sc + sh));                           \
      }                                                                         \
    }                                                                           \
  }
#define ZACC1                                                                   \
  {                                                                             \
    _Pragma("unroll") for (int j = 0; j < 8; ++j) {                             \
      acc1a[j] = (f32x4){0.f, 0.f, 0.f, 0.f};                                   \
      acc1b[j] = (f32x4){0.f, 0.f, 0.f, 0.f};                                   \
    }                                                                           \
  }

  // prologue: T0 -> B0 (immediate), T1 loads in flight
  LD_W1(pA, 0, 0)
  LD_W1(pB, 0, 1)
  ST_B(0, pA)
  __syncthreads();
  // Ph1: MFMA T0; stage T1->B1; issue T2
  LD_W2(pA, 0) MM1(0, 0) ST_B(1, pB) __syncthreads();
  // Ph2: MFMA T1 (acc1 cg0 done); EPI->H; stage T2->B0; issue T3
  LD_W2(pB, 1) MM1(1, 1) EPI(0) ST_B(0, pA) __syncthreads();
  // Ph3: MFMA T2 = W2k0 x H[:,0:64]; stage T3->B1; issue T4
  LD_W1(pA, 1, 0) MM2(0, 0) ST_B(1, pB) __syncthreads();
  // Ph4: MFMA T3 = W2k1 x H[:,64:128]; stage T4->B0; issue T5
  LD_W1(pB, 1, 1) MM2(1, 1) ST_B(0, pA) __syncthreads();
  // Ph5: MFMA T4 = W1cg1k0 (acc1 reset); stage T5->B1; issue T6
  LD_W2(pA, 2) ZACC1 MM1(0, 0) ST_B(1, pB) __syncthreads();
  // Ph6: MFMA T5 (acc1 cg1 done); EPI->H; stage T6->B0; issue T7
  LD_W2(pB, 3) MM1(1, 1) EPI(1) ST_B(0, pA) __syncthreads();
  // Ph7: MFMA T6 = W2k2 x H[:,0:64]; stage T7->B1
  MM2(0, 0) ST_B(1, pB) __syncthreads();
  // Ph8: MFMA T7 = W2k3 x H[:,64:128]
  MM2(1, 1)

  // ---- final epilogue: +b2, BN2 partial stats, coalesced C store (Ct = H) ----
  __syncthreads();  // all H reads done; reuse H as C staging tile
  unsigned short* Ct = H;
  if (tid < 128) { bsum[tid] = 0.f; bsq[tid] = 0.f; }
  float s8[8], q8[8];
#pragma unroll
  for (int j = 0; j < 8; ++j) { s8[j] = 0.f; q8[j] = 0.f; }
  int lrbase = wave * 32 + quad * 4;
#pragma unroll
  for (int cf = 0; cf < 8; ++cf) {
    float bv = b2_l[cf * 16 + l15];
#pragma unroll
    for (int g = 0; g < 4; ++g) {
      {
        int lr = lrbase + g;
        float e = acc2a[cf][g] + bv;
        Ct[lr * HP + cf * 16 + l15] = f2bf(e);
        if (row0 + lr < n) { s8[cf] += e; q8[cf] += e * e; }
      }
      {
        int lr = lrbase + 16 + g;
        float e = acc2b[cf][g] + bv;
        Ct[lr * HP + cf * 16 + l15] = f2bf(e);
        if (row0 + lr < n) { s8[cf] += e; q8[cf] += e * e; }
      }
    }
  }
#pragma unroll
  for (int cf = 0; cf < 8; ++cf) {
    s8[cf] += __shfl_xor(s8[cf], 16, 64);
    s8[cf] += __shfl_xor(s8[cf], 32, 64);
    q8[cf] += __shfl_xor(q8[cf], 16, 64);
    q8[cf] += __shfl_xor(q8[cf], 32, 64);
  }
  __syncthreads();  // Ct complete; bsum zeroed
  if (quad == 0) {
#pragma unroll
    for (int cf = 0; cf < 8; ++cf) {
      atomicAdd(&bsum[cf * 16 + l15], s8[cf]);
      atomicAdd(&bsq[cf * 16 + l15], q8[cf]);
    }
  }
#pragma unroll
  for (int it = 0; it < 8; ++it) {
    int f = tid + it * 512;
    int rr = f >> 4, cc = (f & 15) << 3;
    int gr = row0 + rr;
    if (gr < n)
      *(ushort8v*)(C + (size_t)gr * 128 + cc) = *(const ushort8v*)(&Ct[rr * HP + cc]);
  }
  __syncthreads();
  if (tid < 128) {
    psum[(size_t)blockIdx.x * 128 + tid] = bsum[tid];
    psq[(size_t)blockIdx.x * 128 + tid] = bsq[tid];
  }
#undef LD_W1
#undef LD_W2
#undef ST_B
#undef MM1
#undef MM2
#undef EPI
#undef ZACC1
}

// ---------------- column-stat reduce + BN finalize (one block per column) --------

__global__ __launch_bounds__(256) void k_finred(
    const float* __restrict__ psum, const float* __restrict__ psq, int nb, int nc,
    const float* __restrict__ g, const float* __restrict__ be,
    float* __restrict__ osc, float* __restrict__ osh, float invn) {
  __shared__ float ws[4], wq[4];
  int col = blockIdx.x;
  int t = threadIdx.x;
  float s = 0.f, q = 0.f;
  for (int b = t; b < nb; b += 256) {
    s += psum[(size_t)b * nc + col];
    q += psq[(size_t)b * nc + col];
  }
#pragma unroll
  for (int off = 32; off > 0; off >>= 1) {
    s += __shfl_xor(s, off, 64);
    q += __shfl_xor(q, off, 64);
  }
  if ((t & 63) == 0) { ws[t >> 6] = s; wq[t >> 6] = q; }
  __syncthreads();
  if (t == 0) {
    s = ws[0] + ws[1] + ws[2] + ws[3];
    q = wq[0] + wq[1] + wq[2] + wq[3];
    float m = s * invn;
    float v = fmaxf(q * invn - m * m, 0.f);
    float sc = g[col] * rsqrtf(v + BN_EPS);
    osc[col] = sc;
    osh[col] = be[col] - m * sc;
  }
}

// ---------------- classifier z1 stats (sum & sumsq from one array) ----------------

__global__ __launch_bounds__(256) void k_statz(
    const float* __restrict__ z1, const float* __restrict__ g,
    const float* __restrict__ be, float* __restrict__ osc, float* __restrict__ osh) {
  __shared__ float ws[4], wq[4];
  int col = blockIdx.x;
  int t = threadIdx.x;
  float s = 0.f, q = 0.f;
  for (int b = t; b < GG; b += 256) {
    float v = z1[(size_t)b * 128 + col];
    s += v;
    q += v * v;
  }
#pragma unroll
  for (int off = 32; off > 0; off >>= 1) {
    s += __shfl_xor(s, off, 64);
    q += __shfl_xor(q, off, 64);
  }
  if ((t & 63) == 0) { ws[t >> 6] = s; wq[t >> 6] = q; }
  __syncthreads();
  if (t == 0) {
    s = ws[0] + ws[1] + ws[2] + ws[3];
    q = wq[0] + wq[1] + wq[2] + wq[3];
    float m = s / (float)GG;
    float v = fmaxf(q / (float)GG - m * m, 0.f);
    float sc = g[col] * rsqrtf(v + BN_EPS);
    osc[col] = sc;
    osh[col] = be[col] - m * sc;
  }
}

// ---------------- pooling (batch sorted -> contiguous ranges), bf16 X ------------

static __device__ __forceinline__ int lb_i32(const int* a, int n, int key) {
  int lo = 0, hi = n;
  while (lo < hi) {
    int mid = (lo + hi) >> 1;
    if (a[mid] < key) lo = mid + 1; else hi = mid;
  }
  return lo;
}

__global__ __launch_bounds__(512) void k_pool(
    const unsigned short* __restrict__ X, const int* __restrict__ batch,
    const float* __restrict__ tsc, const float* __restrict__ tsh,
    float* __restrict__ z, int n) {
  __shared__ int slo, shi;
  __shared__ float ssum[8][128], smax[8][128];
  int g = blockIdx.x;
  int t = threadIdx.x;
  int sg = t >> 6;           // 0..7 row-subgroup
  int c2 = (t & 63) << 1;    // column pair base
  if (t == 0) slo = lb_i32(batch, n, g);        // two searches in different
  if (t == 64) shi = lb_i32(batch, n, g + 1);   // waves -> run concurrently
  __syncthreads();
  int lo = slo, hi = shi;
  float a0 = tsc[c2], a1 = tsc[c2 + 1];
  float b0 = tsh[c2], b1 = tsh[c2 + 1];
  float s0 = 0.f, s1 = 0.f;
  float m0 = -3.402823466e38f, m1 = -3.402823466e38f;
  for (int i = lo + sg; i < hi; i += 8) {
    unsigned u = *(const unsigned*)(X + (size_t)i * DD + c2);
    float v0 = fmaxf(0.f, bf2f((unsigned short)(u & 0xffff)) * a0 + b0);
    float v1 = fmaxf(0.f, bf2f((unsigned short)(u >> 16)) * a1 + b1);
    s0 += v0; m0 = fmaxf(m0, v0);
    s1 += v1; m1 = fmaxf(m1, v1);
  }
  ssum[sg][c2] = s0; ssum[sg][c2 + 1] = s1;
  smax[sg][c2] = m0; smax[sg][c2 + 1] = m1;
  __syncthreads();
  if (t < 128) {
    float S = 0.f, M = -3.402823466e38f;
#pragma unroll
    for (int k = 0; k < 8; ++k) {
      S += ssum[k][t];
      M = fmaxf(M, smax[k][t]);
    }
    float cntf = (float)(hi - lo);
    z[(size_t)g * 384 + t] = S;
    z[(size_t)g * 384 + 128 + t] = S / fmaxf(cntf, 1.f);
    z[(size_t)g * 384 + 256 + t] = M;
  }
}

// ---------------- classifier head (fp32, tiny; no atomics) ----------------
// k_cls1 v2: 2 graphs/block, transposed fp32 weights -> 48 independent contiguous
// float4 loads per thread (pipelined), z rows via LDS broadcast. Kills the 43us
// latency chain of v1 (one serial 384-iter column-strided loop per thread).

__global__ __launch_bounds__(256) void k_cls1(
    const float* __restrict__ z, const float* __restrict__ cW1t,
    const float* __restrict__ cb1, float* __restrict__ z1) {
  __shared__ float zr[2][384];
  __shared__ float part[2][2][128];  // [kh][g][c]
  int g0 = blockIdx.x * 2;
  int tid = threadIdx.x;
  int c = tid & 127, kh = tid >> 7;
  for (int i = tid; i < 768; i += 256) {  // rows g0,g0+1 contiguous in z
    int g = i / 384, k = i - g * 384;
    zr[g][k] = z[(size_t)g0 * 384 + i];
    (void)g; (void)k;
  }
  __syncthreads();
  float a0 = 0.f, a1 = 0.f;
  const float* wrow = cW1t + (size_t)c * 384 + kh * 192;
#pragma unroll
  for (int i = 0; i < 48; ++i) {
    float4 w = *(const float4*)(wrow + i * 4);
    float4 z0 = *(const float4*)(&zr[0][kh * 192 + i * 4]);
    float4 z1v = *(const float4*)(&zr[1][kh * 192 + i * 4]);
    a0 += w.x * z0.x + w.y * z0.y + w.z * z0.z + w.w * z0.w;
    a1 += w.x * z1v.x + w.y * z1v.y + w.z * z1v.z + w.w * z1v.w;
  }
  part[kh][0][c] = a0;
  part[kh][1][c] = a1;
  __syncthreads();
  if (kh == 0) {
    float b = cb1[c];
    z1[(size_t)g0 * 128 + c] = part[0][0][c] + part[1][0][c] + b;
    z1[(size_t)(g0 + 1) * 128 + c] = part[0][1][c] + part[1][1][c] + b;
  }
}

__global__ void k_cls2(const float* __restrict__ z1, const float* __restrict__ csc,
                       const float* __restrict__ csh, const float* __restrict__ cW2,
                       const float* __restrict__ cb2, const float* __restrict__ cW3,
                       const float* __restrict__ cb3, float* __restrict__ out) {
  __shared__ float z1n[128];
  __shared__ float z2s[64];
  int g = blockIdx.x;
  int t = threadIdx.x;  // 128
  z1n[t] = fmaxf(0.f, z1[(size_t)g * 128 + t] * csc[t] + csh[t]);
  __syncthreads();
  if (t < 64) {
    float s = cb2[t];
#pragma unroll 4
    for (int k = 0; k < 128; ++k) s = fmaf(z1n[k], cW2[(size_t)k * 64 + t], s);
    z2s[t] = fmaxf(0.f, s);
  }
  __syncthreads();
  if (t < 2) {
    float s = cb3[t];
#pragma unroll 4
    for (int c = 0; c < 64; ++c) s = fmaf(z2s[c], cW3[(size_t)c * 2 + t], s);
    out[(size_t)g * 2 + t] = s;
  }
}

// ---------------- launch ----------------

extern "C" void kernel_launch(void* const* d_in, const int* in_sizes, int n_in,
                              void* d_out, int out_size, void* d_ws, size_t ws_size,
                              hipStream_t stream) {
  const float* x = (const float*)d_in[0];
  const int* ei = (const int*)d_in[1];     // int32 (harness downcasts int64)
  const int* batch = (const int*)d_in[2];  // int32
  const float* W1 = (const float*)d_in[4];
  const float* b1 = (const float*)d_in[5];
  const float* g1 = (const float*)d_in[6];
  const float* be1 = (const float*)d_in[7];
  const float* W2 = (const float*)d_in[8];
  const float* b2 = (const float*)d_in[9];
  const float* gbn = (const float*)d_in[10];
  const float* bbn = (const float*)d_in[11];
  const float* epsv = (const float*)d_in[12];
  const float* cW1 = (const float*)d_in[13];
  const float* cb1 = (const float*)d_in[14];
  const float* cg = (const float*)d_in[15];
  const float* cbeta = (const float*)d_in[16];
  const float* cW2 = (const float*)d_in[17];
  const float* cb2 = (const float*)d_in[18];
  const float* cW3 = (const float*)d_in[19];
  const float* cb3 = (const float*)d_in[20];
  float* out = (float*)d_out;
  (void)b1;  // BN1 shift is independent of b1 (cancels in (y - mean))

  char* p = (char*)d_ws;
  auto alloc = [&](size_t bytes) {
    char* r = p;
    p += (bytes + 255) & ~(size_t)255;
    return r;
  };
  const int NB2 = (NN + 255) / 256;  // 391 fused GEMM row-blocks
  int* cnt = (int*)alloc((size_t)NN * 4);
  int* rs = (int*)alloc((size_t)(NN + 1) * 4);
  int* cur = (int*)alloc((size_t)NN * 4);
  int* ci = (int*)alloc((size_t)EE * 4);
  int* part = (int*)alloc(128 * 4);
  int* partx = (int*)alloc(128 * 4);
  unsigned short* xbf = (unsigned short*)alloc((size_t)NN * DD * 2);
  unsigned short* h0 = (unsigned short*)alloc((size_t)NN * DD * 2);
  unsigned short* xp = (unsigned short*)alloc((size_t)NN * DD * 2);
  float* psum = (float*)alloc((size_t)NB2 * 128 * 4);
  float* psq = (float*)alloc((size_t)NB2 * 128 * 4);
  float* tsc1 = (float*)alloc(256 * 4);
  float* tsh1 = (float*)alloc(256 * 4);
  float* tscX = (float*)alloc(128 * 4);
  float* tshX = (float*)alloc(128 * 4);
  float* zbuf = (float*)alloc((size_t)GG * 384 * 4);
  float* z1 = (float*)alloc((size_t)GG * 128 * 4);
  unsigned short* W1t = (unsigned short*)alloc((size_t)4 * 256 * 128 * 2);
  unsigned short* W2t = (unsigned short*)alloc((size_t)4 * 128 * 256 * 2);
  float* cW1t = (float*)alloc((size_t)128 * 384 * 4);
  float* M2s = (float*)alloc((size_t)196 * 16384 * 4);  // per-block slabs
  float* css = (float*)alloc((size_t)196 * 128 * 4);
  float* M2f = (float*)alloc((size_t)128 * 128 * 4);
  float* csf = (float*)alloc(128 * 4);
  (void)ws_size; (void)n_in; (void)in_sizes; (void)out_size;

  // weight convert+transpose (static across layers/calls)
  k_conv<<<512, 256, 0, stream>>>(W1, W2, cW1, W1t, W2t, cW1t);
  // x -> bf16
  k_x2bf<<<(NN * DD / 4 + 255) / 256, 256, 0, stream>>>(x, xbf);

  // CSR build (edges static across layers)
  hipMemsetAsync(cnt, 0, (size_t)NN * 4, stream);
  k_hist<<<(EE + 255) / 256, 256, 0, stream>>>(ei, cnt);
  const int nscan = (NN + 1023) / 1024;  // 98
  k_part<<<nscan, 1024, 0, stream>>>(cnt, part);
  k_scanpart<<<1, 128, 0, stream>>>(part, partx, nscan);
  k_rs<<<nscan, 1024, 0, stream>>>(cnt, partx, rs, cur);
  k_fill<<<(EE + 255) / 256, 256, 0, stream>>>(ei, cur, ci);

  for (int l = 0; l < LL; ++l) {
    const unsigned short* Xl = (l == 0) ? xbf : xp;
    k_agg_bf16<<<(NN * 16 + 255) / 256, 256, 0, stream>>>(
        Xl, rs, ci, epsv, l, (l > 0) ? 1 : 0, tscX, tshX, h0, NN);
    // analytic BN1 stats: M2 = h0^T h0 (196 reg-accum slabs); fold; scale/shift
    k_mom<<<196, 512, 0, stream>>>(h0, M2s, css, NN);
    k_red<<<64, 256, 0, stream>>>(M2s, css, M2f, csf);
    k_bn1<<<256, 128, 0, stream>>>(M2f, csf, W1t + (size_t)l * 256 * 128,
                                   g1 + (size_t)l * 256, be1 + (size_t)l * 256,
                                   tsc1, tsh1);
    // fused GEMM1+BN1+ReLU+GEMM2 (h1 never touches HBM), 256 rows/block
    k_gfused<<<NB2, 512, 0, stream>>>(
        h0, tsc1, tsh1, W1t + (size_t)l * 256 * 128, W2t + (size_t)l * 128 * 256,
        b2 + (size_t)l * 128, xp, psum, psq, NN);
    k_finred<<<128, 256, 0, stream>>>(psum, psq, NB2, 128, gbn + (size_t)l * 128,
                                      bbn + (size_t)l * 128, tscX, tshX, 1.0f / NN);
  }

  k_pool<<<GG, 512, 0, stream>>>(xp, batch, tscX, tshX, zbuf, NN);
  k_cls1<<<GG / 2, 256, 0, stream>>>(zbuf, cW1t, cb1, z1);
  k_statz<<<128, 256, 0, stream>>>(z1, cg, cbeta, tscX, tshX);
  k_cls2<<<GG, 128, 0, stream>>>(z1, tscX, tshX, cW2, cb2, cW3, cb3, out);
}

// Round 9
// 681.209 us; speedup vs baseline: 1.2664x; 1.0008x over previous
//
#include <hip/hip_runtime.h>
#include <cstdint>
#include <cstddef>

// Problem constants (fixed by the reference setup_inputs).
#define NN 100000
#define EE 500000
#define DD 128
#define GG 512
#define LL 4
#define BN_EPS 1e-5f

typedef __attribute__((ext_vector_type(8))) short short8;
typedef __attribute__((ext_vector_type(8))) unsigned short ushort8v;
typedef __attribute__((ext_vector_type(4))) float f32x4;

static __device__ __forceinline__ unsigned short f2bf(float f) {
  union { float f; unsigned u; } v;
  v.f = f;
  unsigned r = v.u + 0x7fffu + ((v.u >> 16) & 1u);  // RNE
  return (unsigned short)(r >> 16);
}
static __device__ __forceinline__ float bf2f(unsigned short u) {
  union { unsigned u; float f; } v;
  v.u = ((unsigned)u) << 16;
  return v.f;
}

// ---------------- CSR build (int32 inputs) ----------------

__global__ void k_hist(const int* __restrict__ ei, int* __restrict__ cnt) {
  int e = blockIdx.x * 256 + threadIdx.x;
  if (e < EE) {
    int d = ei[EE + e];
    if (d >= 0 && d < NN) atomicAdd(&cnt[d], 1);
  }
}

__global__ void k_part(const int* __restrict__ cnt, int* __restrict__ part) {
  __shared__ int sm[1024];
  int t = threadIdx.x;
  int i = blockIdx.x * 1024 + t;
  sm[t] = (i < NN) ? cnt[i] : 0;
  __syncthreads();
  for (int off = 512; off > 0; off >>= 1) {
    if (t < off) sm[t] += sm[t + off];
    __syncthreads();
  }
  if (t == 0) part[blockIdx.x] = sm[0];
}

__global__ void k_scanpart(const int* __restrict__ part, int* __restrict__ partx, int nb) {
  __shared__ int sm[128];
  int t = threadIdx.x;
  int v = (t < nb) ? part[t] : 0;
  sm[t] = v;
  __syncthreads();
  for (int off = 1; off < 128; off <<= 1) {
    int u = (t >= off) ? sm[t - off] : 0;
    __syncthreads();
    sm[t] += u;
    __syncthreads();
  }
  if (t < nb) partx[t] = sm[t] - v;
}

__global__ void k_rs(const int* __restrict__ cnt, const int* __restrict__ partx,
                     int* __restrict__ rs, int* __restrict__ cur) {
  __shared__ int sm[1024];
  int t = threadIdx.x;
  int i = blockIdx.x * 1024 + t;
  int v = (i < NN) ? cnt[i] : 0;
  sm[t] = v;
  __syncthreads();
  for (int off = 1; off < 1024; off <<= 1) {
    int u = (t >= off) ? sm[t - off] : 0;
    __syncthreads();
    sm[t] += u;
    __syncthreads();
  }
  if (i < NN) {
    int excl = partx[blockIdx.x] + sm[t] - v;
    rs[i] = excl;
    cur[i] = excl;
    if (i == NN - 1) rs[NN] = excl + v;
  }
}

__global__ void k_fill(const int* __restrict__ ei, int* __restrict__ cur,
                       int* __restrict__ ci) {
  int e = blockIdx.x * 256 + threadIdx.x;
  if (e < EE) {
    int s = ei[e];
    int d = ei[EE + e];
    if (d >= 0 && d < NN && s >= 0 && s < NN) {
      int pos = atomicAdd(&cur[d], 1);
      if (pos >= 0 && pos < EE) ci[pos] = s;  // order irrelevant (sum)
    }
  }
}

// ---------------- weight convert: W -> W^T bf16 + cW1 -> cW1t fp32 ----------------

__global__ void k_conv(const float* __restrict__ W1, const float* __restrict__ W2,
                       const float* __restrict__ cW1, unsigned short* __restrict__ W1t,
                       unsigned short* __restrict__ W2t, float* __restrict__ cW1t) {
  int idx = blockIdx.x * 256 + threadIdx.x;
  if (idx < 4 * 256 * 128) {
    {  // W1: [l][k][nc] (K=128,NC=256) -> [l][nc][k]
      int l = idx >> 15, rem = idx & 32767;
      int nc = rem >> 7, k = rem & 127;
      W1t[idx] = f2bf(W1[(l << 15) + k * 256 + nc]);
    }
    {  // W2: [l][k][nc] (K=256,NC=128) -> [l][nc][k]
      int l = idx >> 15, rem = idx & 32767;
      int nc = rem >> 8, k = rem & 255;
      W2t[idx] = f2bf(W2[(l << 15) + k * 128 + nc]);
    }
  }
  if (idx < 128 * 384) {  // cW1: [k][c] -> [c][k] fp32 (for k_cls1 row loads)
    int c = idx / 384, k = idx - c * 384;
    cW1t[idx] = cW1[(size_t)k * 128 + c];
  }
}

// ---------------- x -> bf16 convert (streaming, once per call) ----------------

__global__ void k_x2bf(const float* __restrict__ x, unsigned short* __restrict__ xb) {
  int i = blockIdx.x * 256 + threadIdx.x;
  if (i < NN * DD / 4) {
    float4 v = *(const float4*)(x + (size_t)i * 4);
    ushort4 o;
    o.x = f2bf(v.x); o.y = f2bf(v.y); o.z = f2bf(v.z); o.w = f2bf(v.w);
    *(ushort4*)(xb + (size_t)i * 4) = o;
  }
}

// ---------------- aggregation v2: 4-deep neighbor prefetch ----------------
// 16 lanes/node, ushort8 (16B) loads. Random-gather latency chain (avg degree 5):
// 4 named prefetch regs (static indexing, no scratch) keep 4 loads in flight.

__global__ __launch_bounds__(256) void k_agg_bf16(
    const unsigned short* __restrict__ X, const int* __restrict__ rs,
    const int* __restrict__ ci, const float* __restrict__ epsv, int l, int mode,
    const float* __restrict__ tsc, const float* __restrict__ tsh,
    unsigned short* __restrict__ h0, int n) {
  int idx = blockIdx.x * 256 + threadIdx.x;
  int node = idx >> 4;
  int c8 = (idx & 15) << 3;
  if (node >= n) return;
  float sa[8], sb[8];
  if (mode) {
    float4 a0 = *(const float4*)(tsc + c8), a1 = *(const float4*)(tsc + c8 + 4);
    float4 b0 = *(const float4*)(tsh + c8), b1 = *(const float4*)(tsh + c8 + 4);
    sa[0] = a0.x; sa[1] = a0.y; sa[2] = a0.z; sa[3] = a0.w;
    sa[4] = a1.x; sa[5] = a1.y; sa[6] = a1.z; sa[7] = a1.w;
    sb[0] = b0.x; sb[1] = b0.y; sb[2] = b0.z; sb[3] = b0.w;
    sb[4] = b1.x; sb[5] = b1.y; sb[6] = b1.z; sb[7] = b1.w;
  }
  float se = 1.f + epsv[l];
  ushort8v v = *(const ushort8v*)(X + (size_t)node * DD + c8);
  float acc[8];
#pragma unroll
  for (int j = 0; j < 8; ++j) {
    float f = bf2f(v[j]);
    if (mode) f = fmaxf(0.f, f * sa[j] + sb[j]);
    acc[j] = se * f;
  }
  int e0 = rs[node], e1 = rs[node + 1];
#define NLD(ee) (*(const ushort8v*)(X + (size_t)ci[ee] * DD + c8))
#define NACC(uc)                                                  \
  {                                                               \
    _Pragma("unroll") for (int j = 0; j < 8; ++j) {               \
      float f = bf2f(uc[j]);                                      \
      if (mode) f = fmaxf(0.f, f * sa[j] + sb[j]);                \
      acc[j] += f;                                                \
    }                                                             \
  }
  ushort8v p0 = (ushort8v){0, 0, 0, 0, 0, 0, 0, 0};
  ushort8v p1 = p0, p2 = p0, p3 = p0;
  if (e0 + 0 < e1) p0 = NLD(e0 + 0);
  if (e0 + 1 < e1) p1 = NLD(e0 + 1);
  if (e0 + 2 < e1) p2 = NLD(e0 + 2);
  if (e0 + 3 < e1) p3 = NLD(e0 + 3);
  for (int e = e0; e < e1; e += 4) {
    ushort8v c0 = p0, c1 = p1, c2 = p2, c3 = p3;
    if (e + 4 < e1) p0 = NLD(e + 4);
    if (e + 5 < e1) p1 = NLD(e + 5);
    if (e + 6 < e1) p2 = NLD(e + 6);
    if (e + 7 < e1) p3 = NLD(e + 7);
    NACC(c0);
    if (e + 1 < e1) NACC(c1);
    if (e + 2 < e1) NACC(c2);
    if (e + 3 < e1) NACC(c3);
  }
#undef NLD
#undef NACC
  ushort8v o;
#pragma unroll
  for (int j = 0; j < 8; ++j) o[j] = f2bf(acc[j]);
  *(ushort8v*)(h0 + (size_t)node * DD + c8) = o;
}

// ---------------- M2 = h0^T h0 (128x128) + colsum(h0), for analytic BN1 stats ----
// 196 persistent blocks grid-stride over 391 chunks of 256 rows; register M2
// accumulation; one non-atomic 64KB slab write per block. XOR block-swizzle on
// the transposed staging cuts write bank conflicts to ~4-way.

__global__ __launch_bounds__(512) void k_mom(
    const unsigned short* __restrict__ h0, float* __restrict__ M2s,
    float* __restrict__ css, int n) {
  constexpr int HT = 264;
  constexpr int NCH = (NN + 255) / 256;  // 391
  constexpr int NBLK = 196;
  __shared__ __align__(16) unsigned short Ht[128 * HT];  // 67584 B
  __shared__ float lcs[128];
  int tid = threadIdx.x;
  int lane = tid & 63, wave = tid >> 6;
  int quad = lane >> 4, l15 = lane & 15;
  if (tid < 128) lcs[tid] = 0.f;
  int c8 = (tid & 15) << 3;
  int rloc = tid >> 4;  // 0..31
  float csr[8];
#pragma unroll
  for (int j = 0; j < 8; ++j) csr[j] = 0.f;
  f32x4 acc[8];
#pragma unroll
  for (int j = 0; j < 8; ++j) acc[j] = (f32x4){0.f, 0.f, 0.f, 0.f};

  for (int ch = blockIdx.x; ch < NCH; ch += NBLK) {
    int n0 = ch * 256;
    __syncthreads();  // prev chunk's MFMA reads done (also covers lcs zeroing)
#pragma unroll
    for (int pass = 0; pass < 8; ++pass) {
      int nl = rloc + pass * 32;  // 0..255
      int gr = n0 + nl;
      ushort8v v = (ushort8v){0, 0, 0, 0, 0, 0, 0, 0};
      if (gr < n) v = *(const ushort8v*)(h0 + (size_t)gr * DD + c8);
#pragma unroll
      for (int j = 0; j < 8; ++j) {
        int row = c8 + j;
        int sb = (nl >> 3) ^ ((row >> 3) & 7);
        Ht[row * HT + (sb << 3) + (nl & 7)] = v[j];
        csr[j] += bf2f(v[j]);
      }
    }
    __syncthreads();
#pragma unroll
    for (int kc = 0; kc < 8; ++kc) {
      int b = kc * 4 + quad;  // 8-elem block index of ko = kc*32 + quad*8
      int arow = wave * 16 + l15;
      short8 avv =
          *(const short8*)(&Ht[arow * HT + ((b ^ ((arow >> 3) & 7)) << 3)]);
#pragma unroll
      for (int j = 0; j < 8; ++j) {
        int brow = j * 16 + l15;
        short8 bvv =
            *(const short8*)(&Ht[brow * HT + ((b ^ ((brow >> 3) & 7)) << 3)]);
        acc[j] = __builtin_amdgcn_mfma_f32_16x16x32_bf16(avv, bvv, acc[j], 0, 0, 0);
      }
    }
  }
  // slab write (block-private, non-atomic)
  float* M2 = M2s + (size_t)blockIdx.x * 16384;
  int lr = wave * 16 + quad * 4;
#pragma unroll
  for (int j = 0; j < 8; ++j)
#pragma unroll
    for (int g = 0; g < 4; ++g)
      M2[(lr + g) * 128 + j * 16 + l15] = acc[j][g];
#pragma unroll
  for (int j = 0; j < 8; ++j) atomicAdd(&lcs[c8 + j], csr[j]);
  __syncthreads();
  if (tid < 128) css[(size_t)blockIdx.x * 128 + tid] = lcs[tid];
}

// fold the 196 slabs
__global__ void k_red(const float* __restrict__ M2s, const float* __restrict__ css,
                      float* __restrict__ M2f, float* __restrict__ csf) {
  int i = blockIdx.x * 256 + threadIdx.x;  // 64 blocks -> 16384
  float s = 0.f;
  for (int k = 0; k < 196; ++k) s += M2s[(size_t)k * 16384 + i];
  M2f[i] = s;
  if (i < 128) {
    float c = 0.f;
    for (int k = 0; k < 196; ++k) c += css[(size_t)k * 128 + i];
    csf[i] = c;
  }
}

// analytic BN1 scale/shift: var_c = w^T M2 w / N - (colsum.w/N)^2  (b1 cancels)
__global__ __launch_bounds__(128) void k_bn1(
    const float* __restrict__ M2, const float* __restrict__ cs,
    const unsigned short* __restrict__ W1t_l, const float* __restrict__ g1_l,
    const float* __restrict__ be1_l, float* __restrict__ osc,
    float* __restrict__ osh) {
  __shared__ float wsh[128];
  __shared__ float red1[2], red2[2];
  int c = blockIdx.x, t = threadIdx.x;
  float w = bf2f(W1t_l[c * 128 + t]);
  wsh[t] = w;
  __syncthreads();
  float inner = 0.f;
#pragma unroll 4
  for (int k = 0; k < 128; ++k) inner = fmaf(M2[t * 128 + k], wsh[k], inner);
  float s1 = w * inner;
  float s2 = w * cs[t];
#pragma unroll
  for (int off = 32; off > 0; off >>= 1) {
    s1 += __shfl_xor(s1, off, 64);
    s2 += __shfl_xor(s2, off, 64);
  }
  if ((t & 63) == 0) { red1[t >> 6] = s1; red2[t >> 6] = s2; }
  __syncthreads();
  if (t == 0) {
    float q = (red1[0] + red1[1]) * (1.0f / NN);
    float um = (red2[0] + red2[1]) * (1.0f / NN);
    float var = fmaxf(q - um * um, 0.f);
    float sc = g1_l[c] * rsqrtf(var + BN_EPS);
    osc[c] = sc;
    osh[c] = be1_l[c] - um * sc;
  }
}

// ---------------- fused GEMM1+BN1+ReLU+GEMM2, v5: whole-tile + region aliasing ----
// 256 rows/block, 8 waves x 32 rows. LDS = 3 x 34816B regions (105.5KB total,
// back at the PROVEN v3 size; v4's 140KB exceeded the 128KiB verified ceiling):
//   R0 = H rows 0..127 (waves 0-3's private rows)
//   R1 = W1 cg-tile, then (after barrier) H rows 128..255 (waves 4-7's rows)
//   R2 = W2 half-tile
// Per half: stage both tiles -> bar -> MM1 full-K (64 MFMAs, reads R1) -> bar
// (R1 reads drained; R1 becomes H_hi) -> EPI + MM2 full-half (64 MFMAs)
// barrier-free (own-wave H rows; LDS ops wave-ordered). 7 barriers total with
// 64-MFMA stretches (v3: 9 barriers / 16-MFMA stretches). Next-half tiles
// prefetched into registers under the first stretch. Accumulation order == v3.

__global__ __launch_bounds__(512, 2) void k_gfused(
    const unsigned short* __restrict__ A, const float* __restrict__ sc1,
    const float* __restrict__ sh1, const unsigned short* __restrict__ W1t_l,
    const unsigned short* __restrict__ W2t_l, const float* __restrict__ b2_l,
    unsigned short* __restrict__ C, float* __restrict__ psum,
    float* __restrict__ psq, int n) {
  constexpr int TS = 136;  // row stride (ushorts), 272B -> 2-way bank alias (free)
  __shared__ __align__(16) unsigned short R0[128 * TS];  // 34816 B (H_lo)
  __shared__ __align__(16) unsigned short R1[128 * TS];  // 34816 B (W1 / H_hi)
  __shared__ __align__(16) unsigned short R2[128 * TS];  // 34816 B (W2)
  __shared__ float bsum[128], bsq[128];

  int tid = threadIdx.x;
  int lane = tid & 63, wave = tid >> 6;
  int quad = lane >> 4, l15 = lane & 15;
  int row0 = blockIdx.x * 256;
  int r0 = row0 + wave * 32 + l15;
  int r1 = r0 + 16;

  // per-wave H base: local rows 0..31 map to this wave's 32 private rows
  unsigned short* Hw = (wave < 4) ? (R0 + (wave * 32) * TS)
                                  : (R1 + ((wave - 4) * 32) * TS);

  if (tid < 128) { bsum[tid] = 0.f; bsq[tid] = 0.f; }

  // A row fragments in registers: 2 row-groups x 4 k-slices
  short8 av0[4], av1[4];
#pragma unroll
  for (int ks = 0; ks < 4; ++ks) {
    av0[ks] = (short8){0, 0, 0, 0, 0, 0, 0, 0};
    av1[ks] = (short8){0, 0, 0, 0, 0, 0, 0, 0};
    if (r0 < n) av0[ks] = *(const short8*)(A + (size_t)r0 * 128 + ks * 32 + quad * 8);
    if (r1 < n) av1[ks] = *(const short8*)(A + (size_t)r1 * 128 + ks * 32 + quad * 8);
  }

  ushort8v pW1[4], pW2[4];  // tile prefetch (4 x 16B granules per tile per thread)
  f32x4 acc1a[8], acc1b[8], acc2a[8], acc2b[8];
#pragma unroll
  for (int j = 0; j < 8; ++j) {
    acc1a[j] = (f32x4){0.f, 0.f, 0.f, 0.f};
    acc1b[j] = (f32x4){0.f, 0.f, 0.f, 0.f};
    acc2a[j] = (f32x4){0.f, 0.f, 0.f, 0.f};
    acc2b[j] = (f32x4){0.f, 0.f, 0.f, 0.f};
  }

  // granule mapping for [128 rows][128 cols] tiles: 2048 granules, 4/thread
#define LD_W1TILE(cg)                                                           \
  {                                                                             \
    _Pragma("unroll") for (int it = 0; it < 4; ++it) {                          \
      int f = tid + it * 512, rr = f >> 4, cc = (f & 15) << 3;                  \
      pW1[it] =                                                                 \
          *(const ushort8v*)(W1t_l + (size_t)((cg)*128 + rr) * 128 + cc);       \
    }                                                                           \
  }
#define LD_W2TILE(h)                                                            \
  {                                                                             \
    _Pragma("unroll") for (int it = 0; it < 4; ++it) {                          \
      int f = tid + it * 512, rr = f >> 4, cc = (f & 15) << 3;                  \
      pW2[it] = *(const ushort8v*)(W2t_l + (size_t)rr * 256 + (h)*128 + cc);    \
    }                                                                           \
  }
#define ST_TILES                                                                \
  {                                                                             \
    _Pragma("unroll") for (int it = 0; it < 4; ++it) {                          \
      int f = tid + it * 512, rr = f >> 4, cc = (f & 15) << 3;                  \
      *(ushort8v*)(&R1[rr * TS + cc]) = pW1[it];                                \
      *(ushort8v*)(&R2[rr * TS + cc]) = pW2[it];                                \
    }                                                                           \
  }
#define MM1FULL                                                                 \
  {                                                                             \
    _Pragma("unroll") for (int ks = 0; ks < 4; ++ks) {                          \
      int ko = ks * 32 + quad * 8;                                              \
      short8 a0 = av0[ks];                                                      \
      short8 a1 = av1[ks];                                                      \
      _Pragma("unroll") for (int cf = 0; cf < 8; ++cf) {                        \
        short8 bv = *(const short8*)(&R1[(cf * 16 + l15) * TS + ko]);           \
        acc1a[cf] = __builtin_amdgcn_mfma_f32_16x16x32_bf16(a0, bv, acc1a[cf],  \
                                                            0, 0, 0);           \
        acc1b[cf] = __builtin_amdgcn_mfma_f32_16x16x32_bf16(a1, bv, acc1b[cf],  \
                                                            0, 0, 0);           \
      }                                                                         \
    }                                                                           \
  }
#define MM2FULL                                                                 \
  {                                                                             \
    _Pragma("unroll") for (int ks = 0; ks < 4; ++ks) {                          \
      int ko = ks * 32 + quad * 8;                                              \
      short8 a0 = *(const short8*)(&Hw[l15 * TS + ko]);                         \
      short8 a1 = *(const short8*)(&Hw[(16 + l15) * TS + ko]);                  \
      _Pragma("unroll") for (int cf = 0; cf < 8; ++cf) {                        \
        short8 bv = *(const short8*)(&R2[(cf * 16 + l15) * TS + ko]);           \
        acc2a[cf] = __builtin_amdgcn_mfma_f32_16x16x32_bf16(a0, bv, acc2a[cf],  \
                                                            0, 0, 0);           \
        acc2b[cf] = __builtin_amdgcn_mfma_f32_16x16x32_bf16(a1, bv, acc2b[cf],  \
                                                            0, 0, 0);           \
      }                                                                         \
    }                                                                           \
  }
#define EPI(cg)                                                                 \
  {                                                                             \
    int lrb = quad * 4; /* local rows within this wave's 32 */                  \
    _Pragma("unroll") for (int cf = 0; cf < 8; ++cf) {                          \
      int col = (cg)*128 + cf * 16 + l15;                                       \
      float sc = sc1[col], sh = sh1[col];                                       \
      _Pragma("unroll") for (int g = 0; g < 4; ++g) {                           \
        Hw[(lrb + g) * TS + cf * 16 + l15] =                                    \
            f2bf(fmaxf(0.f, acc1a[cf][g] * sc + sh));                           \
        Hw[(lrb + 16 + g) * TS + cf * 16 + l15] =                               \
            f2bf(fmaxf(0.f, acc1b[cf][g] * sc + sh));                           \
      }                                                                         \
    }                                                                           \
  }
#define ZACC1                                                                   \
  {                                                                             \
    _Pragma("unroll") for (int j = 0; j < 8; ++j) {                             \
      acc1a[j] = (f32x4){0.f, 0.f, 0.f, 0.f};                                   \
      acc1b[j] = (f32x4){0.f, 0.f, 0.f, 0.f};                                   \
    }                                                                           \
  }

  // ---- half 0 ----
  LD_W1TILE(0)
  LD_W2TILE(0)
  ST_TILES
  __syncthreads();  // [1] tiles visible (also bsum zero visible)
  LD_W1TILE(1)      // prefetch half-1 tiles under the MFMA stretch
  LD_W2TILE(1)
  MM1FULL           // acc1 = h0 @ W1cg0 (full K, reads R1)
  __syncthreads();  // [2] all R1-as-W1 reads drained; R1 becomes H_hi
  EPI(0)            // h1 cols 0..127 -> H (own-wave rows; wave-ordered vs MM2)
  MM2FULL           // acc2 += h1[:,0:128] @ W2[0:128,:]
  __syncthreads();  // [3] all H(R1)/R2 reads drained
  // ---- half 1 ----
  ST_TILES
  ZACC1
  __syncthreads();  // [4] half-1 tiles visible
  MM1FULL           // acc1 = h0 @ W1cg1
  __syncthreads();  // [5] R1-as-W1 reads drained
  EPI(1)            // h1 cols 128..255 -> H
  MM2FULL           // acc2 += h1[:,128:256] @ W2[128:256,:]

  // ---- final epilogue: +b2, BN2 partial stats, coalesced C store (Ct = H) ----
  // Ct writes hit own-wave rows (wave-ordered after own MM2 reads); barrier [6]
  // makes Ct globally visible before the coalesced all-rows store.
  float s8[8], q8[8];
#pragma unroll
  for (int j = 0; j < 8; ++j) { s8[j] = 0.f; q8[j] = 0.f; }
  int lrb = quad * 4;
#pragma unroll
  for (int cf = 0; cf < 8; ++cf) {
    float bv = b2_l[cf * 16 + l15];
#pragma unroll
    for (int g = 0; g < 4; ++g) {
      {
        float e = acc2a[cf][g] + bv;
        Hw[(lrb + g) * TS + cf * 16 + l15] = f2bf(e);
        if (r0 - l15 + lrb + g + row0 - row0 >= 0) {}  // no-op
        if (row0 + wave * 32 + lrb + g < n) { s8[cf] += e; q8[cf] += e * e; }
      }
      {
        float e = acc2b[cf][g] + bv;
        Hw[(lrb + 16 + g) * TS + cf * 16 + l15] = f2bf(e);
        if (row0 + wave * 32 + lrb + 16 + g < n) { s8[cf] += e; q8[cf] += e * e; }
      }
    }
  }
#pragma unroll
  for (int cf = 0; cf < 8; ++cf) {
    s8[cf] += __shfl_xor(s8[cf], 16, 64);
    s8[cf] += __shfl_xor(s8[cf], 32, 64);
    q8[cf] += __shfl_xor(q8[cf], 16, 64);
    q8[cf] += __shfl_xor(q8[cf], 32, 64);
  }
  __syncthreads();  // [6] Ct complete everywhere
  if (quad == 0) {
#pragma unroll
    for (int cf = 0; cf < 8; ++cf) {
      atomicAdd(&bsum[cf * 16 + l15], s8[cf]);
      atomicAdd(&bsq[cf * 16 + l15], q8[cf]);
    }
  }
#pragma unroll
  for (int it = 0; it < 8; ++it) {
    int f = tid + it * 512;
    int rr = f >> 4, cc = (f & 15) << 3;
    int gr = row0 + rr;
    const unsigned short* Hrow = (rr < 128) ? &R0[rr * TS] : &R1[(rr - 128) * TS];
    if (gr < n)
      *(ushort8v*)(C + (size_t)gr * 128 + cc) = *(const ushort8v*)(&Hrow[cc]);
  }
  __syncthreads();  // [7] bsum atomics drained
  if (tid < 128) {
    psum[(size_t)blockIdx.x * 128 + tid] = bsum[tid];
    psq[(size_t)blockIdx.x * 128 + tid] = bsq[tid];
  }
#undef LD_W1TILE
#undef LD_W2TILE
#undef ST_TILES
#undef MM1FULL
#undef MM2FULL
#undef EPI
#undef ZACC1
}

// ---------------- column-stat reduce + BN finalize (one block per column) --------

__global__ __launch_bounds__(256) void k_finred(
    const float* __restrict__ psum, const float* __restrict__ psq, int nb, int nc,
    const float* __restrict__ g, const float* __restrict__ be,
    float* __restrict__ osc, float* __restrict__ osh, float invn) {
  __shared__ float ws[4], wq[4];
  int col = blockIdx.x;
  int t = threadIdx.x;
  float s = 0.f, q = 0.f;
  for (int b = t; b < nb; b += 256) {
    s += psum[(size_t)b * nc + col];
    q += psq[(size_t)b * nc + col];
  }
#pragma unroll
  for (int off = 32; off > 0; off >>= 1) {
    s += __shfl_xor(s, off, 64);
    q += __shfl_xor(q, off, 64);
  }
  if ((t & 63) == 0) { ws[t >> 6] = s; wq[t >> 6] = q; }
  __syncthreads();
  if (t == 0) {
    s = ws[0] + ws[1] + ws[2] + ws[3];
    q = wq[0] + wq[1] + wq[2] + wq[3];
    float m = s * invn;
    float v = fmaxf(q * invn - m * m, 0.f);
    float sc = g[col] * rsqrtf(v + BN_EPS);
    osc[col] = sc;
    osh[col] = be[col] - m * sc;
  }
}

// ---------------- classifier z1 stats (sum & sumsq from one array) ----------------

__global__ __launch_bounds__(256) void k_statz(
    const float* __restrict__ z1, const float* __restrict__ g,
    const float* __restrict__ be, float* __restrict__ osc, float* __restrict__ osh) {
  __shared__ float ws[4], wq[4];
  int col = blockIdx.x;
  int t = threadIdx.x;
  float s = 0.f, q = 0.f;
  for (int b = t; b < GG; b += 256) {
    float v = z1[(size_t)b * 128 + col];
    s += v;
    q += v * v;
  }
#pragma unroll
  for (int off = 32; off > 0; off >>= 1) {
    s += __shfl_xor(s, off, 64);
    q += __shfl_xor(q, off, 64);
  }
  if ((t & 63) == 0) { ws[t >> 6] = s; wq[t >> 6] = q; }
  __syncthreads();
  if (t == 0) {
    s = ws[0] + ws[1] + ws[2] + ws[3];
    q = wq[0] + wq[1] + wq[2] + wq[3];
    float m = s / (float)GG;
    float v = fmaxf(q / (float)GG - m * m, 0.f);
    float sc = g[col] * rsqrtf(v + BN_EPS);
    osc[col] = sc;
    osh[col] = be[col] - m * sc;
  }
}

// ---------------- pooling (batch sorted -> contiguous ranges), bf16 X ------------

static __device__ __forceinline__ int lb_i32(const int* a, int n, int key) {
  int lo = 0, hi = n;
  while (lo < hi) {
    int mid = (lo + hi) >> 1;
    if (a[mid] < key) lo = mid + 1; else hi = mid;
  }
  return lo;
}

__global__ __launch_bounds__(512) void k_pool(
    const unsigned short* __restrict__ X, const int* __restrict__ batch,
    const float* __restrict__ tsc, const float* __restrict__ tsh,
    float* __restrict__ z, int n) {
  __shared__ int slo, shi;
  __shared__ float ssum[8][128], smax[8][128];
  int g = blockIdx.x;
  int t = threadIdx.x;
  int sg = t >> 6;           // 0..7 row-subgroup
  int c2 = (t & 63) << 1;    // column pair base
  if (t == 0) slo = lb_i32(batch, n, g);        // two searches in different
  if (t == 64) shi = lb_i32(batch, n, g + 1);   // waves -> run concurrently
  __syncthreads();
  int lo = slo, hi = shi;
  float a0 = tsc[c2], a1 = tsc[c2 + 1];
  float b0 = tsh[c2], b1 = tsh[c2 + 1];
  float s0 = 0.f, s1 = 0.f;
  float m0 = -3.402823466e38f, m1 = -3.402823466e38f;
  for (int i = lo + sg; i < hi; i += 8) {
    unsigned u = *(const unsigned*)(X + (size_t)i * DD + c2);
    float v0 = fmaxf(0.f, bf2f((unsigned short)(u & 0xffff)) * a0 + b0);
    float v1 = fmaxf(0.f, bf2f((unsigned short)(u >> 16)) * a1 + b1);
    s0 += v0; m0 = fmaxf(m0, v0);
    s1 += v1; m1 = fmaxf(m1, v1);
  }
  ssum[sg][c2] = s0; ssum[sg][c2 + 1] = s1;
  smax[sg][c2] = m0; smax[sg][c2 + 1] = m1;
  __syncthreads();
  if (t < 128) {
    float S = 0.f, M = -3.402823466e38f;
#pragma unroll
    for (int k = 0; k < 8; ++k) {
      S += ssum[k][t];
      M = fmaxf(M, smax[k][t]);
    }
    float cntf = (float)(hi - lo);
    z[(size_t)g * 384 + t] = S;
    z[(size_t)g * 384 + 128 + t] = S / fmaxf(cntf, 1.f);
    z[(size_t)g * 384 + 256 + t] = M;
  }
}

// ---------------- classifier head (fp32, tiny; no atomics) ----------------
// k_cls1 v2: 2 graphs/block, transposed fp32 weights -> 48 independent contiguous
// float4 loads per thread (pipelined), z rows via LDS broadcast.

__global__ __launch_bounds__(256) void k_cls1(
    const float* __restrict__ z, const float* __restrict__ cW1t,
    const float* __restrict__ cb1, float* __restrict__ z1) {
  __shared__ float zr[2][384];
  __shared__ float part[2][2][128];  // [kh][g][c]
  int g0 = blockIdx.x * 2;
  int tid = threadIdx.x;
  int c = tid & 127, kh = tid >> 7;
  for (int i = tid; i < 768; i += 256) {  // rows g0,g0+1 contiguous in z
    int g = i / 384, k = i - g * 384;
    zr[g][k] = z[(size_t)g0 * 384 + i];
    (void)g; (void)k;
  }
  __syncthreads();
  float a0 = 0.f, a1 = 0.f;
  const float* wrow = cW1t + (size_t)c * 384 + kh * 192;
#pragma unroll
  for (int i = 0; i < 48; ++i) {
    float4 w = *(const float4*)(wrow + i * 4);
    float4 z0 = *(const float4*)(&zr[0][kh * 192 + i * 4]);
    float4 z1v = *(const float4*)(&zr[1][kh * 192 + i * 4]);
    a0 += w.x * z0.x + w.y * z0.y + w.z * z0.z + w.w * z0.w;
    a1 += w.x * z1v.x + w.y * z1v.y + w.z * z1v.z + w.w * z1v.w;
  }
  part[kh][0][c] = a0;
  part[kh][1][c] = a1;
  __syncthreads();
  if (kh == 0) {
    float b = cb1[c];
    z1[(size_t)g0 * 128 + c] = part[0][0][c] + part[1][0][c] + b;
    z1[(size_t)(g0 + 1) * 128 + c] = part[0][1][c] + part[1][1][c] + b;
  }
}

__global__ void k_cls2(const float* __restrict__ z1, const float* __restrict__ csc,
                       const float* __restrict__ csh, const float* __restrict__ cW2,
                       const float* __restrict__ cb2, const float* __restrict__ cW3,
                       const float* __restrict__ cb3, float* __restrict__ out) {
  __shared__ float z1n[128];
  __shared__ float z2s[64];
  int g = blockIdx.x;
  int t = threadIdx.x;  // 128
  z1n[t] = fmaxf(0.f, z1[(size_t)g * 128 + t] * csc[t] + csh[t]);
  __syncthreads();
  if (t < 64) {
    float s = cb2[t];
#pragma unroll 4
    for (int k = 0; k < 128; ++k) s = fmaf(z1n[k], cW2[(size_t)k * 64 + t], s);
    z2s[t] = fmaxf(0.f, s);
  }
  __syncthreads();
  if (t < 2) {
    float s = cb3[t];
#pragma unroll 4
    for (int c = 0; c < 64; ++c) s = fmaf(z2s[c], cW3[(size_t)c * 2 + t], s);
    out[(size_t)g * 2 + t] = s;
  }
}

// ---------------- launch ----------------

extern "C" void kernel_launch(void* const* d_in, const int* in_sizes, int n_in,
                              void* d_out, int out_size, void* d_ws, size_t ws_size,
                              hipStream_t stream) {
  const float* x = (const float*)d_in[0];
  const int* ei = (const int*)d_in[1];     // int32 (harness downcasts int64)
  const int* batch = (const int*)d_in[2];  // int32
  const float* W1 = (const float*)d_in[4];
  const float* b1 = (const float*)d_in[5];
  const float* g1 = (const float*)d_in[6];
  const float* be1 = (const float*)d_in[7];
  const float* W2 = (const float*)d_in[8];
  const float* b2 = (const float*)d_in[9];
  const float* gbn = (const float*)d_in[10];
  const float* bbn = (const float*)d_in[11];
  const float* epsv = (const float*)d_in[12];
  const float* cW1 = (const float*)d_in[13];
  const float* cb1 = (const float*)d_in[14];
  const float* cg = (const float*)d_in[15];
  const float* cbeta = (const float*)d_in[16];
  const float* cW2 = (const float*)d_in[17];
  const float* cb2 = (const float*)d_in[18];
  const float* cW3 = (const float*)d_in[19];
  const float* cb3 = (const float*)d_in[20];
  float* out = (float*)d_out;
  (void)b1;  // BN1 shift is independent of b1 (cancels in (y - mean))

  char* p = (char*)d_ws;
  auto alloc = [&](size_t bytes) {
    char* r = p;
    p += (bytes + 255) & ~(size_t)255;
    return r;
  };
  const int NB2 = (NN + 255) / 256;  // 391 fused GEMM row-blocks
  int* cnt = (int*)alloc((size_t)NN * 4);
  int* rs = (int*)alloc((size_t)(NN + 1) * 4);
  int* cur = (int*)alloc((size_t)NN * 4);
  int* ci = (int*)alloc((size_t)EE * 4);
  int* part = (int*)alloc(128 * 4);
  int* partx = (int*)alloc(128 * 4);
  unsigned short* xbf = (unsigned short*)alloc((size_t)NN * DD * 2);
  unsigned short* h0 = (unsigned short*)alloc((size_t)NN * DD * 2);
  unsigned short* xp = (unsigned short*)alloc((size_t)NN * DD * 2);
  float* psum = (float*)alloc((size_t)NB2 * 128 * 4);
  float* psq = (float*)alloc((size_t)NB2 * 128 * 4);
  float* tsc1 = (float*)alloc(256 * 4);
  float* tsh1 = (float*)alloc(256 * 4);
  float* tscX = (float*)alloc(128 * 4);
  float* tshX = (float*)alloc(128 * 4);
  float* zbuf = (float*)alloc((size_t)GG * 384 * 4);
  float* z1 = (float*)alloc((size_t)GG * 128 * 4);
  unsigned short* W1t = (unsigned short*)alloc((size_t)4 * 256 * 128 * 2);
  unsigned short* W2t = (unsigned short*)alloc((size_t)4 * 128 * 256 * 2);
  float* cW1t = (float*)alloc((size_t)128 * 384 * 4);
  float* M2s = (float*)alloc((size_t)196 * 16384 * 4);  // per-block slabs
  float* css = (float*)alloc((size_t)196 * 128 * 4);
  float* M2f = (float*)alloc((size_t)128 * 128 * 4);
  float* csf = (float*)alloc(128 * 4);
  (void)ws_size; (void)n_in; (void)in_sizes; (void)out_size;

  // weight convert+transpose (static across layers/calls)
  k_conv<<<512, 256, 0, stream>>>(W1, W2, cW1, W1t, W2t, cW1t);
  // x -> bf16
  k_x2bf<<<(NN * DD / 4 + 255) / 256, 256, 0, stream>>>(x, xbf);

  // CSR build (edges static across layers)
  hipMemsetAsync(cnt, 0, (size_t)NN * 4, stream);
  k_hist<<<(EE + 255) / 256, 256, 0, stream>>>(ei, cnt);
  const int nscan = (NN + 1023) / 1024;  // 98
  k_part<<<nscan, 1024, 0, stream>>>(cnt, part);
  k_scanpart<<<1, 128, 0, stream>>>(part, partx, nscan);
  k_rs<<<nscan, 1024, 0, stream>>>(cnt, partx, rs, cur);
  k_fill<<<(EE + 255) / 256, 256, 0, stream>>>(ei, cur, ci);

  for (int l = 0; l < LL; ++l) {
    const unsigned short* Xl = (l == 0) ? xbf : xp;
    k_agg_bf16<<<(NN * 16 + 255) / 256, 256, 0, stream>>>(
        Xl, rs, ci, epsv, l, (l > 0) ? 1 : 0, tscX, tshX, h0, NN);
    // analytic BN1 stats: M2 = h0^T h0 (196 reg-accum slabs); fold; scale/shift
    k_mom<<<196, 512, 0, stream>>>(h0, M2s, css, NN);
    k_red<<<64, 256, 0, stream>>>(M2s, css, M2f, csf);
    k_bn1<<<256, 128, 0, stream>>>(M2f, csf, W1t + (size_t)l * 256 * 128,
                                   g1 + (size_t)l * 256, be1 + (size_t)l * 256,
                                   tsc1, tsh1);
    // fused GEMM1+BN1+ReLU+GEMM2 (h1 never touches HBM), aliased-region v5
    k_gfused<<<NB2, 512, 0, stream>>>(
        h0, tsc1, tsh1, W1t + (size_t)l * 256 * 128, W2t + (size_t)l * 128 * 256,
        b2 + (size_t)l * 128, xp, psum, psq, NN);
    k_finred<<<128, 256, 0, stream>>>(psum, psq, NB2, 128, gbn + (size_t)l * 128,
                                      bbn + (size_t)l * 128, tscX, tshX, 1.0f / NN);
  }

  k_pool<<<GG, 512, 0, stream>>>(xp, batch, tscX, tshX, zbuf, NN);
  k_cls1<<<GG / 2, 256, 0, stream>>>(zbuf, cW1t, cb1, z1);
  k_statz<<<128, 256, 0, stream>>>(z1, cg, cbeta, tscX, tshX);
  k_cls2<<<GG, 128, 0, stream>>>(z1, tscX, tshX, cW2, cb2, cW3, cb3, out);
}